// Round 4
// baseline (791.085 us; speedup 1.0000x reference)
//
#include <hip/hip_runtime.h>
#include <hip/hip_bf16.h>

constexpr int B_ = 2, L_ = 2048, D_ = 1024, H_ = 16;

using bf16x8 = __attribute__((ext_vector_type(8))) short;
using f32x4  = __attribute__((ext_vector_type(4))) float;

__device__ __forceinline__ short f2b(float f) {
  union { float f; unsigned int u; } v; v.f = f;
  unsigned int r = (v.u + 0x7FFFu + ((v.u >> 16) & 1u)) >> 16;
  return (short)r;
}
__device__ __forceinline__ float b2f(unsigned short h) {
  union { unsigned int u; float f; } v; v.u = ((unsigned int)h) << 16; return v.f;
}
// split x into hi/lo bf16: x ~= hi + lo, |x - hi - lo| ~ 2^-18 |x|
__device__ __forceinline__ void split2(float x, float y, unsigned int& h, unsigned int& l) {
  unsigned short hx = (unsigned short)f2b(x), hy = (unsigned short)f2b(y);
  h = (unsigned int)hx | ((unsigned int)hy << 16);
  unsigned short lx = (unsigned short)f2b(x - b2f(hx)), ly = (unsigned short)f2b(y - b2f(hy));
  l = (unsigned int)lx | ((unsigned int)ly << 16);
}
__device__ __forceinline__ float dot4(float4 a, float4 b) {
  return a.x * b.x + a.y * b.y + a.z * b.z + a.w * b.w;
}

// ---------------- transpose+cast: W[K,N] fp32 -> Wt[N,K] bf16 ----------------
__global__ __launch_bounds__(256) void tcast(const float* __restrict__ W, short* __restrict__ Wt,
                                             int N, int K) {
  __shared__ float T[64][65];
  int n0 = blockIdx.x * 64, k0 = blockIdx.y * 64;
  int tid = threadIdx.x;
#pragma unroll
  for (int i = 0; i < 16; ++i) {
    int idx = i * 256 + tid;
    int r = idx >> 6, c = idx & 63;
    T[r][c] = W[(size_t)(k0 + r) * N + n0 + c];
  }
  __syncthreads();
#pragma unroll
  for (int i = 0; i < 16; ++i) {
    int idx = i * 256 + tid;
    int rr = idx >> 6, cc = idx & 63;
    Wt[(size_t)(n0 + rr) * K + k0 + cc] = f2b(T[cc][rr]);
  }
}

// two-weight tcast (1024x1024 each), blockIdx.z selects
__global__ __launch_bounds__(256) void tcast2(const float* __restrict__ W1, const float* __restrict__ W2,
                                              short* __restrict__ Wt1, short* __restrict__ Wt2) {
  __shared__ float T[64][65];
  const float* W = blockIdx.z ? W2 : W1;
  short* Wt = blockIdx.z ? Wt2 : Wt1;
  int n0 = blockIdx.x * 64, k0 = blockIdx.y * 64;
  int tid = threadIdx.x;
#pragma unroll
  for (int i = 0; i < 16; ++i) {
    int idx = i * 256 + tid;
    int r = idx >> 6, c = idx & 63;
    T[r][c] = W[(size_t)(k0 + r) * 1024 + n0 + c];
  }
  __syncthreads();
#pragma unroll
  for (int i = 0; i < 16; ++i) {
    int idx = i * 256 + tid;
    int rr = idx >> 6, cc = idx & 63;
    Wt[(size_t)(n0 + rr) * 1024 + k0 + cc] = f2b(T[cc][rr]);
  }
}

// two-weight split tcast: W[K,N] fp32 -> (Wh,Wl)[N,K] bf16 hi/lo pair, z selects weight
__global__ __launch_bounds__(256) void tcast_split2(const float* __restrict__ W1, const float* __restrict__ W2,
                                                    short* __restrict__ Wh1, short* __restrict__ Wl1,
                                                    short* __restrict__ Wh2, short* __restrict__ Wl2) {
  __shared__ float T[64][65];
  const float* W = blockIdx.z ? W2 : W1;
  short* Wh = blockIdx.z ? Wh2 : Wh1;
  short* Wl = blockIdx.z ? Wl2 : Wl1;
  int n0 = blockIdx.x * 64, k0 = blockIdx.y * 64;
  int tid = threadIdx.x;
#pragma unroll
  for (int i = 0; i < 16; ++i) {
    int idx = i * 256 + tid;
    int r = idx >> 6, c = idx & 63;
    T[r][c] = W[(size_t)(k0 + r) * 1024 + n0 + c];
  }
  __syncthreads();
#pragma unroll
  for (int i = 0; i < 16; ++i) {
    int idx = i * 256 + tid;
    int rr = idx >> 6, cc = idx & 63;
    float w = T[cc][rr];
    short h = f2b(w);
    short l = f2b(w - b2f((unsigned short)h));
    size_t o = (size_t)(n0 + rr) * 1024 + k0 + cc;
    Wh[o] = h;
    Wl[o] = l;
  }
}

// ---------------- MFMA GEMM core (shared) ----------------
template <int BN, typename CT>
__device__ __forceinline__ void gemm_bt_body(const float* __restrict__ A, const short* __restrict__ Wt,
                                             CT* __restrict__ C, int N, int K, int bx, int by) {
  constexpr int MT = (BN == 128) ? 4 : 2;
  constexpr int NT = 4;
  __shared__ __align__(16) short As[128 * 32];
  __shared__ __align__(16) short Bs[BN * 32];
  int tid = threadIdx.x;
  int wave = tid >> 6, lane = tid & 63, quad = lane >> 4, l15 = lane & 15;
  int m0 = by * 128, n0 = bx * BN;
  int wm = (BN == 128) ? (wave >> 1) * 64 : wave * 32;
  int wn = (BN == 128) ? (wave & 1) * 64 : 0;
  f32x4 acc[MT][NT];
#pragma unroll
  for (int mt = 0; mt < MT; ++mt)
#pragma unroll
    for (int nt = 0; nt < NT; ++nt) acc[mt][nt] = (f32x4){0.f, 0.f, 0.f, 0.f};

  for (int k0 = 0; k0 < K; k0 += 32) {
    __syncthreads();
#pragma unroll
    for (int i = 0; i < 2; ++i) {
      int chunk = i * 256 + tid;
      int m = chunk >> 2, kc = (chunk & 3) * 8;
      const float* ap = A + (size_t)(m0 + m) * K + k0 + kc;
      float4 a0 = *(const float4*)ap;
      float4 a1 = *(const float4*)(ap + 4);
      __hip_bfloat162 c0 = __float22bfloat162_rn(make_float2(a0.x, a0.y));
      __hip_bfloat162 c1 = __float22bfloat162_rn(make_float2(a0.z, a0.w));
      __hip_bfloat162 c2 = __float22bfloat162_rn(make_float2(a1.x, a1.y));
      __hip_bfloat162 c3 = __float22bfloat162_rn(make_float2(a1.z, a1.w));
      uint4 u;
      u.x = *(unsigned int*)&c0; u.y = *(unsigned int*)&c1;
      u.z = *(unsigned int*)&c2; u.w = *(unsigned int*)&c3;
      *(uint4*)&As[m * 32 + kc] = u;
    }
#pragma unroll
    for (int i = 0; i < BN * 4 / 256; ++i) {
      int chunk = i * 256 + tid;
      int n = chunk >> 2, kc = (chunk & 3) * 8;
      uint4 w = *(const uint4*)(Wt + (size_t)(n0 + n) * K + k0 + kc);
      *(uint4*)&Bs[n * 32 + kc] = w;
    }
    __syncthreads();
    bf16x8 af[MT], bf[NT];
#pragma unroll
    for (int mt = 0; mt < MT; ++mt) af[mt] = *(bf16x8*)&As[(wm + mt * 16 + l15) * 32 + quad * 8];
#pragma unroll
    for (int nt = 0; nt < NT; ++nt) bf[nt] = *(bf16x8*)&Bs[(wn + nt * 16 + l15) * 32 + quad * 8];
#pragma unroll
    for (int mt = 0; mt < MT; ++mt)
#pragma unroll
      for (int nt = 0; nt < NT; ++nt)
        acc[mt][nt] = __builtin_amdgcn_mfma_f32_16x16x32_bf16(af[mt], bf[nt], acc[mt][nt], 0, 0, 0);
  }
#pragma unroll
  for (int mt = 0; mt < MT; ++mt)
#pragma unroll
    for (int nt = 0; nt < NT; ++nt)
#pragma unroll
      for (int r = 0; r < 4; ++r) {
        size_t idx = (size_t)(m0 + wm + mt * 16 + quad * 4 + r) * N + n0 + wn + nt * 16 + l15;
        if constexpr (sizeof(CT) == 2) C[idx] = f2b(acc[mt][nt][r]);
        else C[idx] = acc[mt][nt][r];
      }
}

template <int BN>
__global__ __launch_bounds__(256) void gemm_bt(const float* __restrict__ A, const short* __restrict__ Wt,
                                               float* __restrict__ C, int N, int K) {
  gemm_bt_body<BN, float>(A, Wt, C, N, K, blockIdx.x, blockIdx.y);
}

// bf16-output variant (for qkv)
__global__ __launch_bounds__(256) void gemm_bt_h(const float* __restrict__ A, const short* __restrict__ Wt,
                                                 short* __restrict__ C, int N, int K) {
  gemm_bt_body<128, short>(A, Wt, C, N, K, blockIdx.x, blockIdx.y);
}

// two-GEMM variant: z selects (Wt1->C1) vs (Wt2->C2), 1024x1024
__global__ __launch_bounds__(256) void gemm_bt2(const float* __restrict__ A, const short* __restrict__ Wt1,
                                                const short* __restrict__ Wt2, float* __restrict__ C1,
                                                float* __restrict__ C2) {
  gemm_bt_body<64, float>(A, blockIdx.z ? Wt2 : Wt1, blockIdx.z ? C2 : C1, 1024, 1024,
                          blockIdx.x, blockIdx.y);
}

// ---------------- split-precision MFMA GEMM: C = A@W with ~fp32 accuracy ----------------
__global__ __launch_bounds__(256) void gemm_bt_split2(const float* __restrict__ A,
                                                      const short* __restrict__ Wh1, const short* __restrict__ Wl1,
                                                      const short* __restrict__ Wh2, const short* __restrict__ Wl2,
                                                      float* __restrict__ C1, float* __restrict__ C2) {
  constexpr int K = 1024, N = 1024;
  const short* Wh = blockIdx.z ? Wh2 : Wh1;
  const short* Wl = blockIdx.z ? Wl2 : Wl1;
  float* C = blockIdx.z ? C2 : C1;
  __shared__ __align__(16) short Ash[128 * 32];
  __shared__ __align__(16) short Asl[128 * 32];
  __shared__ __align__(16) short Bsh[64 * 32];
  __shared__ __align__(16) short Bsl[64 * 32];
  int tid = threadIdx.x;
  int wave = tid >> 6, lane = tid & 63, quad = lane >> 4, l15 = lane & 15;
  int m0 = blockIdx.y * 128, n0 = blockIdx.x * 64;
  int wm = wave * 32;
  f32x4 acc[2][4];
#pragma unroll
  for (int mt = 0; mt < 2; ++mt)
#pragma unroll
    for (int nt = 0; nt < 4; ++nt) acc[mt][nt] = (f32x4){0.f, 0.f, 0.f, 0.f};

  for (int k0 = 0; k0 < K; k0 += 32) {
    __syncthreads();
#pragma unroll
    for (int i = 0; i < 2; ++i) {
      int chunk = i * 256 + tid;
      int m = chunk >> 2, kc = (chunk & 3) * 8;
      const float* ap = A + (size_t)(m0 + m) * K + k0 + kc;
      float4 a0 = *(const float4*)ap;
      float4 a1 = *(const float4*)(ap + 4);
      uint4 uh, ul;
      split2(a0.x, a0.y, uh.x, ul.x);
      split2(a0.z, a0.w, uh.y, ul.y);
      split2(a1.x, a1.y, uh.z, ul.z);
      split2(a1.z, a1.w, uh.w, ul.w);
      *(uint4*)&Ash[m * 32 + kc] = uh;
      *(uint4*)&Asl[m * 32 + kc] = ul;
    }
    {
      int n = tid >> 2, kc = (tid & 3) * 8;
      size_t off = (size_t)(n0 + n) * K + k0 + kc;
      *(uint4*)&Bsh[n * 32 + kc] = *(const uint4*)(Wh + off);
      *(uint4*)&Bsl[n * 32 + kc] = *(const uint4*)(Wl + off);
    }
    __syncthreads();
    bf16x8 ah[2], al[2], bh[4], bl[4];
#pragma unroll
    for (int mt = 0; mt < 2; ++mt) {
      ah[mt] = *(bf16x8*)&Ash[(wm + mt * 16 + l15) * 32 + quad * 8];
      al[mt] = *(bf16x8*)&Asl[(wm + mt * 16 + l15) * 32 + quad * 8];
    }
#pragma unroll
    for (int nt = 0; nt < 4; ++nt) {
      bh[nt] = *(bf16x8*)&Bsh[(nt * 16 + l15) * 32 + quad * 8];
      bl[nt] = *(bf16x8*)&Bsl[(nt * 16 + l15) * 32 + quad * 8];
    }
#pragma unroll
    for (int mt = 0; mt < 2; ++mt)
#pragma unroll
      for (int nt = 0; nt < 4; ++nt) {
        f32x4 a = acc[mt][nt];
        a = __builtin_amdgcn_mfma_f32_16x16x32_bf16(al[mt], bh[nt], a, 0, 0, 0);
        a = __builtin_amdgcn_mfma_f32_16x16x32_bf16(ah[mt], bl[nt], a, 0, 0, 0);
        a = __builtin_amdgcn_mfma_f32_16x16x32_bf16(ah[mt], bh[nt], a, 0, 0, 0);
        acc[mt][nt] = a;
      }
  }
#pragma unroll
  for (int mt = 0; mt < 2; ++mt)
#pragma unroll
    for (int nt = 0; nt < 4; ++nt)
#pragma unroll
      for (int r = 0; r < 4; ++r) {
        size_t idx = (size_t)(m0 + wm + mt * 16 + quad * 4 + r) * N + n0 + nt * 16 + l15;
        C[idx] = acc[mt][nt][r];
      }
}

// ---------------- MFMA bf16 causal flash attention (bf16 qkv input) ----------------
__global__ __launch_bounds__(256) void attn_mfma(const short* __restrict__ qkv, float* __restrict__ outp) {
  __shared__ __align__(16) short Kl[64 * 64];
  __shared__ __align__(16) short Vt[64 * 64];
  __shared__ __align__(16) short Pl[64 * 64];
  int qb = 31 - blockIdx.x, h = blockIdx.y, b = blockIdx.z;
  int tid = threadIdx.x;
  int wave = tid >> 6, lane = tid & 63;
  int quad = lane >> 4, l15 = lane & 15;
  int qrow = qb * 64 + wave * 16 + l15;
  bf16x8 qf[2];
  {
    const short* qbase = qkv + (size_t)(b * L_ + qrow) * 3072 + h * 64;
#pragma unroll
    for (int s = 0; s < 2; ++s) qf[s] = *(const bf16x8*)(qbase + s * 32 + quad * 8);
  }
  f32x4 Of[4];
  float mrow[4], lrow[4], alpha[4];
#pragma unroll
  for (int dt = 0; dt < 4; ++dt) Of[dt] = (f32x4){0.f, 0.f, 0.f, 0.f};
#pragma unroll
  for (int r = 0; r < 4; ++r) { mrow[r] = -1e30f; lrow[r] = 0.f; }

  for (int kt = 0; kt <= qb; ++kt) {
    __syncthreads();
#pragma unroll
    for (int it = 0; it < 2; ++it) {
      int e8 = tid + it * 256;
      int key = e8 >> 3, g = e8 & 7;
      const short* src = qkv + ((size_t)((b * L_ + kt * 64 + key) * 3) + 1) * 1024 + h * 64 + g * 8;
      *(bf16x8*)&Kl[key * 64 + ((g ^ (key & 7)) << 3)] = *(const bf16x8*)src;
    }
    {
      int key4 = tid >> 4;
      int d4 = tid & 15;
      const short* vsrc = qkv + ((size_t)((b * L_ + kt * 64 + key4 * 4) * 3) + 2) * 1024 + h * 64 + d4 * 4;
      short4 v0 = *(const short4*)vsrc;
      short4 v1 = *(const short4*)(vsrc + 3072);
      short4 v2 = *(const short4*)(vsrc + 6144);
      short4 v3 = *(const short4*)(vsrc + 9216);
      short vr0[4] = {v0.x, v0.y, v0.z, v0.w};
      short vr1[4] = {v1.x, v1.y, v1.z, v1.w};
      short vr2[4] = {v2.x, v2.y, v2.z, v2.w};
      short vr3[4] = {v3.x, v3.y, v3.z, v3.w};
      int kg = key4 >> 1, k7b = (key4 & 1) * 4;
#pragma unroll
      for (int jj = 0; jj < 4; ++jj) {
        int d = d4 * 4 + jj;
        short4 sv;
        sv.x = vr0[jj]; sv.y = vr1[jj]; sv.z = vr2[jj]; sv.w = vr3[jj];
        *(short4*)&Vt[d * 64 + ((kg ^ (d & 7)) << 3) + k7b] = sv;
      }
    }
    __syncthreads();
    f32x4 sc[4];
#pragma unroll
    for (int nt = 0; nt < 4; ++nt) sc[nt] = (f32x4){0.f, 0.f, 0.f, 0.f};
#pragma unroll
    for (int s = 0; s < 2; ++s) {
#pragma unroll
      for (int nt = 0; nt < 4; ++nt) {
        int key = nt * 16 + l15;
        bf16x8 kf = *(bf16x8*)&Kl[key * 64 + (((4 * s + quad) ^ (key & 7)) << 3)];
        sc[nt] = __builtin_amdgcn_mfma_f32_16x16x32_bf16(qf[s], kf, sc[nt], 0, 0, 0);
      }
    }
    bool diag = (kt == qb);
#pragma unroll
    for (int r = 0; r < 4; ++r) {
      float sv[4];
#pragma unroll
      for (int nt = 0; nt < 4; ++nt) {
        float v = sc[nt][r] * 0.125f;
        if (diag && (nt * 16 + l15 > wave * 16 + quad * 4 + r)) v = -1e30f;
        sv[nt] = v;
      }
      float mx = fmaxf(fmaxf(sv[0], sv[1]), fmaxf(sv[2], sv[3]));
      mx = fmaxf(mx, __shfl_xor(mx, 1));
      mx = fmaxf(mx, __shfl_xor(mx, 2));
      mx = fmaxf(mx, __shfl_xor(mx, 4));
      mx = fmaxf(mx, __shfl_xor(mx, 8));
      float mnew = fmaxf(mrow[r], mx);
      float al = __expf(mrow[r] - mnew);
      mrow[r] = mnew;
      alpha[r] = al;
      int prow = wave * 16 + quad * 4 + r;
      int r7 = prow & 7;
      float ps = 0.f;
#pragma unroll
      for (int nt = 0; nt < 4; ++nt) {
        float p = __expf(sv[nt] - mnew);
        ps += p;
        Pl[prow * 64 + ((((nt << 1) + (l15 >> 3)) ^ r7) << 3) + (l15 & 7)] = f2b(p);
      }
      ps += __shfl_xor(ps, 1);
      ps += __shfl_xor(ps, 2);
      ps += __shfl_xor(ps, 4);
      ps += __shfl_xor(ps, 8);
      lrow[r] = lrow[r] * al + ps;
    }
#pragma unroll
    for (int dt = 0; dt < 4; ++dt)
#pragma unroll
      for (int r = 0; r < 4; ++r) Of[dt][r] *= alpha[r];
#pragma unroll
    for (int s = 0; s < 2; ++s) {
      bf16x8 pf = *(bf16x8*)&Pl[(wave * 16 + l15) * 64 + (((4 * s + quad) ^ (l15 & 7)) << 3)];
#pragma unroll
      for (int dt = 0; dt < 4; ++dt) {
        int d = dt * 16 + l15;
        bf16x8 vf = *(bf16x8*)&Vt[d * 64 + (((4 * s + quad) ^ (d & 7)) << 3)];
        Of[dt] = __builtin_amdgcn_mfma_f32_16x16x32_bf16(pf, vf, Of[dt], 0, 0, 0);
      }
    }
  }
#pragma unroll
  for (int r = 0; r < 4; ++r) alpha[r] = 1.f / lrow[r];
  int orow = qb * 64 + wave * 16 + quad * 4;
#pragma unroll
  for (int dt = 0; dt < 4; ++dt)
#pragma unroll
    for (int r = 0; r < 4; ++r)
      outp[(size_t)(b * L_ + orow + r) * 1024 + h * 64 + dt * 16 + l15] = Of[dt][r] * alpha[r];
}

// ---------------- layernorm over last dim D=1024, in place ----------------
__global__ __launch_bounds__(256) void ln_kernel(float* __restrict__ X, const float* __restrict__ g,
                                                 const float* __restrict__ bb) {
  int row = blockIdx.x, tid = threadIdx.x;
  float* xr = X + (size_t)row * D_;
  float v[4], s = 0.f, ss = 0.f;
#pragma unroll
  for (int i = 0; i < 4; ++i) { v[i] = xr[tid + i * 256]; s += v[i]; ss += v[i] * v[i]; }
#pragma unroll
  for (int off = 32; off; off >>= 1) { s += __shfl_xor(s, off); ss += __shfl_xor(ss, off); }
  __shared__ float rs[4], rss[4];
  if ((tid & 63) == 0) { rs[tid >> 6] = s; rss[tid >> 6] = ss; }
  __syncthreads();
  float S = rs[0] + rs[1] + rs[2] + rs[3];
  float SS = rss[0] + rss[1] + rss[2] + rss[3];
  float mean = S * (1.f / 1024.f);
  float var = SS * (1.f / 1024.f) - mean * mean;
  float inv = rsqrtf(var + 1e-5f);
#pragma unroll
  for (int i = 0; i < 4; ++i) {
    int c = tid + i * 256;
    xr[c] = (v[i] - mean) * inv * g[c] + bb[c];
  }
}

// ---------------- fused: LN -> LN -> gate mix ----------------
__global__ __launch_bounds__(256) void ln2mix_kernel(const float* __restrict__ X,
                                                     const float* __restrict__ g1, const float* __restrict__ b1,
                                                     const float* __restrict__ g2, const float* __restrict__ b2,
                                                     const float* __restrict__ gpre, const float* __restrict__ bgate,
                                                     const float* __restrict__ fo, float* __restrict__ outp) {
  int row = blockIdx.x, tid = threadIdx.x;
  const float* xr = X + (size_t)row * D_;
  __shared__ float rs[4], rss[4];
  float v[4], s = 0.f, ss = 0.f;
#pragma unroll
  for (int i = 0; i < 4; ++i) { v[i] = xr[tid + i * 256]; s += v[i]; ss += v[i] * v[i]; }
#pragma unroll
  for (int off = 32; off; off >>= 1) { s += __shfl_xor(s, off); ss += __shfl_xor(ss, off); }
  if ((tid & 63) == 0) { rs[tid >> 6] = s; rss[tid >> 6] = ss; }
  __syncthreads();
  float S = rs[0] + rs[1] + rs[2] + rs[3];
  float SS = rss[0] + rss[1] + rss[2] + rss[3];
  float mean = S * (1.f / 1024.f);
  float var = SS * (1.f / 1024.f) - mean * mean;
  float inv = rsqrtf(var + 1e-5f);
  s = 0.f; ss = 0.f;
#pragma unroll
  for (int i = 0; i < 4; ++i) {
    int c = tid + i * 256;
    v[i] = (v[i] - mean) * inv * g1[c] + b1[c];
    s += v[i]; ss += v[i] * v[i];
  }
#pragma unroll
  for (int off = 32; off; off >>= 1) { s += __shfl_xor(s, off); ss += __shfl_xor(ss, off); }
  __syncthreads();
  if ((tid & 63) == 0) { rs[tid >> 6] = s; rss[tid >> 6] = ss; }
  __syncthreads();
  S = rs[0] + rs[1] + rs[2] + rs[3];
  SS = rss[0] + rss[1] + rss[2] + rss[3];
  mean = S * (1.f / 1024.f);
  var = SS * (1.f / 1024.f) - mean * mean;
  inv = rsqrtf(var + 1e-5f);
#pragma unroll
  for (int i = 0; i < 4; ++i) {
    int c = tid + i * 256;
    size_t idx = (size_t)row * D_ + c;
    float w = (v[i] - mean) * inv * g2[c] + b2[c];
    float gg = 1.f / (1.f + __expf(-(gpre[idx] + bgate[c])));
    outp[idx] = gg * fo[idx] + (1.f - gg) * w;
  }
}

// ---------------- fused conv (q) / conv+L2norm (k) ----------------
__global__ __launch_bounds__(256) void convnorm_kernel(const float* __restrict__ qin, const float* __restrict__ kin,
                                                       const float* __restrict__ qw, const float* __restrict__ qb,
                                                       const float* __restrict__ kw, const float* __restrict__ kb,
                                                       float* __restrict__ qout, float* __restrict__ kout) {
  int path = blockIdx.y;
  int row = blockIdx.x * 4 + (threadIdx.x >> 6);
  int lane = threadIdx.x & 63;
  int bl = row >> 4, h = row & 15;
  int t = bl & (L_ - 1);
  int d = h * 64 + lane;
  size_t idx = (size_t)bl * D_ + d;
  const float* xin = path ? kin : qin;
  const float* w = path ? kw : qw;
  const float* bias = path ? kb : qb;
  float acc = bias[d];
#pragma unroll
  for (int j = 0; j < 4; ++j) {
    int tt = t - 3 + j;
    if (tt >= 0) acc += w[d * 4 + j] * xin[idx + (size_t)(j - 3) * D_];
  }
  if (path) {
    float n2 = acc * acc;
#pragma unroll
    for (int off = 32; off; off >>= 1) n2 += __shfl_xor(n2, off);
    acc = acc / fmaxf(sqrtf(n2), 1e-12f);
    kout[idx] = acc;
  } else {
    qout[idx] = acc;
  }
}

// ---------------- beta = sigmoid(x @ Wbeta + bbeta) ----------------
__global__ __launch_bounds__(256) void beta_kernel(const float* __restrict__ xf, const float* __restrict__ Wb,
                                                   const float* __restrict__ bb, float* __restrict__ beta) {
  int row = blockIdx.x, tid = threadIdx.x;
  int h = tid & 15, seg = tid >> 4;
  const float* xr = xf + (size_t)row * D_ + seg * 64;
  const float* wp = Wb + (seg * 64) * H_ + h;
  float p = 0.f;
  for (int k = 0; k < 64; ++k) p += xr[k] * wp[k * H_];
  __shared__ float red[16][17];
  red[seg][h] = p;
  __syncthreads();
  if (tid < 16) {
    float s = bb[tid];
#pragma unroll
    for (int s2 = 0; s2 < 16; ++s2) s += red[s2][tid];
    beta[(size_t)row * H_ + tid] = 1.f / (1.f + __expf(-s));
  }
}

// ================= chunked delta scan =================
// prep now hoists the Minv applications:
//   MK  = Minv^T @ K   (32x64)   BqM = Bq @ Minv (32x32, strictly lower)
//   denB[t] = sum_s Bq[t][s] beta[s]   zinc[j] = sum_s beta[s] K[s][j]
__global__ __launch_bounds__(256) void prep_kernel(const float* __restrict__ dq, const float* __restrict__ dk,
                                                   const float* __restrict__ beta,
                                                   float* __restrict__ MK_g, float* __restrict__ BqM_g,
                                                   float* __restrict__ denB_g, float* __restrict__ zinc_g) {
  __shared__ __align__(16) float Kl[32 * 68];
  __shared__ __align__(16) float Ql[32 * 68];
  __shared__ __align__(16) float Ml[32 * 36];
  __shared__ __align__(16) float Xl[32 * 36];
  __shared__ __align__(16) float Bql[32 * 36];
  __shared__ __align__(16) float bl[32];
  int c = blockIdx.x, bh = blockIdx.y;
  int b = bh >> 4, h = bh & 15;
  int t0 = c * 32;
  int tid = threadIdx.x;
#pragma unroll
  for (int rep = 0; rep < 2; ++rep) {
    int id = tid * 2 + rep;
    int r = id >> 4, j4 = id & 15;
    size_t gi = (size_t)(b * L_ + t0 + r) * 1024 + h * 64 + j4 * 4;
    *(float4*)&Kl[r * 68 + j4 * 4] = *(const float4*)&dk[gi];
    *(float4*)&Ql[r * 68 + j4 * 4] = *(const float4*)&dq[gi];
  }
  if (tid < 32) bl[tid] = beta[(size_t)(b * L_ + t0 + tid) * 16 + h];
  __syncthreads();
  int t = tid >> 3, s0 = (tid & 7) * 4;
  float accA[4] = {0.f, 0.f, 0.f, 0.f}, accB[4] = {0.f, 0.f, 0.f, 0.f};
#pragma unroll
  for (int k4 = 0; k4 < 16; ++k4) {
    float4 kt = *(float4*)&Kl[t * 68 + k4 * 4];
    float4 qt = *(float4*)&Ql[t * 68 + k4 * 4];
#pragma unroll
    for (int j = 0; j < 4; ++j) {
      float4 ks = *(float4*)&Kl[(s0 + j) * 68 + k4 * 4];
      accA[j] += dot4(kt, ks);
      accB[j] += dot4(qt, ks);
    }
  }
#pragma unroll
  for (int j = 0; j < 4; ++j) {
    int s = s0 + j;
    Ml[t * 36 + s] = (s < t) ? bl[t] * accA[j] : ((s == t) ? 1.f : 0.f);
    Bql[t * 36 + s] = (s < t) ? accB[j] : 0.f;
  }
  __syncthreads();
  if (tid < 32) {
    int col = tid;
    float xr[32];
#pragma unroll
    for (int tt = 0; tt < 32; ++tt) {
      float x = (tt == col) ? 1.f : 0.f;
#pragma unroll
      for (int s = 0; s < tt; ++s) x -= Ml[tt * 36 + s] * xr[s];
      xr[tt] = x;
      Xl[tt * 36 + col] = x;
    }
  }
  __syncthreads();
  size_t cb = (size_t)(bh * 64 + c);
  // MK[s][j] = sum_t Minv[t][s] * K[t][j]
  {
    int s = tid >> 3, j8 = (tid & 7) * 8;
    float4 m0 = make_float4(0.f, 0.f, 0.f, 0.f);
    float4 m1 = make_float4(0.f, 0.f, 0.f, 0.f);
#pragma unroll
    for (int t2 = 0; t2 < 32; ++t2) {
      float xv = Xl[t2 * 36 + s];
      float4 k0 = *(float4*)&Kl[t2 * 68 + j8];
      float4 k1 = *(float4*)&Kl[t2 * 68 + j8 + 4];
      m0.x += xv * k0.x; m0.y += xv * k0.y; m0.z += xv * k0.z; m0.w += xv * k0.w;
      m1.x += xv * k1.x; m1.y += xv * k1.y; m1.z += xv * k1.z; m1.w += xv * k1.w;
    }
    float* mkp = MK_g + (cb * 32 + s) * 64 + j8;
    *(float4*)mkp = m0;
    *(float4*)(mkp + 4) = m1;
  }
  // BqM[t][s] = sum_u Bq[t][u] * Minv[u][s]
  {
    int tt = tid >> 3, s4 = (tid & 7) * 4;
    float4 acc = make_float4(0.f, 0.f, 0.f, 0.f);
#pragma unroll
    for (int u4 = 0; u4 < 8; ++u4) {
      float4 bq = *(float4*)&Bql[tt * 36 + u4 * 4];
      float4 x0 = *(float4*)&Xl[(u4 * 4 + 0) * 36 + s4];
      float4 x1 = *(float4*)&Xl[(u4 * 4 + 1) * 36 + s4];
      float4 x2 = *(float4*)&Xl[(u4 * 4 + 2) * 36 + s4];
      float4 x3 = *(float4*)&Xl[(u4 * 4 + 3) * 36 + s4];
      acc.x += bq.x * x0.x + bq.y * x1.x + bq.z * x2.x + bq.w * x3.x;
      acc.y += bq.x * x0.y + bq.y * x1.y + bq.z * x2.y + bq.w * x3.y;
      acc.z += bq.x * x0.z + bq.y * x1.z + bq.z * x2.z + bq.w * x3.z;
      acc.w += bq.x * x0.w + bq.y * x1.w + bq.z * x2.w + bq.w * x3.w;
    }
    *(float4*)&BqM_g[cb * 1024 + tt * 32 + s4] = acc;
  }
  if (tid < 32) {
    float a = 0.f;
#pragma unroll
    for (int s4i = 0; s4i < 8; ++s4i)
      a += dot4(*(float4*)&Bql[tid * 36 + s4i * 4], *(float4*)&bl[s4i * 4]);
    denB_g[cb * 32 + tid] = a;
  }
  if (tid >= 64 && tid < 128) {
    int j = tid - 64;
    float a = 0.f;
#pragma unroll
    for (int s = 0; s < 32; ++s) a += bl[s] * Kl[s * 68 + j];
    zinc_g[cb * 64 + j] = a;
  }
}

// 2-barrier/iter scan: P1 {Rtmp,Y0,qz} | P2 {y, S+=Rtmp@MK, z+=zinc, stage next}.
// Double-buffered LDS (~65KB, 2 blocks/CU); register prefetch issued at P1 start.
__global__ __launch_bounds__(256) void delta_kernel(const float* __restrict__ dq, const float* __restrict__ dk,
                                                    const float* __restrict__ dv, const float* __restrict__ beta,
                                                    const float* __restrict__ MK_g, const float* __restrict__ BqM_g,
                                                    const float* __restrict__ denB_g, const float* __restrict__ zinc_g,
                                                    float* __restrict__ ys, float* __restrict__ outS,
                                                    float* __restrict__ outZ) {
  __shared__ __align__(16) float Kl[2][32 * 68];
  __shared__ __align__(16) float Ql[2][32 * 68];
  __shared__ __align__(16) float MKl[2][32 * 68];
  __shared__ __align__(16) float BqMl[2][32 * 36];
  __shared__ __align__(16) float Vl[2][32 * 5];
  __shared__ __align__(16) float bll[2][32];
  __shared__ __align__(16) float dnl[2][32];
  __shared__ __align__(16) float zil[2][64];
  __shared__ __align__(16) float S0l[4 * 68];
  __shared__ __align__(16) float Y0l[32 * 5];
  __shared__ __align__(16) float Rtl[4 * 36];
  __shared__ __align__(16) float z0l[64];
  __shared__ __align__(16) float qzl[32];
  int bh = blockIdx.x & 31, grp = blockIdx.x >> 5;  // same-bh groups share an XCD
  int b = bh >> 4, h = bh & 15;
  int i0 = grp * 4;
  int tid = threadIdx.x;
  int r = tid >> 3, j8 = (tid & 7) * 8;
  size_t kqbase = (size_t)(b * L_) * 1024 + h * 64;

  for (int e = tid; e < 4 * 68; e += 256) S0l[e] = 0.f;
  if (tid < 64) z0l[tid] = 0.f;

  float4 kA, kB, qA, qB, mA, mB, bqA, bqB;
  bqA = bqB = make_float4(0.f, 0.f, 0.f, 0.f);
  float vr = 0.f, blr = 0.f, dnb = 0.f, zi = 0.f;

#define DLOAD(CN) { \
    size_t rb_ = kqbase + (size_t)((CN) * 32 + r) * 1024 + j8; \
    kA = ((const float4*)(dk + rb_))[0]; kB = ((const float4*)(dk + rb_))[1]; \
    qA = ((const float4*)(dq + rb_))[0]; qB = ((const float4*)(dq + rb_))[1]; \
    size_t cb_ = (size_t)(bh * 64 + (CN)); \
    const float* mkp_ = MK_g + (cb_ * 32 + r) * 64 + j8; \
    mA = ((const float4*)mkp_)[0]; mB = ((const float4*)mkp_)[1]; \
    if (tid < 128) { \
      const float* bqp_ = BqM_g + cb_ * 1024 + (tid >> 2) * 32 + (tid & 3) * 8; \
      bqA = ((const float4*)bqp_)[0]; bqB = ((const float4*)bqp_)[1]; \
      vr = dv[(size_t)(b * L_ + (CN) * 32 + (tid >> 2)) * 1024 + h * 64 + i0 + (tid & 3)]; \
    } \
    if (tid < 32) { blr = beta[(size_t)(b * L_ + (CN) * 32 + tid) * 16 + h]; dnb = denB_g[cb_ * 32 + tid]; } \
    if (tid < 64) zi = zinc_g[cb_ * 64 + tid]; \
  }
#define DSTORE(NX) { \
    *(float4*)&Kl[NX][r * 68 + j8] = kA; *(float4*)&Kl[NX][r * 68 + j8 + 4] = kB; \
    *(float4*)&Ql[NX][r * 68 + j8] = qA; *(float4*)&Ql[NX][r * 68 + j8 + 4] = qB; \
    *(float4*)&MKl[NX][r * 68 + j8] = mA; *(float4*)&MKl[NX][r * 68 + j8 + 4] = mB; \
    if (tid < 128) { \
      int t_ = tid >> 2, s8_ = (tid & 3) * 8; \
      *(float4*)&BqMl[NX][t_ * 36 + s8_] = bqA; \
      *(float4*)&BqMl[NX][t_ * 36 + s8_ + 4] = bqB; \
      Vl[NX][t_ * 5 + (tid & 3)] = vr; \
    } \
    if (tid < 32) { bll[NX][tid] = blr; dnl[NX][tid] = dnb; } \
    if (tid < 64) zil[NX][tid] = zi; \
  }

  DLOAD(0);
  DSTORE(0);
  __syncthreads();

  for (int c = 0; c < 64; ++c) {
    int cur = c & 1, nxt = cur ^ 1;
    int cn = (c + 1 < 64) ? c + 1 : 63;
    DLOAD(cn);  // HBM/L2 latency hides under P1
    // ---- P1: Rtmp (threads 0-127), Y0 (threads 128-255), qz (threads 0-31) ----
    if (tid < 128) {
      int s = tid >> 2, i = tid & 3;
      float aK = 0.f;
#pragma unroll
      for (int j4 = 0; j4 < 16; ++j4)
        aK += dot4(*(float4*)&Kl[cur][s * 68 + j4 * 4], *(float4*)&S0l[i * 68 + j4 * 4]);
      Rtl[i * 36 + s] = bll[cur][s] * (Vl[cur][s * 5 + i] - aK);
    } else {
      int t = (tid >> 2) & 31, i = tid & 3;
      float aY = 0.f;
#pragma unroll
      for (int j4 = 0; j4 < 16; ++j4)
        aY += dot4(*(float4*)&Ql[cur][t * 68 + j4 * 4], *(float4*)&S0l[i * 68 + j4 * 4]);
      Y0l[t * 5 + i] = aY;
    }
    if (tid < 32) {
      float a = 0.f;
#pragma unroll
      for (int j4 = 0; j4 < 16; ++j4)
        a += dot4(*(float4*)&Ql[cur][tid * 68 + j4 * 4], *(float4*)&z0l[j4 * 4]);
      qzl[tid] = a;
    }
    __syncthreads();
    // ---- P2: S update (all), y out (0-127), z (128-191), stage (all) ----
    {
      int i2 = tid >> 6, j = tid & 63;
      float a = S0l[i2 * 68 + j];
#pragma unroll
      for (int s4i = 0; s4i < 8; ++s4i) {
        float4 rt = *(float4*)&Rtl[i2 * 36 + s4i * 4];
        a += rt.x * MKl[cur][(s4i * 4 + 0) * 68 + j]
           + rt.y * MKl[cur][(s4i * 4 + 1) * 68 + j]
           + rt.z * MKl[cur][(s4i * 4 + 2) * 68 + j]
           + rt.w * MKl[cur][(s4i * 4 + 3) * 68 + j];
      }
      S0l[i2 * 68 + j] = a;
    }
    if (tid < 128) {
      int t = tid >> 2, i = tid & 3;
      float acc = Y0l[t * 5 + i];
#pragma unroll
      for (int s4i = 0; s4i < 8; ++s4i)
        acc += dot4(*(float4*)&BqMl[cur][t * 36 + s4i * 4], *(float4*)&Rtl[i * 36 + s4i * 4]);
      float y = acc / (qzl[t] + dnl[cur][t] + 1e-6f);
      ys[(size_t)(b * L_ + c * 32 + t) * 1024 + h * 64 + i0 + i] = y;
    } else if (tid < 192) {
      int j = tid - 128;
      z0l[j] += zil[cur][j];
    }
    DSTORE(nxt);
    __syncthreads();
  }
#undef DLOAD
#undef DSTORE
  {
    int i = tid >> 6, j = tid & 63;
    outS[((size_t)(bh * 64) + i0 + i) * 64 + j] = S0l[i * 68 + j];
  }
  if (grp == 0 && tid < 64) outZ[bh * 64 + tid] = z0l[tid];
}

extern "C" void kernel_launch(void* const* d_in, const int* in_sizes, int n_in,
                              void* d_out, int out_size, void* d_ws, size_t ws_size,
                              hipStream_t stream) {
  const float* x     = (const float*)d_in[0];
  const float* Wqkv  = (const float*)d_in[1];
  const float* Wout  = (const float*)d_in[2];
  const float* Wgate = (const float*)d_in[3];
  const float* bgate = (const float*)d_in[4];
  const float* fn_g  = (const float*)d_in[5];
  const float* fn_b  = (const float*)d_in[6];
  const float* dn_g  = (const float*)d_in[7];
  const float* dn_b  = (const float*)d_in[8];
  const float* dWq   = (const float*)d_in[9];
  const float* dWk   = (const float*)d_in[10];
  const float* dWv   = (const float*)d_in[11];
  const float* dWo   = (const float*)d_in[12];
  const float* Wbeta = (const float*)d_in[13];
  const float* bbeta = (const float*)d_in[14];
  const float* cq_w  = (const float*)d_in[15];
  const float* cq_b  = (const float*)d_in[16];
  const float* ck_w  = (const float*)d_in[17];
  const float* ck_b  = (const float*)d_in[18];
  const float* ln_g  = (const float*)d_in[19];
  const float* ln_b  = (const float*)d_in[20];

  float* ws = (float*)d_ws;
  short* qkvh   = (short*)ws;      // [0,6.3M floats) as bf16; dead after attn
  float* dv     = ws;              // [0,4M)  after attn
  float* dqc    = ws + 4194304;    // [4M,8M)   after attn
  float* dkc    = ws + 8388608;    // [8M,12M)  after attn (written by convnorm)
  float* attnO  = ws + 12582912;   // [12M,16M)
  short* wtg    = (short*)(ws + 12582912); // [12M,12.5M) after attnO dead
  short* Wvt    = (short*)(ws + 14680064); // [14M,14.5M) dead after gemm_bt2
  float* denB_g = ws + 12582912;   // [12M,+64K) prep output (after wtg dead)
  float* zinc_g = ws + 12582912 + 65536;   // [+64K,+192K)
  float* BqM_g  = ws + 14680064;   // [14M,16M) prep output (after Wvt dead)
  float* do1    = ws + 12582912;   // after delta (denB/zinc dead)
  float* fo     = ws + 16777216;   // [16M,20M)
  float* dqp    = ws + 20971520;   // [20M,24M)
  float* gpre   = ws + 20971520;
  float* dkp    = ws + 25165824;   // [24M,28M) dead after convnorm
  float* MK_g   = ws + 25165824;   // [24M,28M) prep output (reuses dkp)
  float* betab  = ws + 29360128;   // [28M,+64K floats)

  short* Wqkvt = (short*)(ws + 20971520); // [20M,21.57M); dead after gemm_bt_h
  short* Woutt = (short*)(ws + 29426688); // [28M+64K, +0.5M)
  short* Wot   = (short*)(ws + 4194304);  // dqc dead after delta

  // split-precision dWq/dWk (bf16 hi/lo) @ [8M,10M) floats; live only for gemm_bt_split2
  short* Wqh = (short*)(ws + 8388608);   // [8.0M, 8.5M)
  short* Wql = (short*)(ws + 8912896);   // [8.5M, 9.0M)
  short* Wkh = (short*)(ws + 9437184);   // [9.0M, 9.5M)
  short* Wkl = (short*)(ws + 9961472);   // [9.5M,10.0M)

  float* out  = (float*)d_out;
  float* outS = out + 4194304;
  float* outZ = out + 4325376;
  float* ysb  = out;               // ys lives in d_out[0,4M): consumed by gemm_bt -> do1,
                                   // then ln2mix overwrites out (after reading do1). No alias hazard.

  // ---- flash branch ----
  tcast<<<dim3(48, 16), 256, 0, stream>>>(Wqkv, Wqkvt, 3072, 1024);          // Wqkvt@[20M); dqp written later
  gemm_bt_h<<<dim3(24, 32), 256, 0, stream>>>(x, Wqkvt, qkvh, 3072, 1024);   // qkv bf16 @[0,6.3M)
  attn_mfma<<<dim3(32, H_, B_), 256, 0, stream>>>(qkvh, attnO);
  tcast<<<dim3(16, 16), 256, 0, stream>>>(Wout, Woutt, 1024, 1024);          // Woutt@[28M+64K)
  gemm_bt<64><<<dim3(16, 32), 256, 0, stream>>>(attnO, Woutt, fo, 1024, 1024);
  ln_kernel<<<4096, 256, 0, stream>>>(fo, fn_g, fn_b);
  // ---- delta branch ----
  tcast_split2<<<dim3(16, 16, 2), 256, 0, stream>>>(dWq, dWk, Wqh, Wql, Wkh, Wkl);
  gemm_bt_split2<<<dim3(16, 32, 2), 256, 0, stream>>>(x, Wqh, Wql, Wkh, Wkl, dqp, dkp); // kills Wqkvt
  convnorm_kernel<<<dim3(16384, 2), 256, 0, stream>>>(dqp, dkp, cq_w, cq_b, ck_w, ck_b, dqc, dkc); // kills qkvh + split weights
  beta_kernel<<<4096, 256, 0, stream>>>(x, Wbeta, bbeta, betab);
  tcast2<<<dim3(16, 16, 2), 256, 0, stream>>>(dWv, Wgate, Wvt, wtg);         // attnO dead; Wvt@14M, wtg@12M
  gemm_bt2<<<dim3(16, 32, 2), 256, 0, stream>>>(x, Wvt, wtg, dv, gpre);      // gpre kills dqp (dead)
  prep_kernel<<<dim3(64, 32), 256, 0, stream>>>(dqc, dkc, betab, MK_g, BqM_g, denB_g, zinc_g); // kills wtg/Wvt/dkp
  delta_kernel<<<512, 256, 0, stream>>>(dqc, dkc, dv, betab, MK_g, BqM_g, denB_g, zinc_g, ysb, outS, outZ);
  tcast<<<dim3(16, 16), 256, 0, stream>>>(dWo, Wot, 1024, 1024);             // dqc dead
  gemm_bt<64><<<dim3(16, 32), 256, 0, stream>>>(ysb, Wot, do1, 1024, 1024);  // do1 kills denB/zinc
  ln2mix_kernel<<<4096, 256, 0, stream>>>(do1, ln_g, ln_b, dn_g, dn_b, gpre, bgate, fo, out);
}

// Round 5
// 762.162 us; speedup vs baseline: 1.0379x; 1.0379x over previous
//
#include <hip/hip_runtime.h>
#include <hip/hip_bf16.h>

constexpr int B_ = 2, L_ = 2048, D_ = 1024, H_ = 16;

using bf16x8 = __attribute__((ext_vector_type(8))) short;
using f32x4  = __attribute__((ext_vector_type(4))) float;

__device__ __forceinline__ short f2b(float f) {
  union { float f; unsigned int u; } v; v.f = f;
  unsigned int r = (v.u + 0x7FFFu + ((v.u >> 16) & 1u)) >> 16;
  return (short)r;
}
__device__ __forceinline__ float b2f(unsigned short h) {
  union { unsigned int u; float f; } v; v.u = ((unsigned int)h) << 16; return v.f;
}
// split x into hi/lo bf16: x ~= hi + lo, |x - hi - lo| ~ 2^-18 |x|
__device__ __forceinline__ void split2(float x, float y, unsigned int& h, unsigned int& l) {
  unsigned short hx = (unsigned short)f2b(x), hy = (unsigned short)f2b(y);
  h = (unsigned int)hx | ((unsigned int)hy << 16);
  unsigned short lx = (unsigned short)f2b(x - b2f(hx)), ly = (unsigned short)f2b(y - b2f(hy));
  l = (unsigned int)lx | ((unsigned int)ly << 16);
}
__device__ __forceinline__ float dot4(float4 a, float4 b) {
  return a.x * b.x + a.y * b.y + a.z * b.z + a.w * b.w;
}

// ---------------- transpose+cast: W[K,N] fp32 -> Wt[N,K] bf16 ----------------
__global__ __launch_bounds__(256) void tcast(const float* __restrict__ W, short* __restrict__ Wt,
                                             int N, int K) {
  __shared__ float T[64][65];
  int n0 = blockIdx.x * 64, k0 = blockIdx.y * 64;
  int tid = threadIdx.x;
#pragma unroll
  for (int i = 0; i < 16; ++i) {
    int idx = i * 256 + tid;
    int r = idx >> 6, c = idx & 63;
    T[r][c] = W[(size_t)(k0 + r) * N + n0 + c];
  }
  __syncthreads();
#pragma unroll
  for (int i = 0; i < 16; ++i) {
    int idx = i * 256 + tid;
    int rr = idx >> 6, cc = idx & 63;
    Wt[(size_t)(n0 + rr) * K + k0 + cc] = f2b(T[cc][rr]);
  }
}

// two-weight tcast (1024x1024 each), blockIdx.z selects
__global__ __launch_bounds__(256) void tcast2(const float* __restrict__ W1, const float* __restrict__ W2,
                                              short* __restrict__ Wt1, short* __restrict__ Wt2) {
  __shared__ float T[64][65];
  const float* W = blockIdx.z ? W2 : W1;
  short* Wt = blockIdx.z ? Wt2 : Wt1;
  int n0 = blockIdx.x * 64, k0 = blockIdx.y * 64;
  int tid = threadIdx.x;
#pragma unroll
  for (int i = 0; i < 16; ++i) {
    int idx = i * 256 + tid;
    int r = idx >> 6, c = idx & 63;
    T[r][c] = W[(size_t)(k0 + r) * 1024 + n0 + c];
  }
  __syncthreads();
#pragma unroll
  for (int i = 0; i < 16; ++i) {
    int idx = i * 256 + tid;
    int rr = idx >> 6, cc = idx & 63;
    Wt[(size_t)(n0 + rr) * 1024 + k0 + cc] = f2b(T[cc][rr]);
  }
}

// two-weight split tcast: W[K,N] fp32 -> (Wh,Wl)[N,K] bf16 hi/lo pair, z selects weight
__global__ __launch_bounds__(256) void tcast_split2(const float* __restrict__ W1, const float* __restrict__ W2,
                                                    short* __restrict__ Wh1, short* __restrict__ Wl1,
                                                    short* __restrict__ Wh2, short* __restrict__ Wl2) {
  __shared__ float T[64][65];
  const float* W = blockIdx.z ? W2 : W1;
  short* Wh = blockIdx.z ? Wh2 : Wh1;
  short* Wl = blockIdx.z ? Wl2 : Wl1;
  int n0 = blockIdx.x * 64, k0 = blockIdx.y * 64;
  int tid = threadIdx.x;
#pragma unroll
  for (int i = 0; i < 16; ++i) {
    int idx = i * 256 + tid;
    int r = idx >> 6, c = idx & 63;
    T[r][c] = W[(size_t)(k0 + r) * 1024 + n0 + c];
  }
  __syncthreads();
#pragma unroll
  for (int i = 0; i < 16; ++i) {
    int idx = i * 256 + tid;
    int rr = idx >> 6, cc = idx & 63;
    float w = T[cc][rr];
    short h = f2b(w);
    short l = f2b(w - b2f((unsigned short)h));
    size_t o = (size_t)(n0 + rr) * 1024 + k0 + cc;
    Wh[o] = h;
    Wl[o] = l;
  }
}

// ---------------- MFMA GEMM core (shared) ----------------
template <int BN, typename CT>
__device__ __forceinline__ void gemm_bt_body(const float* __restrict__ A, const short* __restrict__ Wt,
                                             CT* __restrict__ C, int N, int K, int bx, int by) {
  constexpr int MT = (BN == 128) ? 4 : 2;
  constexpr int NT = 4;
  __shared__ __align__(16) short As[128 * 32];
  __shared__ __align__(16) short Bs[BN * 32];
  int tid = threadIdx.x;
  int wave = tid >> 6, lane = tid & 63, quad = lane >> 4, l15 = lane & 15;
  int m0 = by * 128, n0 = bx * BN;
  int wm = (BN == 128) ? (wave >> 1) * 64 : wave * 32;
  int wn = (BN == 128) ? (wave & 1) * 64 : 0;
  f32x4 acc[MT][NT];
#pragma unroll
  for (int mt = 0; mt < MT; ++mt)
#pragma unroll
    for (int nt = 0; nt < NT; ++nt) acc[mt][nt] = (f32x4){0.f, 0.f, 0.f, 0.f};

  for (int k0 = 0; k0 < K; k0 += 32) {
    __syncthreads();
#pragma unroll
    for (int i = 0; i < 2; ++i) {
      int chunk = i * 256 + tid;
      int m = chunk >> 2, kc = (chunk & 3) * 8;
      const float* ap = A + (size_t)(m0 + m) * K + k0 + kc;
      float4 a0 = *(const float4*)ap;
      float4 a1 = *(const float4*)(ap + 4);
      __hip_bfloat162 c0 = __float22bfloat162_rn(make_float2(a0.x, a0.y));
      __hip_bfloat162 c1 = __float22bfloat162_rn(make_float2(a0.z, a0.w));
      __hip_bfloat162 c2 = __float22bfloat162_rn(make_float2(a1.x, a1.y));
      __hip_bfloat162 c3 = __float22bfloat162_rn(make_float2(a1.z, a1.w));
      uint4 u;
      u.x = *(unsigned int*)&c0; u.y = *(unsigned int*)&c1;
      u.z = *(unsigned int*)&c2; u.w = *(unsigned int*)&c3;
      *(uint4*)&As[m * 32 + kc] = u;
    }
#pragma unroll
    for (int i = 0; i < BN * 4 / 256; ++i) {
      int chunk = i * 256 + tid;
      int n = chunk >> 2, kc = (chunk & 3) * 8;
      uint4 w = *(const uint4*)(Wt + (size_t)(n0 + n) * K + k0 + kc);
      *(uint4*)&Bs[n * 32 + kc] = w;
    }
    __syncthreads();
    bf16x8 af[MT], bf[NT];
#pragma unroll
    for (int mt = 0; mt < MT; ++mt) af[mt] = *(bf16x8*)&As[(wm + mt * 16 + l15) * 32 + quad * 8];
#pragma unroll
    for (int nt = 0; nt < NT; ++nt) bf[nt] = *(bf16x8*)&Bs[(wn + nt * 16 + l15) * 32 + quad * 8];
#pragma unroll
    for (int mt = 0; mt < MT; ++mt)
#pragma unroll
      for (int nt = 0; nt < NT; ++nt)
        acc[mt][nt] = __builtin_amdgcn_mfma_f32_16x16x32_bf16(af[mt], bf[nt], acc[mt][nt], 0, 0, 0);
  }
#pragma unroll
  for (int mt = 0; mt < MT; ++mt)
#pragma unroll
    for (int nt = 0; nt < NT; ++nt)
#pragma unroll
      for (int r = 0; r < 4; ++r) {
        size_t idx = (size_t)(m0 + wm + mt * 16 + quad * 4 + r) * N + n0 + wn + nt * 16 + l15;
        if constexpr (sizeof(CT) == 2) C[idx] = f2b(acc[mt][nt][r]);
        else C[idx] = acc[mt][nt][r];
      }
}

template <int BN>
__global__ __launch_bounds__(256) void gemm_bt(const float* __restrict__ A, const short* __restrict__ Wt,
                                               float* __restrict__ C, int N, int K) {
  gemm_bt_body<BN, float>(A, Wt, C, N, K, blockIdx.x, blockIdx.y);
}

// bf16-output variant (for qkv)
__global__ __launch_bounds__(256) void gemm_bt_h(const float* __restrict__ A, const short* __restrict__ Wt,
                                                 short* __restrict__ C, int N, int K) {
  gemm_bt_body<128, short>(A, Wt, C, N, K, blockIdx.x, blockIdx.y);
}

// two-GEMM variant: z selects (Wt1->C1) vs (Wt2->C2), 1024x1024
__global__ __launch_bounds__(256) void gemm_bt2(const float* __restrict__ A, const short* __restrict__ Wt1,
                                                const short* __restrict__ Wt2, float* __restrict__ C1,
                                                float* __restrict__ C2) {
  gemm_bt_body<64, float>(A, blockIdx.z ? Wt2 : Wt1, blockIdx.z ? C2 : C1, 1024, 1024,
                          blockIdx.x, blockIdx.y);
}

// ---------------- split-precision MFMA GEMM: C = A@W with ~fp32 accuracy ----------------
__global__ __launch_bounds__(256) void gemm_bt_split2(const float* __restrict__ A,
                                                      const short* __restrict__ Wh1, const short* __restrict__ Wl1,
                                                      const short* __restrict__ Wh2, const short* __restrict__ Wl2,
                                                      float* __restrict__ C1, float* __restrict__ C2) {
  constexpr int K = 1024, N = 1024;
  const short* Wh = blockIdx.z ? Wh2 : Wh1;
  const short* Wl = blockIdx.z ? Wl2 : Wl1;
  float* C = blockIdx.z ? C2 : C1;
  __shared__ __align__(16) short Ash[128 * 32];
  __shared__ __align__(16) short Asl[128 * 32];
  __shared__ __align__(16) short Bsh[64 * 32];
  __shared__ __align__(16) short Bsl[64 * 32];
  int tid = threadIdx.x;
  int wave = tid >> 6, lane = tid & 63, quad = lane >> 4, l15 = lane & 15;
  int m0 = blockIdx.y * 128, n0 = blockIdx.x * 64;
  int wm = wave * 32;
  f32x4 acc[2][4];
#pragma unroll
  for (int mt = 0; mt < 2; ++mt)
#pragma unroll
    for (int nt = 0; nt < 4; ++nt) acc[mt][nt] = (f32x4){0.f, 0.f, 0.f, 0.f};

  for (int k0 = 0; k0 < K; k0 += 32) {
    __syncthreads();
#pragma unroll
    for (int i = 0; i < 2; ++i) {
      int chunk = i * 256 + tid;
      int m = chunk >> 2, kc = (chunk & 3) * 8;
      const float* ap = A + (size_t)(m0 + m) * K + k0 + kc;
      float4 a0 = *(const float4*)ap;
      float4 a1 = *(const float4*)(ap + 4);
      uint4 uh, ul;
      split2(a0.x, a0.y, uh.x, ul.x);
      split2(a0.z, a0.w, uh.y, ul.y);
      split2(a1.x, a1.y, uh.z, ul.z);
      split2(a1.z, a1.w, uh.w, ul.w);
      *(uint4*)&Ash[m * 32 + kc] = uh;
      *(uint4*)&Asl[m * 32 + kc] = ul;
    }
    {
      int n = tid >> 2, kc = (tid & 3) * 8;
      size_t off = (size_t)(n0 + n) * K + k0 + kc;
      *(uint4*)&Bsh[n * 32 + kc] = *(const uint4*)(Wh + off);
      *(uint4*)&Bsl[n * 32 + kc] = *(const uint4*)(Wl + off);
    }
    __syncthreads();
    bf16x8 ah[2], al[2], bh[4], bl[4];
#pragma unroll
    for (int mt = 0; mt < 2; ++mt) {
      ah[mt] = *(bf16x8*)&Ash[(wm + mt * 16 + l15) * 32 + quad * 8];
      al[mt] = *(bf16x8*)&Asl[(wm + mt * 16 + l15) * 32 + quad * 8];
    }
#pragma unroll
    for (int nt = 0; nt < 4; ++nt) {
      bh[nt] = *(bf16x8*)&Bsh[(nt * 16 + l15) * 32 + quad * 8];
      bl[nt] = *(bf16x8*)&Bsl[(nt * 16 + l15) * 32 + quad * 8];
    }
#pragma unroll
    for (int mt = 0; mt < 2; ++mt)
#pragma unroll
      for (int nt = 0; nt < 4; ++nt) {
        f32x4 a = acc[mt][nt];
        a = __builtin_amdgcn_mfma_f32_16x16x32_bf16(al[mt], bh[nt], a, 0, 0, 0);
        a = __builtin_amdgcn_mfma_f32_16x16x32_bf16(ah[mt], bl[nt], a, 0, 0, 0);
        a = __builtin_amdgcn_mfma_f32_16x16x32_bf16(ah[mt], bh[nt], a, 0, 0, 0);
        acc[mt][nt] = a;
      }
  }
#pragma unroll
  for (int mt = 0; mt < 2; ++mt)
#pragma unroll
    for (int nt = 0; nt < 4; ++nt)
#pragma unroll
      for (int r = 0; r < 4; ++r) {
        size_t idx = (size_t)(m0 + wm + mt * 16 + quad * 4 + r) * N + n0 + nt * 16 + l15;
        C[idx] = acc[mt][nt][r];
      }
}

// ---------------- MFMA bf16 causal flash attention (bf16 qkv input) ----------------
__global__ __launch_bounds__(256) void attn_mfma(const short* __restrict__ qkv, float* __restrict__ outp) {
  __shared__ __align__(16) short Kl[64 * 64];
  __shared__ __align__(16) short Vt[64 * 64];
  __shared__ __align__(16) short Pl[64 * 64];
  int qb = 31 - blockIdx.x, h = blockIdx.y, b = blockIdx.z;
  int tid = threadIdx.x;
  int wave = tid >> 6, lane = tid & 63;
  int quad = lane >> 4, l15 = lane & 15;
  int qrow = qb * 64 + wave * 16 + l15;
  bf16x8 qf[2];
  {
    const short* qbase = qkv + (size_t)(b * L_ + qrow) * 3072 + h * 64;
#pragma unroll
    for (int s = 0; s < 2; ++s) qf[s] = *(const bf16x8*)(qbase + s * 32 + quad * 8);
  }
  f32x4 Of[4];
  float mrow[4], lrow[4], alpha[4];
#pragma unroll
  for (int dt = 0; dt < 4; ++dt) Of[dt] = (f32x4){0.f, 0.f, 0.f, 0.f};
#pragma unroll
  for (int r = 0; r < 4; ++r) { mrow[r] = -1e30f; lrow[r] = 0.f; }

  for (int kt = 0; kt <= qb; ++kt) {
    __syncthreads();
#pragma unroll
    for (int it = 0; it < 2; ++it) {
      int e8 = tid + it * 256;
      int key = e8 >> 3, g = e8 & 7;
      const short* src = qkv + ((size_t)((b * L_ + kt * 64 + key) * 3) + 1) * 1024 + h * 64 + g * 8;
      *(bf16x8*)&Kl[key * 64 + ((g ^ (key & 7)) << 3)] = *(const bf16x8*)src;
    }
    {
      int key4 = tid >> 4;
      int d4 = tid & 15;
      const short* vsrc = qkv + ((size_t)((b * L_ + kt * 64 + key4 * 4) * 3) + 2) * 1024 + h * 64 + d4 * 4;
      short4 v0 = *(const short4*)vsrc;
      short4 v1 = *(const short4*)(vsrc + 3072);
      short4 v2 = *(const short4*)(vsrc + 6144);
      short4 v3 = *(const short4*)(vsrc + 9216);
      short vr0[4] = {v0.x, v0.y, v0.z, v0.w};
      short vr1[4] = {v1.x, v1.y, v1.z, v1.w};
      short vr2[4] = {v2.x, v2.y, v2.z, v2.w};
      short vr3[4] = {v3.x, v3.y, v3.z, v3.w};
      int kg = key4 >> 1, k7b = (key4 & 1) * 4;
#pragma unroll
      for (int jj = 0; jj < 4; ++jj) {
        int d = d4 * 4 + jj;
        short4 sv;
        sv.x = vr0[jj]; sv.y = vr1[jj]; sv.z = vr2[jj]; sv.w = vr3[jj];
        *(short4*)&Vt[d * 64 + ((kg ^ (d & 7)) << 3) + k7b] = sv;
      }
    }
    __syncthreads();
    f32x4 sc[4];
#pragma unroll
    for (int nt = 0; nt < 4; ++nt) sc[nt] = (f32x4){0.f, 0.f, 0.f, 0.f};
#pragma unroll
    for (int s = 0; s < 2; ++s) {
#pragma unroll
      for (int nt = 0; nt < 4; ++nt) {
        int key = nt * 16 + l15;
        bf16x8 kf = *(bf16x8*)&Kl[key * 64 + (((4 * s + quad) ^ (key & 7)) << 3)];
        sc[nt] = __builtin_amdgcn_mfma_f32_16x16x32_bf16(qf[s], kf, sc[nt], 0, 0, 0);
      }
    }
    bool diag = (kt == qb);
#pragma unroll
    for (int r = 0; r < 4; ++r) {
      float sv[4];
#pragma unroll
      for (int nt = 0; nt < 4; ++nt) {
        float v = sc[nt][r] * 0.125f;
        if (diag && (nt * 16 + l15 > wave * 16 + quad * 4 + r)) v = -1e30f;
        sv[nt] = v;
      }
      float mx = fmaxf(fmaxf(sv[0], sv[1]), fmaxf(sv[2], sv[3]));
      mx = fmaxf(mx, __shfl_xor(mx, 1));
      mx = fmaxf(mx, __shfl_xor(mx, 2));
      mx = fmaxf(mx, __shfl_xor(mx, 4));
      mx = fmaxf(mx, __shfl_xor(mx, 8));
      float mnew = fmaxf(mrow[r], mx);
      float al = __expf(mrow[r] - mnew);
      mrow[r] = mnew;
      alpha[r] = al;
      int prow = wave * 16 + quad * 4 + r;
      int r7 = prow & 7;
      float ps = 0.f;
#pragma unroll
      for (int nt = 0; nt < 4; ++nt) {
        float p = __expf(sv[nt] - mnew);
        ps += p;
        Pl[prow * 64 + ((((nt << 1) + (l15 >> 3)) ^ r7) << 3) + (l15 & 7)] = f2b(p);
      }
      ps += __shfl_xor(ps, 1);
      ps += __shfl_xor(ps, 2);
      ps += __shfl_xor(ps, 4);
      ps += __shfl_xor(ps, 8);
      lrow[r] = lrow[r] * al + ps;
    }
#pragma unroll
    for (int dt = 0; dt < 4; ++dt)
#pragma unroll
      for (int r = 0; r < 4; ++r) Of[dt][r] *= alpha[r];
#pragma unroll
    for (int s = 0; s < 2; ++s) {
      bf16x8 pf = *(bf16x8*)&Pl[(wave * 16 + l15) * 64 + (((4 * s + quad) ^ (l15 & 7)) << 3)];
#pragma unroll
      for (int dt = 0; dt < 4; ++dt) {
        int d = dt * 16 + l15;
        bf16x8 vf = *(bf16x8*)&Vt[d * 64 + (((4 * s + quad) ^ (d & 7)) << 3)];
        Of[dt] = __builtin_amdgcn_mfma_f32_16x16x32_bf16(pf, vf, Of[dt], 0, 0, 0);
      }
    }
  }
#pragma unroll
  for (int r = 0; r < 4; ++r) alpha[r] = 1.f / lrow[r];
  int orow = qb * 64 + wave * 16 + quad * 4;
#pragma unroll
  for (int dt = 0; dt < 4; ++dt)
#pragma unroll
    for (int r = 0; r < 4; ++r)
      outp[(size_t)(b * L_ + orow + r) * 1024 + h * 64 + dt * 16 + l15] = Of[dt][r] * alpha[r];
}

// ---------------- layernorm over last dim D=1024, in place ----------------
__global__ __launch_bounds__(256) void ln_kernel(float* __restrict__ X, const float* __restrict__ g,
                                                 const float* __restrict__ bb) {
  int row = blockIdx.x, tid = threadIdx.x;
  float* xr = X + (size_t)row * D_;
  float v[4], s = 0.f, ss = 0.f;
#pragma unroll
  for (int i = 0; i < 4; ++i) { v[i] = xr[tid + i * 256]; s += v[i]; ss += v[i] * v[i]; }
#pragma unroll
  for (int off = 32; off; off >>= 1) { s += __shfl_xor(s, off); ss += __shfl_xor(ss, off); }
  __shared__ float rs[4], rss[4];
  if ((tid & 63) == 0) { rs[tid >> 6] = s; rss[tid >> 6] = ss; }
  __syncthreads();
  float S = rs[0] + rs[1] + rs[2] + rs[3];
  float SS = rss[0] + rss[1] + rss[2] + rss[3];
  float mean = S * (1.f / 1024.f);
  float var = SS * (1.f / 1024.f) - mean * mean;
  float inv = rsqrtf(var + 1e-5f);
#pragma unroll
  for (int i = 0; i < 4; ++i) {
    int c = tid + i * 256;
    xr[c] = (v[i] - mean) * inv * g[c] + bb[c];
  }
}

// ---------------- fused: LN -> LN -> gate mix ----------------
__global__ __launch_bounds__(256) void ln2mix_kernel(const float* __restrict__ X,
                                                     const float* __restrict__ g1, const float* __restrict__ b1,
                                                     const float* __restrict__ g2, const float* __restrict__ b2,
                                                     const float* __restrict__ gpre, const float* __restrict__ bgate,
                                                     const float* __restrict__ fo, float* __restrict__ outp) {
  int row = blockIdx.x, tid = threadIdx.x;
  const float* xr = X + (size_t)row * D_;
  __shared__ float rs[4], rss[4];
  float v[4], s = 0.f, ss = 0.f;
#pragma unroll
  for (int i = 0; i < 4; ++i) { v[i] = xr[tid + i * 256]; s += v[i]; ss += v[i] * v[i]; }
#pragma unroll
  for (int off = 32; off; off >>= 1) { s += __shfl_xor(s, off); ss += __shfl_xor(ss, off); }
  if ((tid & 63) == 0) { rs[tid >> 6] = s; rss[tid >> 6] = ss; }
  __syncthreads();
  float S = rs[0] + rs[1] + rs[2] + rs[3];
  float SS = rss[0] + rss[1] + rss[2] + rss[3];
  float mean = S * (1.f / 1024.f);
  float var = SS * (1.f / 1024.f) - mean * mean;
  float inv = rsqrtf(var + 1e-5f);
  s = 0.f; ss = 0.f;
#pragma unroll
  for (int i = 0; i < 4; ++i) {
    int c = tid + i * 256;
    v[i] = (v[i] - mean) * inv * g1[c] + b1[c];
    s += v[i]; ss += v[i] * v[i];
  }
#pragma unroll
  for (int off = 32; off; off >>= 1) { s += __shfl_xor(s, off); ss += __shfl_xor(ss, off); }
  __syncthreads();
  if ((tid & 63) == 0) { rs[tid >> 6] = s; rss[tid >> 6] = ss; }
  __syncthreads();
  S = rs[0] + rs[1] + rs[2] + rs[3];
  SS = rss[0] + rss[1] + rss[2] + rss[3];
  mean = S * (1.f / 1024.f);
  var = SS * (1.f / 1024.f) - mean * mean;
  inv = rsqrtf(var + 1e-5f);
#pragma unroll
  for (int i = 0; i < 4; ++i) {
    int c = tid + i * 256;
    size_t idx = (size_t)row * D_ + c;
    float w = (v[i] - mean) * inv * g2[c] + b2[c];
    float gg = 1.f / (1.f + __expf(-(gpre[idx] + bgate[c])));
    outp[idx] = gg * fo[idx] + (1.f - gg) * w;
  }
}

// ---------------- fused conv (q) / conv+L2norm (k) ----------------
__global__ __launch_bounds__(256) void convnorm_kernel(const float* __restrict__ qin, const float* __restrict__ kin,
                                                       const float* __restrict__ qw, const float* __restrict__ qb,
                                                       const float* __restrict__ kw, const float* __restrict__ kb,
                                                       float* __restrict__ qout, float* __restrict__ kout) {
  int path = blockIdx.y;
  int row = blockIdx.x * 4 + (threadIdx.x >> 6);
  int lane = threadIdx.x & 63;
  int bl = row >> 4, h = row & 15;
  int t = bl & (L_ - 1);
  int d = h * 64 + lane;
  size_t idx = (size_t)bl * D_ + d;
  const float* xin = path ? kin : qin;
  const float* w = path ? kw : qw;
  const float* bias = path ? kb : qb;
  float acc = bias[d];
#pragma unroll
  for (int j = 0; j < 4; ++j) {
    int tt = t - 3 + j;
    if (tt >= 0) acc += w[d * 4 + j] * xin[idx + (size_t)(j - 3) * D_];
  }
  if (path) {
    float n2 = acc * acc;
#pragma unroll
    for (int off = 32; off; off >>= 1) n2 += __shfl_xor(n2, off);
    acc = acc / fmaxf(sqrtf(n2), 1e-12f);
    kout[idx] = acc;
  } else {
    qout[idx] = acc;
  }
}

// ---------------- beta = sigmoid(x @ Wbeta + bbeta) ----------------
__global__ __launch_bounds__(256) void beta_kernel(const float* __restrict__ xf, const float* __restrict__ Wb,
                                                   const float* __restrict__ bb, float* __restrict__ beta) {
  int row = blockIdx.x, tid = threadIdx.x;
  int h = tid & 15, seg = tid >> 4;
  const float* xr = xf + (size_t)row * D_ + seg * 64;
  const float* wp = Wb + (seg * 64) * H_ + h;
  float p = 0.f;
  for (int k = 0; k < 64; ++k) p += xr[k] * wp[k * H_];
  __shared__ float red[16][17];
  red[seg][h] = p;
  __syncthreads();
  if (tid < 16) {
    float s = bb[tid];
#pragma unroll
    for (int s2 = 0; s2 < 16; ++s2) s += red[s2][tid];
    beta[(size_t)row * H_ + tid] = 1.f / (1.f + __expf(-s));
  }
}

// ================= chunked delta scan =================
// prep hoists the Minv applications:
//   MK  = Minv^T @ K   (32x64)   BqM = Bq @ Minv (32x32, strictly lower)
//   denB[t] = sum_s Bq[t][s] beta[s]   zinc[j] = sum_s beta[s] K[s][j]
__global__ __launch_bounds__(256) void prep_kernel(const float* __restrict__ dq, const float* __restrict__ dk,
                                                   const float* __restrict__ beta,
                                                   float* __restrict__ MK_g, float* __restrict__ BqM_g,
                                                   float* __restrict__ denB_g, float* __restrict__ zinc_g) {
  __shared__ __align__(16) float Kl[32 * 68];
  __shared__ __align__(16) float Ql[32 * 68];
  __shared__ __align__(16) float Ml[32 * 36];
  __shared__ __align__(16) float Xl[32 * 36];
  __shared__ __align__(16) float Bql[32 * 36];
  __shared__ __align__(16) float bl[32];
  int c = blockIdx.x, bh = blockIdx.y;
  int b = bh >> 4, h = bh & 15;
  int t0 = c * 32;
  int tid = threadIdx.x;
#pragma unroll
  for (int rep = 0; rep < 2; ++rep) {
    int id = tid * 2 + rep;
    int r = id >> 4, j4 = id & 15;
    size_t gi = (size_t)(b * L_ + t0 + r) * 1024 + h * 64 + j4 * 4;
    *(float4*)&Kl[r * 68 + j4 * 4] = *(const float4*)&dk[gi];
    *(float4*)&Ql[r * 68 + j4 * 4] = *(const float4*)&dq[gi];
  }
  if (tid < 32) bl[tid] = beta[(size_t)(b * L_ + t0 + tid) * 16 + h];
  __syncthreads();
  int t = tid >> 3, s0 = (tid & 7) * 4;
  float accA[4] = {0.f, 0.f, 0.f, 0.f}, accB[4] = {0.f, 0.f, 0.f, 0.f};
#pragma unroll
  for (int k4 = 0; k4 < 16; ++k4) {
    float4 kt = *(float4*)&Kl[t * 68 + k4 * 4];
    float4 qt = *(float4*)&Ql[t * 68 + k4 * 4];
#pragma unroll
    for (int j = 0; j < 4; ++j) {
      float4 ks = *(float4*)&Kl[(s0 + j) * 68 + k4 * 4];
      accA[j] += dot4(kt, ks);
      accB[j] += dot4(qt, ks);
    }
  }
#pragma unroll
  for (int j = 0; j < 4; ++j) {
    int s = s0 + j;
    Ml[t * 36 + s] = (s < t) ? bl[t] * accA[j] : ((s == t) ? 1.f : 0.f);
    Bql[t * 36 + s] = (s < t) ? accB[j] : 0.f;
  }
  __syncthreads();
  if (tid < 32) {
    int col = tid;
    float xr[32];
#pragma unroll
    for (int tt = 0; tt < 32; ++tt) {
      float x = (tt == col) ? 1.f : 0.f;
#pragma unroll
      for (int s = 0; s < tt; ++s) x -= Ml[tt * 36 + s] * xr[s];
      xr[tt] = x;
      Xl[tt * 36 + col] = x;
    }
  }
  __syncthreads();
  size_t cb = (size_t)(bh * 64 + c);
  // MK[s][j] = sum_t Minv[t][s] * K[t][j]
  {
    int s = tid >> 3, j8 = (tid & 7) * 8;
    float4 m0 = make_float4(0.f, 0.f, 0.f, 0.f);
    float4 m1 = make_float4(0.f, 0.f, 0.f, 0.f);
#pragma unroll
    for (int t2 = 0; t2 < 32; ++t2) {
      float xv = Xl[t2 * 36 + s];
      float4 k0 = *(float4*)&Kl[t2 * 68 + j8];
      float4 k1 = *(float4*)&Kl[t2 * 68 + j8 + 4];
      m0.x += xv * k0.x; m0.y += xv * k0.y; m0.z += xv * k0.z; m0.w += xv * k0.w;
      m1.x += xv * k1.x; m1.y += xv * k1.y; m1.z += xv * k1.z; m1.w += xv * k1.w;
    }
    float* mkp = MK_g + (cb * 32 + s) * 64 + j8;
    *(float4*)mkp = m0;
    *(float4*)(mkp + 4) = m1;
  }
  // BqM[t][s] = sum_u Bq[t][u] * Minv[u][s]
  {
    int tt = tid >> 3, s4 = (tid & 7) * 4;
    float4 acc = make_float4(0.f, 0.f, 0.f, 0.f);
#pragma unroll
    for (int u4 = 0; u4 < 8; ++u4) {
      float4 bq = *(float4*)&Bql[tt * 36 + u4 * 4];
      float4 x0 = *(float4*)&Xl[(u4 * 4 + 0) * 36 + s4];
      float4 x1 = *(float4*)&Xl[(u4 * 4 + 1) * 36 + s4];
      float4 x2 = *(float4*)&Xl[(u4 * 4 + 2) * 36 + s4];
      float4 x3 = *(float4*)&Xl[(u4 * 4 + 3) * 36 + s4];
      acc.x += bq.x * x0.x + bq.y * x1.x + bq.z * x2.x + bq.w * x3.x;
      acc.y += bq.x * x0.y + bq.y * x1.y + bq.z * x2.y + bq.w * x3.y;
      acc.z += bq.x * x0.z + bq.y * x1.z + bq.z * x2.z + bq.w * x3.z;
      acc.w += bq.x * x0.w + bq.y * x1.w + bq.z * x2.w + bq.w * x3.w;
    }
    *(float4*)&BqM_g[cb * 1024 + tt * 32 + s4] = acc;
  }
  if (tid < 32) {
    float a = 0.f;
#pragma unroll
    for (int s4i = 0; s4i < 8; ++s4i)
      a += dot4(*(float4*)&Bql[tid * 36 + s4i * 4], *(float4*)&bl[s4i * 4]);
    denB_g[cb * 32 + tid] = a;
  }
  if (tid >= 64 && tid < 128) {
    int j = tid - 64;
    float a = 0.f;
#pragma unroll
    for (int s = 0; s < 32; ++s) a += bl[s] * Kl[s * 68 + j];
    zinc_g[cb * 64 + j] = a;
  }
}

// 2-barrier/iter scan, LDS-traffic-minimized:
//  P1: j-slice split (32 rows x 8 slices); K/Q read once per thread; S/z broadcast;
//      shfl-reduce over 8 lanes -> Rtmp, Y0, qz.   (LDS-issue bound kernel: m4 model)
//  P2: threads 0-127 S-update (float2 cols) + z; threads 128-255 y-out concurrently.
__global__ __launch_bounds__(256) void delta_kernel(const float* __restrict__ dq, const float* __restrict__ dk,
                                                    const float* __restrict__ dv, const float* __restrict__ beta,
                                                    const float* __restrict__ MK_g, const float* __restrict__ BqM_g,
                                                    const float* __restrict__ denB_g, const float* __restrict__ zinc_g,
                                                    float* __restrict__ ys, float* __restrict__ outS,
                                                    float* __restrict__ outZ) {
  __shared__ __align__(16) float Kl[2][32 * 68];
  __shared__ __align__(16) float Ql[2][32 * 68];
  __shared__ __align__(16) float MKl[2][32 * 68];
  __shared__ __align__(16) float BqMl[2][32 * 36];
  __shared__ __align__(16) float Vl[2][32 * 5];
  __shared__ __align__(16) float bll[2][32];
  __shared__ __align__(16) float dnl[2][32];
  __shared__ __align__(16) float zil[2][64];
  __shared__ __align__(16) float S0l[4 * 68];
  __shared__ __align__(16) float Y0l[32 * 5];
  __shared__ __align__(16) float Rtl[4 * 36];
  __shared__ __align__(16) float z0l[64];
  __shared__ __align__(16) float qzl[32];
  int bh = blockIdx.x & 31, grp = blockIdx.x >> 5;  // same-bh groups share an XCD
  int b = bh >> 4, h = bh & 15;
  int i0 = grp * 4;
  int tid = threadIdx.x;
  int r = tid >> 3, j8 = (tid & 7) * 8;   // row / j-slice; used by staging AND P1
  int js = tid & 7;
  size_t kqbase = (size_t)(b * L_) * 1024 + h * 64;

  for (int e = tid; e < 4 * 68; e += 256) S0l[e] = 0.f;
  if (tid < 64) z0l[tid] = 0.f;

  float4 kA, kB, qA, qB, mA, mB, bqA, bqB;
  bqA = bqB = make_float4(0.f, 0.f, 0.f, 0.f);
  float vr = 0.f, blr = 0.f, dnb = 0.f, zi = 0.f;

#define DLOAD(CN) { \
    size_t rb_ = kqbase + (size_t)((CN) * 32 + r) * 1024 + j8; \
    kA = ((const float4*)(dk + rb_))[0]; kB = ((const float4*)(dk + rb_))[1]; \
    qA = ((const float4*)(dq + rb_))[0]; qB = ((const float4*)(dq + rb_))[1]; \
    size_t cb_ = (size_t)(bh * 64 + (CN)); \
    const float* mkp_ = MK_g + (cb_ * 32 + r) * 64 + j8; \
    mA = ((const float4*)mkp_)[0]; mB = ((const float4*)mkp_)[1]; \
    if (tid < 128) { \
      const float* bqp_ = BqM_g + cb_ * 1024 + (tid >> 2) * 32 + (tid & 3) * 8; \
      bqA = ((const float4*)bqp_)[0]; bqB = ((const float4*)bqp_)[1]; \
      vr = dv[(size_t)(b * L_ + (CN) * 32 + (tid >> 2)) * 1024 + h * 64 + i0 + (tid & 3)]; \
    } \
    if (tid < 32) { blr = beta[(size_t)(b * L_ + (CN) * 32 + tid) * 16 + h]; dnb = denB_g[cb_ * 32 + tid]; } \
    if (tid < 64) zi = zinc_g[cb_ * 64 + tid]; \
  }
#define DSTORE(NX) { \
    *(float4*)&Kl[NX][r * 68 + j8] = kA; *(float4*)&Kl[NX][r * 68 + j8 + 4] = kB; \
    *(float4*)&Ql[NX][r * 68 + j8] = qA; *(float4*)&Ql[NX][r * 68 + j8 + 4] = qB; \
    *(float4*)&MKl[NX][r * 68 + j8] = mA; *(float4*)&MKl[NX][r * 68 + j8 + 4] = mB; \
    if (tid < 128) { \
      int t_ = tid >> 2, s8_ = (tid & 3) * 8; \
      *(float4*)&BqMl[NX][t_ * 36 + s8_] = bqA; \
      *(float4*)&BqMl[NX][t_ * 36 + s8_ + 4] = bqB; \
      Vl[NX][t_ * 5 + (tid & 3)] = vr; \
    } \
    if (tid < 32) { bll[NX][tid] = blr; dnl[NX][tid] = dnb; } \
    if (tid < 64) zil[NX][tid] = zi; \
  }

  DLOAD(0);
  DSTORE(0);
  __syncthreads();

  for (int c = 0; c < 64; ++c) {
    int cur = c & 1, nxt = cur ^ 1;
    int cn = (c + 1 < 64) ? c + 1 : 63;
    DLOAD(cn);  // HBM/L2 latency hides under P1
    // ---- P1: each thread owns (row r, slice js); K/Q read ONCE; S/z broadcast ----
    {
      float4 k0 = *(float4*)&Kl[cur][r * 68 + j8];
      float4 k1 = *(float4*)&Kl[cur][r * 68 + j8 + 4];
      float4 q0 = *(float4*)&Ql[cur][r * 68 + j8];
      float4 q1 = *(float4*)&Ql[cur][r * 68 + j8 + 4];
      float aK[4], aY[4];
#pragma unroll
      for (int i = 0; i < 4; ++i) {
        float4 s0 = *(float4*)&S0l[i * 68 + j8];
        float4 s1 = *(float4*)&S0l[i * 68 + j8 + 4];
        aK[i] = dot4(k0, s0) + dot4(k1, s1);
        aY[i] = dot4(q0, s0) + dot4(q1, s1);
      }
      float4 z0 = *(float4*)&z0l[j8];
      float4 z1 = *(float4*)&z0l[j8 + 4];
      float aZ = dot4(q0, z0) + dot4(q1, z1);
#pragma unroll
      for (int off = 1; off <= 4; off <<= 1) {
#pragma unroll
        for (int i = 0; i < 4; ++i) {
          aK[i] += __shfl_xor(aK[i], off);
          aY[i] += __shfl_xor(aY[i], off);
        }
        aZ += __shfl_xor(aZ, off);
      }
      if (js == 0) {
        float be = bll[cur][r];
#pragma unroll
        for (int i = 0; i < 4; ++i) {
          Rtl[i * 36 + r] = be * (Vl[cur][r * 5 + i] - aK[i]);
          Y0l[r * 5 + i] = aY[i];
        }
        qzl[r] = aZ;
      }
    }
    __syncthreads();
    // ---- P2: S-update + z (threads 0-127) || y-out (threads 128-255) ----
    if (tid < 128) {
      int i2 = tid >> 5;
      int j2 = (tid & 31) * 2;
      float a0 = S0l[i2 * 68 + j2];
      float a1 = S0l[i2 * 68 + j2 + 1];
#pragma unroll
      for (int s4i = 0; s4i < 8; ++s4i) {
        float4 rt = *(float4*)&Rtl[i2 * 36 + s4i * 4];
        float2 m0 = *(float2*)&MKl[cur][(s4i * 4 + 0) * 68 + j2];
        float2 m1 = *(float2*)&MKl[cur][(s4i * 4 + 1) * 68 + j2];
        float2 m2 = *(float2*)&MKl[cur][(s4i * 4 + 2) * 68 + j2];
        float2 m3 = *(float2*)&MKl[cur][(s4i * 4 + 3) * 68 + j2];
        a0 += rt.x * m0.x + rt.y * m1.x + rt.z * m2.x + rt.w * m3.x;
        a1 += rt.x * m0.y + rt.y * m1.y + rt.z * m2.y + rt.w * m3.y;
      }
      S0l[i2 * 68 + j2] = a0;
      S0l[i2 * 68 + j2 + 1] = a1;
      if (tid < 64) z0l[tid] += zil[cur][tid];
    } else {
      int t = (tid >> 2) & 31;
      int i = tid & 3;
      float acc = Y0l[t * 5 + i];
#pragma unroll
      for (int s4i = 0; s4i < 8; ++s4i)
        acc += dot4(*(float4*)&BqMl[cur][t * 36 + s4i * 4], *(float4*)&Rtl[i * 36 + s4i * 4]);
      float y = acc / (qzl[t] + dnl[cur][t] + 1e-6f);
      ys[(size_t)(b * L_ + c * 32 + t) * 1024 + h * 64 + i0 + i] = y;
    }
    DSTORE(nxt);
    __syncthreads();
  }
#undef DLOAD
#undef DSTORE
  {
    int i = tid >> 6, j = tid & 63;
    outS[((size_t)(bh * 64) + i0 + i) * 64 + j] = S0l[i * 68 + j];
  }
  if (grp == 0 && tid < 64) outZ[bh * 64 + tid] = z0l[tid];
}

extern "C" void kernel_launch(void* const* d_in, const int* in_sizes, int n_in,
                              void* d_out, int out_size, void* d_ws, size_t ws_size,
                              hipStream_t stream) {
  const float* x     = (const float*)d_in[0];
  const float* Wqkv  = (const float*)d_in[1];
  const float* Wout  = (const float*)d_in[2];
  const float* Wgate = (const float*)d_in[3];
  const float* bgate = (const float*)d_in[4];
  const float* fn_g  = (const float*)d_in[5];
  const float* fn_b  = (const float*)d_in[6];
  const float* dn_g  = (const float*)d_in[7];
  const float* dn_b  = (const float*)d_in[8];
  const float* dWq   = (const float*)d_in[9];
  const float* dWk   = (const float*)d_in[10];
  const float* dWv   = (const float*)d_in[11];
  const float* dWo   = (const float*)d_in[12];
  const float* Wbeta = (const float*)d_in[13];
  const float* bbeta = (const float*)d_in[14];
  const float* cq_w  = (const float*)d_in[15];
  const float* cq_b  = (const float*)d_in[16];
  const float* ck_w  = (const float*)d_in[17];
  const float* ck_b  = (const float*)d_in[18];
  const float* ln_g  = (const float*)d_in[19];
  const float* ln_b  = (const float*)d_in[20];

  float* ws = (float*)d_ws;
  short* qkvh   = (short*)ws;      // [0,6.3M floats) as bf16; dead after attn
  float* dv     = ws;              // [0,4M)  after attn
  float* dqc    = ws + 4194304;    // [4M,8M)   after attn
  float* dkc    = ws + 8388608;    // [8M,12M)  after attn (written by convnorm)
  float* attnO  = ws + 12582912;   // [12M,16M)
  short* wtg    = (short*)(ws + 12582912); // [12M,12.5M) after attnO dead
  short* Wvt    = (short*)(ws + 14680064); // [14M,14.5M) dead after gemm_bt2
  float* denB_g = ws + 12582912;   // [12M,+64K) prep output (after wtg dead)
  float* zinc_g = ws + 12582912 + 65536;   // [+64K,+192K)
  float* BqM_g  = ws + 14680064;   // [14M,16M) prep output (after Wvt dead)
  float* do1    = ws + 12582912;   // after delta (denB/zinc dead)
  float* fo     = ws + 16777216;   // [16M,20M)
  float* dqp    = ws + 20971520;   // [20M,24M)
  float* gpre   = ws + 20971520;
  float* dkp    = ws + 25165824;   // [24M,28M) dead after convnorm
  float* MK_g   = ws + 25165824;   // [24M,28M) prep output (reuses dkp)
  float* betab  = ws + 29360128;   // [28M,+64K floats)

  short* Wqkvt = (short*)(ws + 20971520); // [20M,21.57M); dead after gemm_bt_h
  short* Woutt = (short*)(ws + 29426688); // [28M+64K, +0.5M)
  short* Wot   = (short*)(ws + 4194304);  // dqc dead after delta

  // split-precision dWq/dWk (bf16 hi/lo) @ [8M,10M) floats; live only for gemm_bt_split2
  short* Wqh = (short*)(ws + 8388608);   // [8.0M, 8.5M)
  short* Wql = (short*)(ws + 8912896);   // [8.5M, 9.0M)
  short* Wkh = (short*)(ws + 9437184);   // [9.0M, 9.5M)
  short* Wkl = (short*)(ws + 9961472);   // [9.5M,10.0M)

  float* out  = (float*)d_out;
  float* outS = out + 4194304;
  float* outZ = out + 4325376;
  float* ysb  = out;               // ys lives in d_out[0,4M): consumed by gemm_bt -> do1,
                                   // then ln2mix overwrites out (after reading do1). No alias hazard.

  // ---- flash branch ----
  tcast<<<dim3(48, 16), 256, 0, stream>>>(Wqkv, Wqkvt, 3072, 1024);          // Wqkvt@[20M); dqp written later
  gemm_bt_h<<<dim3(24, 32), 256, 0, stream>>>(x, Wqkvt, qkvh, 3072, 1024);   // qkv bf16 @[0,6.3M)
  attn_mfma<<<dim3(32, H_, B_), 256, 0, stream>>>(qkvh, attnO);
  tcast<<<dim3(16, 16), 256, 0, stream>>>(Wout, Woutt, 1024, 1024);          // Woutt@[28M+64K)
  gemm_bt<64><<<dim3(16, 32), 256, 0, stream>>>(attnO, Woutt, fo, 1024, 1024);
  ln_kernel<<<4096, 256, 0, stream>>>(fo, fn_g, fn_b);
  // ---- delta branch ----
  tcast_split2<<<dim3(16, 16, 2), 256, 0, stream>>>(dWq, dWk, Wqh, Wql, Wkh, Wkl);
  gemm_bt_split2<<<dim3(16, 32, 2), 256, 0, stream>>>(x, Wqh, Wql, Wkh, Wkl, dqp, dkp); // kills Wqkvt
  convnorm_kernel<<<dim3(16384, 2), 256, 0, stream>>>(dqp, dkp, cq_w, cq_b, ck_w, ck_b, dqc, dkc); // kills qkvh + split weights
  beta_kernel<<<4096, 256, 0, stream>>>(x, Wbeta, bbeta, betab);
  tcast2<<<dim3(16, 16, 2), 256, 0, stream>>>(dWv, Wgate, Wvt, wtg);         // attnO dead; Wvt@14M, wtg@12M
  gemm_bt2<<<dim3(16, 32, 2), 256, 0, stream>>>(x, Wvt, wtg, dv, gpre);      // gpre kills dqp (dead)
  prep_kernel<<<dim3(64, 32), 256, 0, stream>>>(dqc, dkc, betab, MK_g, BqM_g, denB_g, zinc_g); // kills wtg/Wvt/dkp
  delta_kernel<<<512, 256, 0, stream>>>(dqc, dkc, dv, betab, MK_g, BqM_g, denB_g, zinc_g, ysb, outS, outZ);
  tcast<<<dim3(16, 16), 256, 0, stream>>>(dWo, Wot, 1024, 1024);             // dqc dead
  gemm_bt<64><<<dim3(16, 32), 256, 0, stream>>>(ysb, Wot, do1, 1024, 1024);  // do1 kills denB/zinc
  ln2mix_kernel<<<4096, 256, 0, stream>>>(do1, ln_g, ln_b, dn_g, dn_b, gpre, bgate, fo, out);
}

// Round 6
// 750.394 us; speedup vs baseline: 1.0542x; 1.0157x over previous
//
#include <hip/hip_runtime.h>
#include <hip/hip_bf16.h>

constexpr int B_ = 2, L_ = 2048, D_ = 1024, H_ = 16;

using bf16x8 = __attribute__((ext_vector_type(8))) short;
using f32x4  = __attribute__((ext_vector_type(4))) float;

__device__ __forceinline__ short f2b(float f) {
  union { float f; unsigned int u; } v; v.f = f;
  unsigned int r = (v.u + 0x7FFFu + ((v.u >> 16) & 1u)) >> 16;
  return (short)r;
}
__device__ __forceinline__ float b2f(unsigned short h) {
  union { unsigned int u; float f; } v; v.u = ((unsigned int)h) << 16; return v.f;
}
// split x into hi/lo bf16: x ~= hi + lo, |x - hi - lo| ~ 2^-18 |x|
__device__ __forceinline__ void split2(float x, float y, unsigned int& h, unsigned int& l) {
  unsigned short hx = (unsigned short)f2b(x), hy = (unsigned short)f2b(y);
  h = (unsigned int)hx | ((unsigned int)hy << 16);
  unsigned short lx = (unsigned short)f2b(x - b2f(hx)), ly = (unsigned short)f2b(y - b2f(hy));
  l = (unsigned int)lx | ((unsigned int)ly << 16);
}
__device__ __forceinline__ float dot4(float4 a, float4 b) {
  return a.x * b.x + a.y * b.y + a.z * b.z + a.w * b.w;
}

// ---------------- transpose+cast: W[K,N] fp32 -> Wt[N,K] bf16 ----------------
__global__ __launch_bounds__(256) void tcast(const float* __restrict__ W, short* __restrict__ Wt,
                                             int N, int K) {
  __shared__ float T[64][65];
  int n0 = blockIdx.x * 64, k0 = blockIdx.y * 64;
  int tid = threadIdx.x;
#pragma unroll
  for (int i = 0; i < 16; ++i) {
    int idx = i * 256 + tid;
    int r = idx >> 6, c = idx & 63;
    T[r][c] = W[(size_t)(k0 + r) * N + n0 + c];
  }
  __syncthreads();
#pragma unroll
  for (int i = 0; i < 16; ++i) {
    int idx = i * 256 + tid;
    int rr = idx >> 6, cc = idx & 63;
    Wt[(size_t)(n0 + rr) * K + k0 + cc] = f2b(T[cc][rr]);
  }
}

// two-weight tcast (1024x1024 each), blockIdx.z selects
__global__ __launch_bounds__(256) void tcast2(const float* __restrict__ W1, const float* __restrict__ W2,
                                              short* __restrict__ Wt1, short* __restrict__ Wt2) {
  __shared__ float T[64][65];
  const float* W = blockIdx.z ? W2 : W1;
  short* Wt = blockIdx.z ? Wt2 : Wt1;
  int n0 = blockIdx.x * 64, k0 = blockIdx.y * 64;
  int tid = threadIdx.x;
#pragma unroll
  for (int i = 0; i < 16; ++i) {
    int idx = i * 256 + tid;
    int r = idx >> 6, c = idx & 63;
    T[r][c] = W[(size_t)(k0 + r) * 1024 + n0 + c];
  }
  __syncthreads();
#pragma unroll
  for (int i = 0; i < 16; ++i) {
    int idx = i * 256 + tid;
    int rr = idx >> 6, cc = idx & 63;
    Wt[(size_t)(n0 + rr) * 1024 + k0 + cc] = f2b(T[cc][rr]);
  }
}

// two-weight split tcast: W[K,N] fp32 -> (Wh,Wl)[N,K] bf16 hi/lo pair, z selects weight
__global__ __launch_bounds__(256) void tcast_split2(const float* __restrict__ W1, const float* __restrict__ W2,
                                                    short* __restrict__ Wh1, short* __restrict__ Wl1,
                                                    short* __restrict__ Wh2, short* __restrict__ Wl2) {
  __shared__ float T[64][65];
  const float* W = blockIdx.z ? W2 : W1;
  short* Wh = blockIdx.z ? Wh2 : Wh1;
  short* Wl = blockIdx.z ? Wl2 : Wl1;
  int n0 = blockIdx.x * 64, k0 = blockIdx.y * 64;
  int tid = threadIdx.x;
#pragma unroll
  for (int i = 0; i < 16; ++i) {
    int idx = i * 256 + tid;
    int r = idx >> 6, c = idx & 63;
    T[r][c] = W[(size_t)(k0 + r) * 1024 + n0 + c];
  }
  __syncthreads();
#pragma unroll
  for (int i = 0; i < 16; ++i) {
    int idx = i * 256 + tid;
    int rr = idx >> 6, cc = idx & 63;
    float w = T[cc][rr];
    short h = f2b(w);
    short l = f2b(w - b2f((unsigned short)h));
    size_t o = (size_t)(n0 + rr) * 1024 + k0 + cc;
    Wh[o] = h;
    Wl[o] = l;
  }
}

// ---------------- MFMA GEMM core (shared) ----------------
template <int BN, typename CT>
__device__ __forceinline__ void gemm_bt_body(const float* __restrict__ A, const short* __restrict__ Wt,
                                             CT* __restrict__ C, int N, int K, int bx, int by) {
  constexpr int MT = (BN == 128) ? 4 : 2;
  constexpr int NT = 4;
  __shared__ __align__(16) short As[128 * 32];
  __shared__ __align__(16) short Bs[BN * 32];
  int tid = threadIdx.x;
  int wave = tid >> 6, lane = tid & 63, quad = lane >> 4, l15 = lane & 15;
  int m0 = by * 128, n0 = bx * BN;
  int wm = (BN == 128) ? (wave >> 1) * 64 : wave * 32;
  int wn = (BN == 128) ? (wave & 1) * 64 : 0;
  f32x4 acc[MT][NT];
#pragma unroll
  for (int mt = 0; mt < MT; ++mt)
#pragma unroll
    for (int nt = 0; nt < NT; ++nt) acc[mt][nt] = (f32x4){0.f, 0.f, 0.f, 0.f};

  for (int k0 = 0; k0 < K; k0 += 32) {
    __syncthreads();
#pragma unroll
    for (int i = 0; i < 2; ++i) {
      int chunk = i * 256 + tid;
      int m = chunk >> 2, kc = (chunk & 3) * 8;
      const float* ap = A + (size_t)(m0 + m) * K + k0 + kc;
      float4 a0 = *(const float4*)ap;
      float4 a1 = *(const float4*)(ap + 4);
      __hip_bfloat162 c0 = __float22bfloat162_rn(make_float2(a0.x, a0.y));
      __hip_bfloat162 c1 = __float22bfloat162_rn(make_float2(a0.z, a0.w));
      __hip_bfloat162 c2 = __float22bfloat162_rn(make_float2(a1.x, a1.y));
      __hip_bfloat162 c3 = __float22bfloat162_rn(make_float2(a1.z, a1.w));
      uint4 u;
      u.x = *(unsigned int*)&c0; u.y = *(unsigned int*)&c1;
      u.z = *(unsigned int*)&c2; u.w = *(unsigned int*)&c3;
      *(uint4*)&As[m * 32 + kc] = u;
    }
#pragma unroll
    for (int i = 0; i < BN * 4 / 256; ++i) {
      int chunk = i * 256 + tid;
      int n = chunk >> 2, kc = (chunk & 3) * 8;
      uint4 w = *(const uint4*)(Wt + (size_t)(n0 + n) * K + k0 + kc);
      *(uint4*)&Bs[n * 32 + kc] = w;
    }
    __syncthreads();
    bf16x8 af[MT], bf[NT];
#pragma unroll
    for (int mt = 0; mt < MT; ++mt) af[mt] = *(bf16x8*)&As[(wm + mt * 16 + l15) * 32 + quad * 8];
#pragma unroll
    for (int nt = 0; nt < NT; ++nt) bf[nt] = *(bf16x8*)&Bs[(wn + nt * 16 + l15) * 32 + quad * 8];
#pragma unroll
    for (int mt = 0; mt < MT; ++mt)
#pragma unroll
      for (int nt = 0; nt < NT; ++nt)
        acc[mt][nt] = __builtin_amdgcn_mfma_f32_16x16x32_bf16(af[mt], bf[nt], acc[mt][nt], 0, 0, 0);
  }
#pragma unroll
  for (int mt = 0; mt < MT; ++mt)
#pragma unroll
    for (int nt = 0; nt < NT; ++nt)
#pragma unroll
      for (int r = 0; r < 4; ++r) {
        size_t idx = (size_t)(m0 + wm + mt * 16 + quad * 4 + r) * N + n0 + wn + nt * 16 + l15;
        if constexpr (sizeof(CT) == 2) C[idx] = f2b(acc[mt][nt][r]);
        else C[idx] = acc[mt][nt][r];
      }
}

template <int BN>
__global__ __launch_bounds__(256) void gemm_bt(const float* __restrict__ A, const short* __restrict__ Wt,
                                               float* __restrict__ C, int N, int K) {
  gemm_bt_body<BN, float>(A, Wt, C, N, K, blockIdx.x, blockIdx.y);
}

// bf16-output variant (for qkv)
__global__ __launch_bounds__(256) void gemm_bt_h(const float* __restrict__ A, const short* __restrict__ Wt,
                                                 short* __restrict__ C, int N, int K) {
  gemm_bt_body<128, short>(A, Wt, C, N, K, blockIdx.x, blockIdx.y);
}

// two-GEMM variant: z selects (Wt1->C1) vs (Wt2->C2), 1024x1024
__global__ __launch_bounds__(256) void gemm_bt2(const float* __restrict__ A, const short* __restrict__ Wt1,
                                                const short* __restrict__ Wt2, float* __restrict__ C1,
                                                float* __restrict__ C2) {
  gemm_bt_body<64, float>(A, blockIdx.z ? Wt2 : Wt1, blockIdx.z ? C2 : C1, 1024, 1024,
                          blockIdx.x, blockIdx.y);
}

// ---------------- split-precision MFMA GEMM: C = A@W with ~fp32 accuracy ----------------
__global__ __launch_bounds__(256) void gemm_bt_split2(const float* __restrict__ A,
                                                      const short* __restrict__ Wh1, const short* __restrict__ Wl1,
                                                      const short* __restrict__ Wh2, const short* __restrict__ Wl2,
                                                      float* __restrict__ C1, float* __restrict__ C2) {
  constexpr int K = 1024, N = 1024;
  const short* Wh = blockIdx.z ? Wh2 : Wh1;
  const short* Wl = blockIdx.z ? Wl2 : Wl1;
  float* C = blockIdx.z ? C2 : C1;
  __shared__ __align__(16) short Ash[128 * 32];
  __shared__ __align__(16) short Asl[128 * 32];
  __shared__ __align__(16) short Bsh[64 * 32];
  __shared__ __align__(16) short Bsl[64 * 32];
  int tid = threadIdx.x;
  int wave = tid >> 6, lane = tid & 63, quad = lane >> 4, l15 = lane & 15;
  int m0 = blockIdx.y * 128, n0 = blockIdx.x * 64;
  int wm = wave * 32;
  f32x4 acc[2][4];
#pragma unroll
  for (int mt = 0; mt < 2; ++mt)
#pragma unroll
    for (int nt = 0; nt < 4; ++nt) acc[mt][nt] = (f32x4){0.f, 0.f, 0.f, 0.f};

  for (int k0 = 0; k0 < K; k0 += 32) {
    __syncthreads();
#pragma unroll
    for (int i = 0; i < 2; ++i) {
      int chunk = i * 256 + tid;
      int m = chunk >> 2, kc = (chunk & 3) * 8;
      const float* ap = A + (size_t)(m0 + m) * K + k0 + kc;
      float4 a0 = *(const float4*)ap;
      float4 a1 = *(const float4*)(ap + 4);
      uint4 uh, ul;
      split2(a0.x, a0.y, uh.x, ul.x);
      split2(a0.z, a0.w, uh.y, ul.y);
      split2(a1.x, a1.y, uh.z, ul.z);
      split2(a1.z, a1.w, uh.w, ul.w);
      *(uint4*)&Ash[m * 32 + kc] = uh;
      *(uint4*)&Asl[m * 32 + kc] = ul;
    }
    {
      int n = tid >> 2, kc = (tid & 3) * 8;
      size_t off = (size_t)(n0 + n) * K + k0 + kc;
      *(uint4*)&Bsh[n * 32 + kc] = *(const uint4*)(Wh + off);
      *(uint4*)&Bsl[n * 32 + kc] = *(const uint4*)(Wl + off);
    }
    __syncthreads();
    bf16x8 ah[2], al[2], bh[4], bl[4];
#pragma unroll
    for (int mt = 0; mt < 2; ++mt) {
      ah[mt] = *(bf16x8*)&Ash[(wm + mt * 16 + l15) * 32 + quad * 8];
      al[mt] = *(bf16x8*)&Asl[(wm + mt * 16 + l15) * 32 + quad * 8];
    }
#pragma unroll
    for (int nt = 0; nt < 4; ++nt) {
      bh[nt] = *(bf16x8*)&Bsh[(nt * 16 + l15) * 32 + quad * 8];
      bl[nt] = *(bf16x8*)&Bsl[(nt * 16 + l15) * 32 + quad * 8];
    }
#pragma unroll
    for (int mt = 0; mt < 2; ++mt)
#pragma unroll
      for (int nt = 0; nt < 4; ++nt) {
        f32x4 a = acc[mt][nt];
        a = __builtin_amdgcn_mfma_f32_16x16x32_bf16(al[mt], bh[nt], a, 0, 0, 0);
        a = __builtin_amdgcn_mfma_f32_16x16x32_bf16(ah[mt], bl[nt], a, 0, 0, 0);
        a = __builtin_amdgcn_mfma_f32_16x16x32_bf16(ah[mt], bh[nt], a, 0, 0, 0);
        acc[mt][nt] = a;
      }
  }
#pragma unroll
  for (int mt = 0; mt < 2; ++mt)
#pragma unroll
    for (int nt = 0; nt < 4; ++nt)
#pragma unroll
      for (int r = 0; r < 4; ++r) {
        size_t idx = (size_t)(m0 + wm + mt * 16 + quad * 4 + r) * N + n0 + nt * 16 + l15;
        C[idx] = acc[mt][nt][r];
      }
}

// ---------------- MFMA bf16 causal flash attention (bf16 qkv input) ----------------
__global__ __launch_bounds__(256) void attn_mfma(const short* __restrict__ qkv, float* __restrict__ outp) {
  __shared__ __align__(16) short Kl[64 * 64];
  __shared__ __align__(16) short Vt[64 * 64];
  __shared__ __align__(16) short Pl[64 * 64];
  int qb = 31 - blockIdx.x, h = blockIdx.y, b = blockIdx.z;
  int tid = threadIdx.x;
  int wave = tid >> 6, lane = tid & 63;
  int quad = lane >> 4, l15 = lane & 15;
  int qrow = qb * 64 + wave * 16 + l15;
  bf16x8 qf[2];
  {
    const short* qbase = qkv + (size_t)(b * L_ + qrow) * 3072 + h * 64;
#pragma unroll
    for (int s = 0; s < 2; ++s) qf[s] = *(const bf16x8*)(qbase + s * 32 + quad * 8);
  }
  f32x4 Of[4];
  float mrow[4], lrow[4], alpha[4];
#pragma unroll
  for (int dt = 0; dt < 4; ++dt) Of[dt] = (f32x4){0.f, 0.f, 0.f, 0.f};
#pragma unroll
  for (int r = 0; r < 4; ++r) { mrow[r] = -1e30f; lrow[r] = 0.f; }

  for (int kt = 0; kt <= qb; ++kt) {
    __syncthreads();
#pragma unroll
    for (int it = 0; it < 2; ++it) {
      int e8 = tid + it * 256;
      int key = e8 >> 3, g = e8 & 7;
      const short* src = qkv + ((size_t)((b * L_ + kt * 64 + key) * 3) + 1) * 1024 + h * 64 + g * 8;
      *(bf16x8*)&Kl[key * 64 + ((g ^ (key & 7)) << 3)] = *(const bf16x8*)src;
    }
    {
      int key4 = tid >> 4;
      int d4 = tid & 15;
      const short* vsrc = qkv + ((size_t)((b * L_ + kt * 64 + key4 * 4) * 3) + 2) * 1024 + h * 64 + d4 * 4;
      short4 v0 = *(const short4*)vsrc;
      short4 v1 = *(const short4*)(vsrc + 3072);
      short4 v2 = *(const short4*)(vsrc + 6144);
      short4 v3 = *(const short4*)(vsrc + 9216);
      short vr0[4] = {v0.x, v0.y, v0.z, v0.w};
      short vr1[4] = {v1.x, v1.y, v1.z, v1.w};
      short vr2[4] = {v2.x, v2.y, v2.z, v2.w};
      short vr3[4] = {v3.x, v3.y, v3.z, v3.w};
      int kg = key4 >> 1, k7b = (key4 & 1) * 4;
#pragma unroll
      for (int jj = 0; jj < 4; ++jj) {
        int d = d4 * 4 + jj;
        short4 sv;
        sv.x = vr0[jj]; sv.y = vr1[jj]; sv.z = vr2[jj]; sv.w = vr3[jj];
        *(short4*)&Vt[d * 64 + ((kg ^ (d & 7)) << 3) + k7b] = sv;
      }
    }
    __syncthreads();
    f32x4 sc[4];
#pragma unroll
    for (int nt = 0; nt < 4; ++nt) sc[nt] = (f32x4){0.f, 0.f, 0.f, 0.f};
#pragma unroll
    for (int s = 0; s < 2; ++s) {
#pragma unroll
      for (int nt = 0; nt < 4; ++nt) {
        int key = nt * 16 + l15;
        bf16x8 kf = *(bf16x8*)&Kl[key * 64 + (((4 * s + quad) ^ (key & 7)) << 3)];
        sc[nt] = __builtin_amdgcn_mfma_f32_16x16x32_bf16(qf[s], kf, sc[nt], 0, 0, 0);
      }
    }
    bool diag = (kt == qb);
#pragma unroll
    for (int r = 0; r < 4; ++r) {
      float sv[4];
#pragma unroll
      for (int nt = 0; nt < 4; ++nt) {
        float v = sc[nt][r] * 0.125f;
        if (diag && (nt * 16 + l15 > wave * 16 + quad * 4 + r)) v = -1e30f;
        sv[nt] = v;
      }
      float mx = fmaxf(fmaxf(sv[0], sv[1]), fmaxf(sv[2], sv[3]));
      mx = fmaxf(mx, __shfl_xor(mx, 1));
      mx = fmaxf(mx, __shfl_xor(mx, 2));
      mx = fmaxf(mx, __shfl_xor(mx, 4));
      mx = fmaxf(mx, __shfl_xor(mx, 8));
      float mnew = fmaxf(mrow[r], mx);
      float al = __expf(mrow[r] - mnew);
      mrow[r] = mnew;
      alpha[r] = al;
      int prow = wave * 16 + quad * 4 + r;
      int r7 = prow & 7;
      float ps = 0.f;
#pragma unroll
      for (int nt = 0; nt < 4; ++nt) {
        float p = __expf(sv[nt] - mnew);
        ps += p;
        Pl[prow * 64 + ((((nt << 1) + (l15 >> 3)) ^ r7) << 3) + (l15 & 7)] = f2b(p);
      }
      ps += __shfl_xor(ps, 1);
      ps += __shfl_xor(ps, 2);
      ps += __shfl_xor(ps, 4);
      ps += __shfl_xor(ps, 8);
      lrow[r] = lrow[r] * al + ps;
    }
#pragma unroll
    for (int dt = 0; dt < 4; ++dt)
#pragma unroll
      for (int r = 0; r < 4; ++r) Of[dt][r] *= alpha[r];
#pragma unroll
    for (int s = 0; s < 2; ++s) {
      bf16x8 pf = *(bf16x8*)&Pl[(wave * 16 + l15) * 64 + (((4 * s + quad) ^ (l15 & 7)) << 3)];
#pragma unroll
      for (int dt = 0; dt < 4; ++dt) {
        int d = dt * 16 + l15;
        bf16x8 vf = *(bf16x8*)&Vt[d * 64 + (((4 * s + quad) ^ (d & 7)) << 3)];
        Of[dt] = __builtin_amdgcn_mfma_f32_16x16x32_bf16(pf, vf, Of[dt], 0, 0, 0);
      }
    }
  }
#pragma unroll
  for (int r = 0; r < 4; ++r) alpha[r] = 1.f / lrow[r];
  int orow = qb * 64 + wave * 16 + quad * 4;
#pragma unroll
  for (int dt = 0; dt < 4; ++dt)
#pragma unroll
    for (int r = 0; r < 4; ++r)
      outp[(size_t)(b * L_ + orow + r) * 1024 + h * 64 + dt * 16 + l15] = Of[dt][r] * alpha[r];
}

// ---------------- layernorm over last dim D=1024, in place ----------------
__global__ __launch_bounds__(256) void ln_kernel(float* __restrict__ X, const float* __restrict__ g,
                                                 const float* __restrict__ bb) {
  int row = blockIdx.x, tid = threadIdx.x;
  float* xr = X + (size_t)row * D_;
  float v[4], s = 0.f, ss = 0.f;
#pragma unroll
  for (int i = 0; i < 4; ++i) { v[i] = xr[tid + i * 256]; s += v[i]; ss += v[i] * v[i]; }
#pragma unroll
  for (int off = 32; off; off >>= 1) { s += __shfl_xor(s, off); ss += __shfl_xor(ss, off); }
  __shared__ float rs[4], rss[4];
  if ((tid & 63) == 0) { rs[tid >> 6] = s; rss[tid >> 6] = ss; }
  __syncthreads();
  float S = rs[0] + rs[1] + rs[2] + rs[3];
  float SS = rss[0] + rss[1] + rss[2] + rss[3];
  float mean = S * (1.f / 1024.f);
  float var = SS * (1.f / 1024.f) - mean * mean;
  float inv = rsqrtf(var + 1e-5f);
#pragma unroll
  for (int i = 0; i < 4; ++i) {
    int c = tid + i * 256;
    xr[c] = (v[i] - mean) * inv * g[c] + bb[c];
  }
}

// ---------------- fused: LN -> LN -> gate mix ----------------
__global__ __launch_bounds__(256) void ln2mix_kernel(const float* __restrict__ X,
                                                     const float* __restrict__ g1, const float* __restrict__ b1,
                                                     const float* __restrict__ g2, const float* __restrict__ b2,
                                                     const float* __restrict__ gpre, const float* __restrict__ bgate,
                                                     const float* __restrict__ fo, float* __restrict__ outp) {
  int row = blockIdx.x, tid = threadIdx.x;
  const float* xr = X + (size_t)row * D_;
  __shared__ float rs[4], rss[4];
  float v[4], s = 0.f, ss = 0.f;
#pragma unroll
  for (int i = 0; i < 4; ++i) { v[i] = xr[tid + i * 256]; s += v[i]; ss += v[i] * v[i]; }
#pragma unroll
  for (int off = 32; off; off >>= 1) { s += __shfl_xor(s, off); ss += __shfl_xor(ss, off); }
  if ((tid & 63) == 0) { rs[tid >> 6] = s; rss[tid >> 6] = ss; }
  __syncthreads();
  float S = rs[0] + rs[1] + rs[2] + rs[3];
  float SS = rss[0] + rss[1] + rss[2] + rss[3];
  float mean = S * (1.f / 1024.f);
  float var = SS * (1.f / 1024.f) - mean * mean;
  float inv = rsqrtf(var + 1e-5f);
  s = 0.f; ss = 0.f;
#pragma unroll
  for (int i = 0; i < 4; ++i) {
    int c = tid + i * 256;
    v[i] = (v[i] - mean) * inv * g1[c] + b1[c];
    s += v[i]; ss += v[i] * v[i];
  }
#pragma unroll
  for (int off = 32; off; off >>= 1) { s += __shfl_xor(s, off); ss += __shfl_xor(ss, off); }
  __syncthreads();
  if ((tid & 63) == 0) { rs[tid >> 6] = s; rss[tid >> 6] = ss; }
  __syncthreads();
  S = rs[0] + rs[1] + rs[2] + rs[3];
  SS = rss[0] + rss[1] + rss[2] + rss[3];
  mean = S * (1.f / 1024.f);
  var = SS * (1.f / 1024.f) - mean * mean;
  inv = rsqrtf(var + 1e-5f);
#pragma unroll
  for (int i = 0; i < 4; ++i) {
    int c = tid + i * 256;
    size_t idx = (size_t)row * D_ + c;
    float w = (v[i] - mean) * inv * g2[c] + b2[c];
    float gg = 1.f / (1.f + __expf(-(gpre[idx] + bgate[c])));
    outp[idx] = gg * fo[idx] + (1.f - gg) * w;
  }
}

// ---------------- fused conv (q) / conv+L2norm (k) ----------------
__global__ __launch_bounds__(256) void convnorm_kernel(const float* __restrict__ qin, const float* __restrict__ kin,
                                                       const float* __restrict__ qw, const float* __restrict__ qb,
                                                       const float* __restrict__ kw, const float* __restrict__ kb,
                                                       float* __restrict__ qout, float* __restrict__ kout) {
  int path = blockIdx.y;
  int row = blockIdx.x * 4 + (threadIdx.x >> 6);
  int lane = threadIdx.x & 63;
  int bl = row >> 4, h = row & 15;
  int t = bl & (L_ - 1);
  int d = h * 64 + lane;
  size_t idx = (size_t)bl * D_ + d;
  const float* xin = path ? kin : qin;
  const float* w = path ? kw : qw;
  const float* bias = path ? kb : qb;
  float acc = bias[d];
#pragma unroll
  for (int j = 0; j < 4; ++j) {
    int tt = t - 3 + j;
    if (tt >= 0) acc += w[d * 4 + j] * xin[idx + (size_t)(j - 3) * D_];
  }
  if (path) {
    float n2 = acc * acc;
#pragma unroll
    for (int off = 32; off; off >>= 1) n2 += __shfl_xor(n2, off);
    acc = acc / fmaxf(sqrtf(n2), 1e-12f);
    kout[idx] = acc;
  } else {
    qout[idx] = acc;
  }
}

// ---------------- beta = sigmoid(x @ Wbeta + bbeta) ----------------
__global__ __launch_bounds__(256) void beta_kernel(const float* __restrict__ xf, const float* __restrict__ Wb,
                                                   const float* __restrict__ bb, float* __restrict__ beta) {
  int row = blockIdx.x, tid = threadIdx.x;
  int h = tid & 15, seg = tid >> 4;
  const float* xr = xf + (size_t)row * D_ + seg * 64;
  const float* wp = Wb + (seg * 64) * H_ + h;
  float p = 0.f;
  for (int k = 0; k < 64; ++k) p += xr[k] * wp[k * H_];
  __shared__ float red[16][17];
  red[seg][h] = p;
  __syncthreads();
  if (tid < 16) {
    float s = bb[tid];
#pragma unroll
    for (int s2 = 0; s2 < 16; ++s2) s += red[s2][tid];
    beta[(size_t)row * H_ + tid] = 1.f / (1.f + __expf(-s));
  }
}

// ================= chunked delta scan =================
// prep hoists the Minv applications:
//   MK  = Minv^T @ K   (32x64)   BqM = Bq @ Minv (32x32, strictly lower)
//   denB[t] = sum_s Bq[t][s] beta[s]   zinc[j] = sum_s beta[s] K[s][j]
__global__ __launch_bounds__(256) void prep_kernel(const float* __restrict__ dq, const float* __restrict__ dk,
                                                   const float* __restrict__ beta,
                                                   float* __restrict__ MK_g, float* __restrict__ BqM_g,
                                                   float* __restrict__ denB_g, float* __restrict__ zinc_g) {
  __shared__ __align__(16) float Kl[32 * 68];
  __shared__ __align__(16) float Ql[32 * 68];
  __shared__ __align__(16) float Ml[32 * 36];
  __shared__ __align__(16) float Xl[32 * 36];
  __shared__ __align__(16) float Bql[32 * 36];
  __shared__ __align__(16) float bl[32];
  int c = blockIdx.x, bh = blockIdx.y;
  int b = bh >> 4, h = bh & 15;
  int t0 = c * 32;
  int tid = threadIdx.x;
#pragma unroll
  for (int rep = 0; rep < 2; ++rep) {
    int id = tid * 2 + rep;
    int r = id >> 4, j4 = id & 15;
    size_t gi = (size_t)(b * L_ + t0 + r) * 1024 + h * 64 + j4 * 4;
    *(float4*)&Kl[r * 68 + j4 * 4] = *(const float4*)&dk[gi];
    *(float4*)&Ql[r * 68 + j4 * 4] = *(const float4*)&dq[gi];
  }
  if (tid < 32) bl[tid] = beta[(size_t)(b * L_ + t0 + tid) * 16 + h];
  __syncthreads();
  int t = tid >> 3, s0 = (tid & 7) * 4;
  float accA[4] = {0.f, 0.f, 0.f, 0.f}, accB[4] = {0.f, 0.f, 0.f, 0.f};
#pragma unroll
  for (int k4 = 0; k4 < 16; ++k4) {
    float4 kt = *(float4*)&Kl[t * 68 + k4 * 4];
    float4 qt = *(float4*)&Ql[t * 68 + k4 * 4];
#pragma unroll
    for (int j = 0; j < 4; ++j) {
      float4 ks = *(float4*)&Kl[(s0 + j) * 68 + k4 * 4];
      accA[j] += dot4(kt, ks);
      accB[j] += dot4(qt, ks);
    }
  }
#pragma unroll
  for (int j = 0; j < 4; ++j) {
    int s = s0 + j;
    Ml[t * 36 + s] = (s < t) ? bl[t] * accA[j] : ((s == t) ? 1.f : 0.f);
    Bql[t * 36 + s] = (s < t) ? accB[j] : 0.f;
  }
  __syncthreads();
  if (tid < 32) {
    int col = tid;
    float xr[32];
#pragma unroll
    for (int tt = 0; tt < 32; ++tt) {
      float x = (tt == col) ? 1.f : 0.f;
#pragma unroll
      for (int s = 0; s < tt; ++s) x -= Ml[tt * 36 + s] * xr[s];
      xr[tt] = x;
      Xl[tt * 36 + col] = x;
    }
  }
  __syncthreads();
  size_t cb = (size_t)(bh * 64 + c);
  // MK[s][j] = sum_t Minv[t][s] * K[t][j]
  {
    int s = tid >> 3, j8 = (tid & 7) * 8;
    float4 m0 = make_float4(0.f, 0.f, 0.f, 0.f);
    float4 m1 = make_float4(0.f, 0.f, 0.f, 0.f);
#pragma unroll
    for (int t2 = 0; t2 < 32; ++t2) {
      float xv = Xl[t2 * 36 + s];
      float4 k0 = *(float4*)&Kl[t2 * 68 + j8];
      float4 k1 = *(float4*)&Kl[t2 * 68 + j8 + 4];
      m0.x += xv * k0.x; m0.y += xv * k0.y; m0.z += xv * k0.z; m0.w += xv * k0.w;
      m1.x += xv * k1.x; m1.y += xv * k1.y; m1.z += xv * k1.z; m1.w += xv * k1.w;
    }
    float* mkp = MK_g + (cb * 32 + s) * 64 + j8;
    *(float4*)mkp = m0;
    *(float4*)(mkp + 4) = m1;
  }
  // BqM[t][s] = sum_u Bq[t][u] * Minv[u][s]
  {
    int tt = tid >> 3, s4 = (tid & 7) * 4;
    float4 acc = make_float4(0.f, 0.f, 0.f, 0.f);
#pragma unroll
    for (int u4 = 0; u4 < 8; ++u4) {
      float4 bq = *(float4*)&Bql[tt * 36 + u4 * 4];
      float4 x0 = *(float4*)&Xl[(u4 * 4 + 0) * 36 + s4];
      float4 x1 = *(float4*)&Xl[(u4 * 4 + 1) * 36 + s4];
      float4 x2 = *(float4*)&Xl[(u4 * 4 + 2) * 36 + s4];
      float4 x3 = *(float4*)&Xl[(u4 * 4 + 3) * 36 + s4];
      acc.x += bq.x * x0.x + bq.y * x1.x + bq.z * x2.x + bq.w * x3.x;
      acc.y += bq.x * x0.y + bq.y * x1.y + bq.z * x2.y + bq.w * x3.y;
      acc.z += bq.x * x0.z + bq.y * x1.z + bq.z * x2.z + bq.w * x3.z;
      acc.w += bq.x * x0.w + bq.y * x1.w + bq.z * x2.w + bq.w * x3.w;
    }
    *(float4*)&BqM_g[cb * 1024 + tt * 32 + s4] = acc;
  }
  if (tid < 32) {
    float a = 0.f;
#pragma unroll
    for (int s4i = 0; s4i < 8; ++s4i)
      a += dot4(*(float4*)&Bql[tid * 36 + s4i * 4], *(float4*)&bl[s4i * 4]);
    denB_g[cb * 32 + tid] = a;
  }
  if (tid >= 64 && tid < 128) {
    int j = tid - 64;
    float a = 0.f;
#pragma unroll
    for (int s = 0; s < 32; ++s) a += bl[s] * Kl[s * 68 + j];
    zinc_g[cb * 64 + j] = a;
  }
}

// 2-barrier/iter scan. K/Q never touch LDS: thread (r,js) loads exactly the
// (row r, slice j8) its P1 needs -> registers, explicit 2-set double-buffer.
// LDS ~31.6KB (MK/BqM/V/aux only). LDS-issue was the bound (r4/r5 model).
__global__ __launch_bounds__(256) void delta_kernel(const float* __restrict__ dq, const float* __restrict__ dk,
                                                    const float* __restrict__ dv, const float* __restrict__ beta,
                                                    const float* __restrict__ MK_g, const float* __restrict__ BqM_g,
                                                    const float* __restrict__ denB_g, const float* __restrict__ zinc_g,
                                                    float* __restrict__ ys, float* __restrict__ outS,
                                                    float* __restrict__ outZ) {
  __shared__ __align__(16) float MKl[2][32 * 68];
  __shared__ __align__(16) float BqMl[2][32 * 36];
  __shared__ __align__(16) float Vl[2][32 * 5];
  __shared__ __align__(16) float bll[2][32];
  __shared__ __align__(16) float dnl[2][32];
  __shared__ __align__(16) float zil[2][64];
  __shared__ __align__(16) float S0l[4 * 68];
  __shared__ __align__(16) float Y0l[32 * 5];
  __shared__ __align__(16) float Rtl[4 * 36];
  __shared__ __align__(16) float z0l[64];
  __shared__ __align__(16) float qzl[32];
  int bh = blockIdx.x & 31, grp = blockIdx.x >> 5;  // same-bh groups share an XCD
  int b = bh >> 4, h = bh & 15;
  int i0 = grp * 4;
  int tid = threadIdx.x;
  int r = tid >> 3, j8 = (tid & 7) * 8;
  int js = tid & 7;
  size_t kqbase = (size_t)(b * L_) * 1024 + h * 64;

  for (int e = tid; e < 4 * 68; e += 256) S0l[e] = 0.f;
  if (tid < 64) z0l[tid] = 0.f;

  // K/Q registers: current (c-suffix) + prefetch (n-suffix). No LDS round-trip.
  float4 kAc, kBc, qAc, qBc, kAn, kBn, qAn, qBn;
  float4 mA, mB, bqA, bqB;
  bqA = bqB = make_float4(0.f, 0.f, 0.f, 0.f);
  float vr = 0.f, blr = 0.f, dnb = 0.f, zi = 0.f;

#define KQLOAD(CN, KA, KB, QA, QB) { \
    size_t rb_ = kqbase + (size_t)((CN) * 32 + r) * 1024 + j8; \
    KA = ((const float4*)(dk + rb_))[0]; KB = ((const float4*)(dk + rb_))[1]; \
    QA = ((const float4*)(dq + rb_))[0]; QB = ((const float4*)(dq + rb_))[1]; \
  }
#define AUXLOAD(CN) { \
    size_t cb_ = (size_t)(bh * 64 + (CN)); \
    const float* mkp_ = MK_g + (cb_ * 32 + r) * 64 + j8; \
    mA = ((const float4*)mkp_)[0]; mB = ((const float4*)mkp_)[1]; \
    if (tid < 128) { \
      const float* bqp_ = BqM_g + cb_ * 1024 + (tid >> 2) * 32 + (tid & 3) * 8; \
      bqA = ((const float4*)bqp_)[0]; bqB = ((const float4*)bqp_)[1]; \
      vr = dv[(size_t)(b * L_ + (CN) * 32 + (tid >> 2)) * 1024 + h * 64 + i0 + (tid & 3)]; \
    } \
    if (tid < 32) { blr = beta[(size_t)(b * L_ + (CN) * 32 + tid) * 16 + h]; dnb = denB_g[cb_ * 32 + tid]; } \
    if (tid < 64) zi = zinc_g[cb_ * 64 + tid]; \
  }
#define AUXSTORE(NX) { \
    *(float4*)&MKl[NX][r * 68 + j8] = mA; *(float4*)&MKl[NX][r * 68 + j8 + 4] = mB; \
    if (tid < 128) { \
      int t_ = tid >> 2, s8_ = (tid & 3) * 8; \
      *(float4*)&BqMl[NX][t_ * 36 + s8_] = bqA; \
      *(float4*)&BqMl[NX][t_ * 36 + s8_ + 4] = bqB; \
      Vl[NX][t_ * 5 + (tid & 3)] = vr; \
    } \
    if (tid < 32) { bll[NX][tid] = blr; dnl[NX][tid] = dnb; } \
    if (tid < 64) zil[NX][tid] = zi; \
  }

  KQLOAD(0, kAc, kBc, qAc, qBc);
  AUXLOAD(0);
  AUXSTORE(0);
  __syncthreads();

  for (int c = 0; c < 64; ++c) {
    int cur = c & 1, nxt = cur ^ 1;
    int cn = (c + 1 < 64) ? c + 1 : 63;
    KQLOAD(cn, kAn, kBn, qAn, qBn);   // HBM/L2 latency hides under P1
    AUXLOAD(cn);
    // ---- P1: K/Q from registers; S/z broadcast reads; shfl-reduce over 8 slices ----
    {
      float aK[4], aY[4];
#pragma unroll
      for (int i = 0; i < 4; ++i) {
        float4 s0 = *(float4*)&S0l[i * 68 + j8];
        float4 s1 = *(float4*)&S0l[i * 68 + j8 + 4];
        aK[i] = dot4(kAc, s0) + dot4(kBc, s1);
        aY[i] = dot4(qAc, s0) + dot4(qBc, s1);
      }
      float4 z0 = *(float4*)&z0l[j8];
      float4 z1 = *(float4*)&z0l[j8 + 4];
      float aZ = dot4(qAc, z0) + dot4(qBc, z1);
#pragma unroll
      for (int off = 1; off <= 4; off <<= 1) {
#pragma unroll
        for (int i = 0; i < 4; ++i) {
          aK[i] += __shfl_xor(aK[i], off);
          aY[i] += __shfl_xor(aY[i], off);
        }
        aZ += __shfl_xor(aZ, off);
      }
      if (js == 0) {
        float be = bll[cur][r];
#pragma unroll
        for (int i = 0; i < 4; ++i) {
          Rtl[i * 36 + r] = be * (Vl[cur][r * 5 + i] - aK[i]);
          Y0l[r * 5 + i] = aY[i];
        }
        qzl[r] = aZ;
      }
    }
    __syncthreads();
    // ---- P2: S-update + z (threads 0-127) || y-out (threads 128-255) ----
    if (tid < 128) {
      int i2 = tid >> 5;
      int j2 = (tid & 31) * 2;
      float a0 = S0l[i2 * 68 + j2];
      float a1 = S0l[i2 * 68 + j2 + 1];
#pragma unroll
      for (int s4i = 0; s4i < 8; ++s4i) {
        float4 rt = *(float4*)&Rtl[i2 * 36 + s4i * 4];
        float2 m0 = *(float2*)&MKl[cur][(s4i * 4 + 0) * 68 + j2];
        float2 m1 = *(float2*)&MKl[cur][(s4i * 4 + 1) * 68 + j2];
        float2 m2 = *(float2*)&MKl[cur][(s4i * 4 + 2) * 68 + j2];
        float2 m3 = *(float2*)&MKl[cur][(s4i * 4 + 3) * 68 + j2];
        a0 += rt.x * m0.x + rt.y * m1.x + rt.z * m2.x + rt.w * m3.x;
        a1 += rt.x * m0.y + rt.y * m1.y + rt.z * m2.y + rt.w * m3.y;
      }
      S0l[i2 * 68 + j2] = a0;
      S0l[i2 * 68 + j2 + 1] = a1;
      if (tid < 64) z0l[tid] += zil[cur][tid];
    } else {
      int t = (tid >> 2) & 31;
      int i = tid & 3;
      float acc = Y0l[t * 5 + i];
#pragma unroll
      for (int s4i = 0; s4i < 8; ++s4i)
        acc += dot4(*(float4*)&BqMl[cur][t * 36 + s4i * 4], *(float4*)&Rtl[i * 36 + s4i * 4]);
      float y = acc / (qzl[t] + dnl[cur][t] + 1e-6f);
      ys[(size_t)(b * L_ + c * 32 + t) * 1024 + h * 64 + i0 + i] = y;
    }
    AUXSTORE(nxt);
    // rotate K/Q register double-buffer (register moves, no memory)
    kAc = kAn; kBc = kBn; qAc = qAn; qBc = qBn;
    __syncthreads();
  }
#undef KQLOAD
#undef AUXLOAD
#undef AUXSTORE
  {
    int i = tid >> 6, j = tid & 63;
    outS[((size_t)(bh * 64) + i0 + i) * 64 + j] = S0l[i * 68 + j];
  }
  if (grp == 0 && tid < 64) outZ[bh * 64 + tid] = z0l[tid];
}

extern "C" void kernel_launch(void* const* d_in, const int* in_sizes, int n_in,
                              void* d_out, int out_size, void* d_ws, size_t ws_size,
                              hipStream_t stream) {
  const float* x     = (const float*)d_in[0];
  const float* Wqkv  = (const float*)d_in[1];
  const float* Wout  = (const float*)d_in[2];
  const float* Wgate = (const float*)d_in[3];
  const float* bgate = (const float*)d_in[4];
  const float* fn_g  = (const float*)d_in[5];
  const float* fn_b  = (const float*)d_in[6];
  const float* dn_g  = (const float*)d_in[7];
  const float* dn_b  = (const float*)d_in[8];
  const float* dWq   = (const float*)d_in[9];
  const float* dWk   = (const float*)d_in[10];
  const float* dWv   = (const float*)d_in[11];
  const float* dWo   = (const float*)d_in[12];
  const float* Wbeta = (const float*)d_in[13];
  const float* bbeta = (const float*)d_in[14];
  const float* cq_w  = (const float*)d_in[15];
  const float* cq_b  = (const float*)d_in[16];
  const float* ck_w  = (const float*)d_in[17];
  const float* ck_b  = (const float*)d_in[18];
  const float* ln_g  = (const float*)d_in[19];
  const float* ln_b  = (const float*)d_in[20];

  float* ws = (float*)d_ws;
  short* qkvh   = (short*)ws;      // [0,6.3M floats) as bf16; dead after attn
  float* dv     = ws;              // [0,4M)  after attn
  float* dqc    = ws + 4194304;    // [4M,8M)   after attn
  float* dkc    = ws + 8388608;    // [8M,12M)  after attn (written by convnorm)
  float* attnO  = ws + 12582912;   // [12M,16M)
  short* wtg    = (short*)(ws + 12582912); // [12M,12.5M) after attnO dead
  short* Wvt    = (short*)(ws + 14680064); // [14M,14.5M) dead after gemm_bt2
  float* denB_g = ws + 12582912;   // [12M,+64K) prep output (after wtg dead)
  float* zinc_g = ws + 12582912 + 65536;   // [+64K,+192K)
  float* BqM_g  = ws + 14680064;   // [14M,16M) prep output (after Wvt dead)
  float* do1    = ws + 12582912;   // after delta (denB/zinc dead)
  float* fo     = ws + 16777216;   // [16M,20M)
  float* dqp    = ws + 20971520;   // [20M,24M)
  float* gpre   = ws + 20971520;
  float* dkp    = ws + 25165824;   // [24M,28M) dead after convnorm
  float* MK_g   = ws + 25165824;   // [24M,28M) prep output (reuses dkp)
  float* betab  = ws + 29360128;   // [28M,+64K floats)

  short* Wqkvt = (short*)(ws + 20971520); // [20M,21.57M); dead after gemm_bt_h
  short* Woutt = (short*)(ws + 29426688); // [28M+64K, +0.5M)
  short* Wot   = (short*)(ws + 4194304);  // dqc dead after delta

  // split-precision dWq/dWk (bf16 hi/lo) @ [8M,10M) floats; live only for gemm_bt_split2
  short* Wqh = (short*)(ws + 8388608);   // [8.0M, 8.5M)
  short* Wql = (short*)(ws + 8912896);   // [8.5M, 9.0M)
  short* Wkh = (short*)(ws + 9437184);   // [9.0M, 9.5M)
  short* Wkl = (short*)(ws + 9961472);   // [9.5M,10.0M)

  float* out  = (float*)d_out;
  float* outS = out + 4194304;
  float* outZ = out + 4325376;
  float* ysb  = out;               // ys lives in d_out[0,4M): consumed by gemm_bt -> do1,
                                   // then ln2mix overwrites out (after reading do1). No alias hazard.

  // ---- flash branch ----
  tcast<<<dim3(48, 16), 256, 0, stream>>>(Wqkv, Wqkvt, 3072, 1024);          // Wqkvt@[20M); dqp written later
  gemm_bt_h<<<dim3(24, 32), 256, 0, stream>>>(x, Wqkvt, qkvh, 3072, 1024);   // qkv bf16 @[0,6.3M)
  attn_mfma<<<dim3(32, H_, B_), 256, 0, stream>>>(qkvh, attnO);
  tcast<<<dim3(16, 16), 256, 0, stream>>>(Wout, Woutt, 1024, 1024);          // Woutt@[28M+64K)
  gemm_bt<64><<<dim3(16, 32), 256, 0, stream>>>(attnO, Woutt, fo, 1024, 1024);
  ln_kernel<<<4096, 256, 0, stream>>>(fo, fn_g, fn_b);
  // ---- delta branch ----
  tcast_split2<<<dim3(16, 16, 2), 256, 0, stream>>>(dWq, dWk, Wqh, Wql, Wkh, Wkl);
  gemm_bt_split2<<<dim3(16, 32, 2), 256, 0, stream>>>(x, Wqh, Wql, Wkh, Wkl, dqp, dkp); // kills Wqkvt
  convnorm_kernel<<<dim3(16384, 2), 256, 0, stream>>>(dqp, dkp, cq_w, cq_b, ck_w, ck_b, dqc, dkc); // kills qkvh + split weights
  beta_kernel<<<4096, 256, 0, stream>>>(x, Wbeta, bbeta, betab);
  tcast2<<<dim3(16, 16, 2), 256, 0, stream>>>(dWv, Wgate, Wvt, wtg);         // attnO dead; Wvt@14M, wtg@12M
  gemm_bt2<<<dim3(16, 32, 2), 256, 0, stream>>>(x, Wvt, wtg, dv, gpre);      // gpre kills dqp (dead)
  prep_kernel<<<dim3(64, 32), 256, 0, stream>>>(dqc, dkc, betab, MK_g, BqM_g, denB_g, zinc_g); // kills wtg/Wvt/dkp
  delta_kernel<<<512, 256, 0, stream>>>(dqc, dkc, dv, betab, MK_g, BqM_g, denB_g, zinc_g, ysb, outS, outZ);
  tcast<<<dim3(16, 16), 256, 0, stream>>>(dWo, Wot, 1024, 1024);             // dqc dead
  gemm_bt<64><<<dim3(16, 32), 256, 0, stream>>>(ysb, Wot, do1, 1024, 1024);  // do1 kills denB/zinc
  ln2mix_kernel<<<4096, 256, 0, stream>>>(do1, ln_g, ln_b, dn_g, dn_b, gpre, bgate, fo, out);
}

// Round 7
// 701.677 us; speedup vs baseline: 1.1274x; 1.0694x over previous
//
#include <hip/hip_runtime.h>
#include <hip/hip_bf16.h>

constexpr int B_ = 2, L_ = 2048, D_ = 1024, H_ = 16;

using bf16x8 = __attribute__((ext_vector_type(8))) short;
using f32x4  = __attribute__((ext_vector_type(4))) float;

__device__ __forceinline__ short f2b(float f) {
  union { float f; unsigned int u; } v; v.f = f;
  unsigned int r = (v.u + 0x7FFFu + ((v.u >> 16) & 1u)) >> 16;
  return (short)r;
}
__device__ __forceinline__ float b2f(unsigned short h) {
  union { unsigned int u; float f; } v; v.u = ((unsigned int)h) << 16; return v.f;
}
__device__ __forceinline__ void split2(float x, float y, unsigned int& h, unsigned int& l) {
  unsigned short hx = (unsigned short)f2b(x), hy = (unsigned short)f2b(y);
  h = (unsigned int)hx | ((unsigned int)hy << 16);
  unsigned short lx = (unsigned short)f2b(x - b2f(hx)), ly = (unsigned short)f2b(y - b2f(hy));
  l = (unsigned int)lx | ((unsigned int)ly << 16);
}
__device__ __forceinline__ float dot4(float4 a, float4 b) {
  return a.x * b.x + a.y * b.y + a.z * b.z + a.w * b.w;
}

// ---------------- transpose+cast: W[K,N] fp32 -> Wt[N,K] bf16 ----------------
__global__ __launch_bounds__(256) void tcast(const float* __restrict__ W, short* __restrict__ Wt,
                                             int N, int K) {
  __shared__ float T[64][65];
  int n0 = blockIdx.x * 64, k0 = blockIdx.y * 64;
  int tid = threadIdx.x;
#pragma unroll
  for (int i = 0; i < 16; ++i) {
    int idx = i * 256 + tid;
    int r = idx >> 6, c = idx & 63;
    T[r][c] = W[(size_t)(k0 + r) * N + n0 + c];
  }
  __syncthreads();
#pragma unroll
  for (int i = 0; i < 16; ++i) {
    int idx = i * 256 + tid;
    int rr = idx >> 6, cc = idx & 63;
    Wt[(size_t)(n0 + rr) * K + k0 + cc] = f2b(T[cc][rr]);
  }
}

// two-weight tcast (1024x1024 each), blockIdx.z selects
__global__ __launch_bounds__(256) void tcast2(const float* __restrict__ W1, const float* __restrict__ W2,
                                              short* __restrict__ Wt1, short* __restrict__ Wt2) {
  __shared__ float T[64][65];
  const float* W = blockIdx.z ? W2 : W1;
  short* Wt = blockIdx.z ? Wt2 : Wt1;
  int n0 = blockIdx.x * 64, k0 = blockIdx.y * 64;
  int tid = threadIdx.x;
#pragma unroll
  for (int i = 0; i < 16; ++i) {
    int idx = i * 256 + tid;
    int r = idx >> 6, c = idx & 63;
    T[r][c] = W[(size_t)(k0 + r) * 1024 + n0 + c];
  }
  __syncthreads();
#pragma unroll
  for (int i = 0; i < 16; ++i) {
    int idx = i * 256 + tid;
    int rr = idx >> 6, cc = idx & 63;
    Wt[(size_t)(n0 + rr) * 1024 + k0 + cc] = f2b(T[cc][rr]);
  }
}

// two-weight split tcast: W[K,N] fp32 -> (Wh,Wl)[N,K] bf16 hi/lo pair, z selects weight
__global__ __launch_bounds__(256) void tcast_split2(const float* __restrict__ W1, const float* __restrict__ W2,
                                                    short* __restrict__ Wh1, short* __restrict__ Wl1,
                                                    short* __restrict__ Wh2, short* __restrict__ Wl2) {
  __shared__ float T[64][65];
  const float* W = blockIdx.z ? W2 : W1;
  short* Wh = blockIdx.z ? Wh2 : Wh1;
  short* Wl = blockIdx.z ? Wl2 : Wl1;
  int n0 = blockIdx.x * 64, k0 = blockIdx.y * 64;
  int tid = threadIdx.x;
#pragma unroll
  for (int i = 0; i < 16; ++i) {
    int idx = i * 256 + tid;
    int r = idx >> 6, c = idx & 63;
    T[r][c] = W[(size_t)(k0 + r) * 1024 + n0 + c];
  }
  __syncthreads();
#pragma unroll
  for (int i = 0; i < 16; ++i) {
    int idx = i * 256 + tid;
    int rr = idx >> 6, cc = idx & 63;
    float w = T[cc][rr];
    short h = f2b(w);
    short l = f2b(w - b2f((unsigned short)h));
    size_t o = (size_t)(n0 + rr) * 1024 + k0 + cc;
    Wh[o] = h;
    Wl[o] = l;
  }
}

// ---------------- MFMA GEMM core (fp32 A) ----------------
template <int BN, typename CT>
__device__ __forceinline__ void gemm_bt_body(const float* __restrict__ A, const short* __restrict__ Wt,
                                             CT* __restrict__ C, int N, int K, int bx, int by) {
  constexpr int MT = (BN == 128) ? 4 : 2;
  constexpr int NT = 4;
  __shared__ __align__(16) short As[128 * 32];
  __shared__ __align__(16) short Bs[BN * 32];
  int tid = threadIdx.x;
  int wave = tid >> 6, lane = tid & 63, quad = lane >> 4, l15 = lane & 15;
  int m0 = by * 128, n0 = bx * BN;
  int wm = (BN == 128) ? (wave >> 1) * 64 : wave * 32;
  int wn = (BN == 128) ? (wave & 1) * 64 : 0;
  f32x4 acc[MT][NT];
#pragma unroll
  for (int mt = 0; mt < MT; ++mt)
#pragma unroll
    for (int nt = 0; nt < NT; ++nt) acc[mt][nt] = (f32x4){0.f, 0.f, 0.f, 0.f};

  for (int k0 = 0; k0 < K; k0 += 32) {
    __syncthreads();
#pragma unroll
    for (int i = 0; i < 2; ++i) {
      int chunk = i * 256 + tid;
      int m = chunk >> 2, kc = (chunk & 3) * 8;
      const float* ap = A + (size_t)(m0 + m) * K + k0 + kc;
      float4 a0 = *(const float4*)ap;
      float4 a1 = *(const float4*)(ap + 4);
      __hip_bfloat162 c0 = __float22bfloat162_rn(make_float2(a0.x, a0.y));
      __hip_bfloat162 c1 = __float22bfloat162_rn(make_float2(a0.z, a0.w));
      __hip_bfloat162 c2 = __float22bfloat162_rn(make_float2(a1.x, a1.y));
      __hip_bfloat162 c3 = __float22bfloat162_rn(make_float2(a1.z, a1.w));
      uint4 u;
      u.x = *(unsigned int*)&c0; u.y = *(unsigned int*)&c1;
      u.z = *(unsigned int*)&c2; u.w = *(unsigned int*)&c3;
      *(uint4*)&As[m * 32 + kc] = u;
    }
#pragma unroll
    for (int i = 0; i < BN * 4 / 256; ++i) {
      int chunk = i * 256 + tid;
      int n = chunk >> 2, kc = (chunk & 3) * 8;
      uint4 w = *(const uint4*)(Wt + (size_t)(n0 + n) * K + k0 + kc);
      *(uint4*)&Bs[n * 32 + kc] = w;
    }
    __syncthreads();
    bf16x8 af[MT], bf[NT];
#pragma unroll
    for (int mt = 0; mt < MT; ++mt) af[mt] = *(bf16x8*)&As[(wm + mt * 16 + l15) * 32 + quad * 8];
#pragma unroll
    for (int nt = 0; nt < NT; ++nt) bf[nt] = *(bf16x8*)&Bs[(wn + nt * 16 + l15) * 32 + quad * 8];
#pragma unroll
    for (int mt = 0; mt < MT; ++mt)
#pragma unroll
      for (int nt = 0; nt < NT; ++nt)
        acc[mt][nt] = __builtin_amdgcn_mfma_f32_16x16x32_bf16(af[mt], bf[nt], acc[mt][nt], 0, 0, 0);
  }
#pragma unroll
  for (int mt = 0; mt < MT; ++mt)
#pragma unroll
    for (int nt = 0; nt < NT; ++nt)
#pragma unroll
      for (int r = 0; r < 4; ++r) {
        size_t idx = (size_t)(m0 + wm + mt * 16 + quad * 4 + r) * N + n0 + wn + nt * 16 + l15;
        if constexpr (sizeof(CT) == 2) C[idx] = f2b(acc[mt][nt][r]);
        else C[idx] = acc[mt][nt][r];
      }
}

// bf16-output qkv GEMM
__global__ __launch_bounds__(256) void gemm_bt_h(const float* __restrict__ A, const short* __restrict__ Wt,
                                                 short* __restrict__ C, int N, int K) {
  gemm_bt_body<128, short>(A, Wt, C, N, K, blockIdx.x, blockIdx.y);
}

// dual fp32-A GEMM: z selects (Wt1->C1) vs (Wt2->C2), 1024x1024
__global__ __launch_bounds__(256) void gemm_bt2(const float* __restrict__ A, const short* __restrict__ Wt1,
                                                const short* __restrict__ Wt2, float* __restrict__ C1,
                                                float* __restrict__ C2) {
  gemm_bt_body<64, float>(A, blockIdx.z ? Wt2 : Wt1, blockIdx.z ? C2 : C1, 1024, 1024,
                          blockIdx.x, blockIdx.y);
}

// dual bf16-A GEMM: z=0: A1@Wt1->C1, z=1: A2@Wt2->C2 (A already bf16, 1024x1024)
__global__ __launch_bounds__(256) void gemm_bt2_hA(const short* __restrict__ A1, const short* __restrict__ Wt1,
                                                   const short* __restrict__ A2, const short* __restrict__ Wt2,
                                                   float* __restrict__ C1, float* __restrict__ C2) {
  constexpr int K = 1024, N = 1024;
  const short* A = blockIdx.z ? A2 : A1;
  const short* Wt = blockIdx.z ? Wt2 : Wt1;
  float* C = blockIdx.z ? C2 : C1;
  __shared__ __align__(16) short As[128 * 32];
  __shared__ __align__(16) short Bs[64 * 32];
  int tid = threadIdx.x;
  int wave = tid >> 6, lane = tid & 63, quad = lane >> 4, l15 = lane & 15;
  int m0 = blockIdx.y * 128, n0 = blockIdx.x * 64;
  int wm = wave * 32;
  f32x4 acc[2][4];
#pragma unroll
  for (int mt = 0; mt < 2; ++mt)
#pragma unroll
    for (int nt = 0; nt < 4; ++nt) acc[mt][nt] = (f32x4){0.f, 0.f, 0.f, 0.f};
  for (int k0 = 0; k0 < K; k0 += 32) {
    __syncthreads();
#pragma unroll
    for (int i = 0; i < 2; ++i) {
      int chunk = i * 256 + tid;
      int m = chunk >> 2, kc = (chunk & 3) * 8;
      *(uint4*)&As[m * 32 + kc] = *(const uint4*)(A + (size_t)(m0 + m) * K + k0 + kc);
    }
    {
      int n = tid >> 2, kc = (tid & 3) * 8;
      *(uint4*)&Bs[n * 32 + kc] = *(const uint4*)(Wt + (size_t)(n0 + n) * K + k0 + kc);
    }
    __syncthreads();
    bf16x8 af[2], bf[4];
#pragma unroll
    for (int mt = 0; mt < 2; ++mt) af[mt] = *(bf16x8*)&As[(wm + mt * 16 + l15) * 32 + quad * 8];
#pragma unroll
    for (int nt = 0; nt < 4; ++nt) bf[nt] = *(bf16x8*)&Bs[(nt * 16 + l15) * 32 + quad * 8];
#pragma unroll
    for (int mt = 0; mt < 2; ++mt)
#pragma unroll
      for (int nt = 0; nt < 4; ++nt)
        acc[mt][nt] = __builtin_amdgcn_mfma_f32_16x16x32_bf16(af[mt], bf[nt], acc[mt][nt], 0, 0, 0);
  }
#pragma unroll
  for (int mt = 0; mt < 2; ++mt)
#pragma unroll
    for (int nt = 0; nt < 4; ++nt)
#pragma unroll
      for (int r = 0; r < 4; ++r) {
        size_t idx = (size_t)(m0 + wm + mt * 16 + quad * 4 + r) * N + n0 + nt * 16 + l15;
        C[idx] = acc[mt][nt][r];
      }
}

// ---------------- split-precision MFMA GEMM: C = A@W with ~fp32 accuracy ----------------
__global__ __launch_bounds__(256) void gemm_bt_split2(const float* __restrict__ A,
                                                      const short* __restrict__ Wh1, const short* __restrict__ Wl1,
                                                      const short* __restrict__ Wh2, const short* __restrict__ Wl2,
                                                      float* __restrict__ C1, float* __restrict__ C2) {
  constexpr int K = 1024, N = 1024;
  const short* Wh = blockIdx.z ? Wh2 : Wh1;
  const short* Wl = blockIdx.z ? Wl2 : Wl1;
  float* C = blockIdx.z ? C2 : C1;
  __shared__ __align__(16) short Ash[128 * 32];
  __shared__ __align__(16) short Asl[128 * 32];
  __shared__ __align__(16) short Bsh[64 * 32];
  __shared__ __align__(16) short Bsl[64 * 32];
  int tid = threadIdx.x;
  int wave = tid >> 6, lane = tid & 63, quad = lane >> 4, l15 = lane & 15;
  int m0 = blockIdx.y * 128, n0 = blockIdx.x * 64;
  int wm = wave * 32;
  f32x4 acc[2][4];
#pragma unroll
  for (int mt = 0; mt < 2; ++mt)
#pragma unroll
    for (int nt = 0; nt < 4; ++nt) acc[mt][nt] = (f32x4){0.f, 0.f, 0.f, 0.f};

  for (int k0 = 0; k0 < K; k0 += 32) {
    __syncthreads();
#pragma unroll
    for (int i = 0; i < 2; ++i) {
      int chunk = i * 256 + tid;
      int m = chunk >> 2, kc = (chunk & 3) * 8;
      const float* ap = A + (size_t)(m0 + m) * K + k0 + kc;
      float4 a0 = *(const float4*)ap;
      float4 a1 = *(const float4*)(ap + 4);
      uint4 uh, ul;
      split2(a0.x, a0.y, uh.x, ul.x);
      split2(a0.z, a0.w, uh.y, ul.y);
      split2(a1.x, a1.y, uh.z, ul.z);
      split2(a1.z, a1.w, uh.w, ul.w);
      *(uint4*)&Ash[m * 32 + kc] = uh;
      *(uint4*)&Asl[m * 32 + kc] = ul;
    }
    {
      int n = tid >> 2, kc = (tid & 3) * 8;
      size_t off = (size_t)(n0 + n) * K + k0 + kc;
      *(uint4*)&Bsh[n * 32 + kc] = *(const uint4*)(Wh + off);
      *(uint4*)&Bsl[n * 32 + kc] = *(const uint4*)(Wl + off);
    }
    __syncthreads();
    bf16x8 ah[2], al[2], bh[4], bl[4];
#pragma unroll
    for (int mt = 0; mt < 2; ++mt) {
      ah[mt] = *(bf16x8*)&Ash[(wm + mt * 16 + l15) * 32 + quad * 8];
      al[mt] = *(bf16x8*)&Asl[(wm + mt * 16 + l15) * 32 + quad * 8];
    }
#pragma unroll
    for (int nt = 0; nt < 4; ++nt) {
      bh[nt] = *(bf16x8*)&Bsh[(nt * 16 + l15) * 32 + quad * 8];
      bl[nt] = *(bf16x8*)&Bsl[(nt * 16 + l15) * 32 + quad * 8];
    }
#pragma unroll
    for (int mt = 0; mt < 2; ++mt)
#pragma unroll
      for (int nt = 0; nt < 4; ++nt) {
        f32x4 a = acc[mt][nt];
        a = __builtin_amdgcn_mfma_f32_16x16x32_bf16(al[mt], bh[nt], a, 0, 0, 0);
        a = __builtin_amdgcn_mfma_f32_16x16x32_bf16(ah[mt], bl[nt], a, 0, 0, 0);
        a = __builtin_amdgcn_mfma_f32_16x16x32_bf16(ah[mt], bh[nt], a, 0, 0, 0);
        acc[mt][nt] = a;
      }
  }
#pragma unroll
  for (int mt = 0; mt < 2; ++mt)
#pragma unroll
    for (int nt = 0; nt < 4; ++nt)
#pragma unroll
      for (int r = 0; r < 4; ++r) {
        size_t idx = (size_t)(m0 + wm + mt * 16 + quad * 4 + r) * N + n0 + nt * 16 + l15;
        C[idx] = acc[mt][nt][r];
      }
}

// ================= fused attn + delta (shared-LDS overlay, block-range split) =================
struct DeltaSmem {
  float MKl[2][32 * 68];
  float BqMl[2][32 * 36];
  float Vl[2][32 * 5];
  float bll[2][32];
  float dnl[2][32];
  float zil[2][64];
  float S0l[4 * 68];
  float Y0l[32 * 5];
  float Rtl[4 * 36];
  float z0l[64];
  float qzl[32];
};
struct AttnSmem {
  short Kl[64 * 64];
  short Vt[64 * 64];
  short Pl[64 * 64];
};

__device__ __forceinline__ void delta_body(char* smraw, int bidx,
                                           const float* __restrict__ dq, const float* __restrict__ dk,
                                           const float* __restrict__ dv, const float* __restrict__ beta,
                                           const float* __restrict__ MK_g, const float* __restrict__ BqM_g,
                                           const float* __restrict__ denB_g, const float* __restrict__ zinc_g,
                                           short* __restrict__ ys_h, float* __restrict__ outS,
                                           float* __restrict__ outZ) {
  DeltaSmem& sm = *reinterpret_cast<DeltaSmem*>(smraw);
  int bh = bidx & 31, grp = bidx >> 5;  // same-bh groups share an XCD
  int b = bh >> 4, h = bh & 15;
  int i0 = grp * 4;
  int tid = threadIdx.x;
  int r = tid >> 3, j8 = (tid & 7) * 8;
  int js = tid & 7;
  size_t kqbase = (size_t)(b * L_) * 1024 + h * 64;

  for (int e = tid; e < 4 * 68; e += 256) sm.S0l[e] = 0.f;
  if (tid < 64) sm.z0l[tid] = 0.f;

  float4 kAc, kBc, qAc, qBc, kAn, kBn, qAn, qBn;
  float4 mA, mB, bqA, bqB;
  bqA = bqB = make_float4(0.f, 0.f, 0.f, 0.f);
  float vr = 0.f, blr = 0.f, dnb = 0.f, zi = 0.f;

#define KQLOAD(CN, KA, KB, QA, QB) { \
    size_t rb_ = kqbase + (size_t)((CN) * 32 + r) * 1024 + j8; \
    KA = ((const float4*)(dk + rb_))[0]; KB = ((const float4*)(dk + rb_))[1]; \
    QA = ((const float4*)(dq + rb_))[0]; QB = ((const float4*)(dq + rb_))[1]; \
  }
#define AUXLOAD(CN) { \
    size_t cb_ = (size_t)(bh * 64 + (CN)); \
    const float* mkp_ = MK_g + (cb_ * 32 + r) * 64 + j8; \
    mA = ((const float4*)mkp_)[0]; mB = ((const float4*)mkp_)[1]; \
    if (tid < 128) { \
      const float* bqp_ = BqM_g + cb_ * 1024 + (tid >> 2) * 32 + (tid & 3) * 8; \
      bqA = ((const float4*)bqp_)[0]; bqB = ((const float4*)bqp_)[1]; \
      vr = dv[(size_t)(b * L_ + (CN) * 32 + (tid >> 2)) * 1024 + h * 64 + i0 + (tid & 3)]; \
    } \
    if (tid < 32) { blr = beta[(size_t)(b * L_ + (CN) * 32 + tid) * 16 + h]; dnb = denB_g[cb_ * 32 + tid]; } \
    if (tid < 64) zi = zinc_g[cb_ * 64 + tid]; \
  }
#define AUXSTORE(NX) { \
    *(float4*)&sm.MKl[NX][r * 68 + j8] = mA; *(float4*)&sm.MKl[NX][r * 68 + j8 + 4] = mB; \
    if (tid < 128) { \
      int t_ = tid >> 2, s8_ = (tid & 3) * 8; \
      *(float4*)&sm.BqMl[NX][t_ * 36 + s8_] = bqA; \
      *(float4*)&sm.BqMl[NX][t_ * 36 + s8_ + 4] = bqB; \
      sm.Vl[NX][t_ * 5 + (tid & 3)] = vr; \
    } \
    if (tid < 32) { sm.bll[NX][tid] = blr; sm.dnl[NX][tid] = dnb; } \
    if (tid < 64) sm.zil[NX][tid] = zi; \
  }

  KQLOAD(0, kAc, kBc, qAc, qBc);
  AUXLOAD(0);
  AUXSTORE(0);
  __syncthreads();

  for (int c = 0; c < 64; ++c) {
    int cur = c & 1, nxt = cur ^ 1;
    int cn = (c + 1 < 64) ? c + 1 : 63;
    KQLOAD(cn, kAn, kBn, qAn, qBn);   // HBM/L2 latency hides under P1
    AUXLOAD(cn);
    // ---- P1 ----
    {
      float aK[4], aY[4];
#pragma unroll
      for (int i = 0; i < 4; ++i) {
        float4 s0 = *(float4*)&sm.S0l[i * 68 + j8];
        float4 s1 = *(float4*)&sm.S0l[i * 68 + j8 + 4];
        aK[i] = dot4(kAc, s0) + dot4(kBc, s1);
        aY[i] = dot4(qAc, s0) + dot4(qBc, s1);
      }
      float4 z0 = *(float4*)&sm.z0l[j8];
      float4 z1 = *(float4*)&sm.z0l[j8 + 4];
      float aZ = dot4(qAc, z0) + dot4(qBc, z1);
#pragma unroll
      for (int off = 1; off <= 4; off <<= 1) {
#pragma unroll
        for (int i = 0; i < 4; ++i) {
          aK[i] += __shfl_xor(aK[i], off);
          aY[i] += __shfl_xor(aY[i], off);
        }
        aZ += __shfl_xor(aZ, off);
      }
      if (js == 0) {
        float be = sm.bll[cur][r];
#pragma unroll
        for (int i = 0; i < 4; ++i) {
          sm.Rtl[i * 36 + r] = be * (sm.Vl[cur][r * 5 + i] - aK[i]);
          sm.Y0l[r * 5 + i] = aY[i];
        }
        sm.qzl[r] = aZ;
      }
    }
    __syncthreads();
    // ---- P2 ----
    if (tid < 128) {
      int i2 = tid >> 5;
      int j2 = (tid & 31) * 2;
      float a0 = sm.S0l[i2 * 68 + j2];
      float a1 = sm.S0l[i2 * 68 + j2 + 1];
#pragma unroll
      for (int s4i = 0; s4i < 8; ++s4i) {
        float4 rt = *(float4*)&sm.Rtl[i2 * 36 + s4i * 4];
        float2 m0 = *(float2*)&sm.MKl[cur][(s4i * 4 + 0) * 68 + j2];
        float2 m1 = *(float2*)&sm.MKl[cur][(s4i * 4 + 1) * 68 + j2];
        float2 m2 = *(float2*)&sm.MKl[cur][(s4i * 4 + 2) * 68 + j2];
        float2 m3 = *(float2*)&sm.MKl[cur][(s4i * 4 + 3) * 68 + j2];
        a0 += rt.x * m0.x + rt.y * m1.x + rt.z * m2.x + rt.w * m3.x;
        a1 += rt.x * m0.y + rt.y * m1.y + rt.z * m2.y + rt.w * m3.y;
      }
      sm.S0l[i2 * 68 + j2] = a0;
      sm.S0l[i2 * 68 + j2 + 1] = a1;
      if (tid < 64) sm.z0l[tid] += sm.zil[cur][tid];
    } else {
      int t = (tid >> 2) & 31;
      int i = tid & 3;
      float acc = sm.Y0l[t * 5 + i];
#pragma unroll
      for (int s4i = 0; s4i < 8; ++s4i)
        acc += dot4(*(float4*)&sm.BqMl[cur][t * 36 + s4i * 4], *(float4*)&sm.Rtl[i * 36 + s4i * 4]);
      float y = acc / (sm.qzl[t] + sm.dnl[cur][t] + 1e-6f);
      ys_h[(size_t)(b * L_ + c * 32 + t) * 1024 + h * 64 + i0 + i] = f2b(y);
    }
    AUXSTORE(nxt);
    kAc = kAn; kBc = kBn; qAc = qAn; qBc = qBn;
    __syncthreads();
  }
#undef KQLOAD
#undef AUXLOAD
#undef AUXSTORE
  {
    int i = tid >> 6, j = tid & 63;
    outS[((size_t)(bh * 64) + i0 + i) * 64 + j] = sm.S0l[i * 68 + j];
  }
  if (grp == 0 && tid < 64) outZ[bh * 64 + tid] = sm.z0l[tid];
}

__device__ __forceinline__ void attn_body(char* smraw, int idx, const short* __restrict__ qkv,
                                          short* __restrict__ outp_h) {
  AttnSmem& sm = *reinterpret_cast<AttnSmem*>(smraw);
  int qb = 31 - (idx & 31), h = (idx >> 5) & 15, b = idx >> 9;
  int tid = threadIdx.x;
  int wave = tid >> 6, lane = tid & 63;
  int quad = lane >> 4, l15 = lane & 15;
  int qrow = qb * 64 + wave * 16 + l15;
  bf16x8 qf[2];
  {
    const short* qbase = qkv + (size_t)(b * L_ + qrow) * 3072 + h * 64;
#pragma unroll
    for (int s = 0; s < 2; ++s) qf[s] = *(const bf16x8*)(qbase + s * 32 + quad * 8);
  }
  f32x4 Of[4];
  float mrow[4], lrow[4], alpha[4];
#pragma unroll
  for (int dt = 0; dt < 4; ++dt) Of[dt] = (f32x4){0.f, 0.f, 0.f, 0.f};
#pragma unroll
  for (int r = 0; r < 4; ++r) { mrow[r] = -1e30f; lrow[r] = 0.f; }

  for (int kt = 0; kt <= qb; ++kt) {
    __syncthreads();
#pragma unroll
    for (int it = 0; it < 2; ++it) {
      int e8 = tid + it * 256;
      int key = e8 >> 3, g = e8 & 7;
      const short* src = qkv + ((size_t)((b * L_ + kt * 64 + key) * 3) + 1) * 1024 + h * 64 + g * 8;
      *(bf16x8*)&sm.Kl[key * 64 + ((g ^ (key & 7)) << 3)] = *(const bf16x8*)src;
    }
    {
      int key4 = tid >> 4;
      int d4 = tid & 15;
      const short* vsrc = qkv + ((size_t)((b * L_ + kt * 64 + key4 * 4) * 3) + 2) * 1024 + h * 64 + d4 * 4;
      short4 v0 = *(const short4*)vsrc;
      short4 v1 = *(const short4*)(vsrc + 3072);
      short4 v2 = *(const short4*)(vsrc + 6144);
      short4 v3 = *(const short4*)(vsrc + 9216);
      short vr0[4] = {v0.x, v0.y, v0.z, v0.w};
      short vr1[4] = {v1.x, v1.y, v1.z, v1.w};
      short vr2[4] = {v2.x, v2.y, v2.z, v2.w};
      short vr3[4] = {v3.x, v3.y, v3.z, v3.w};
      int kg = key4 >> 1, k7b = (key4 & 1) * 4;
#pragma unroll
      for (int jj = 0; jj < 4; ++jj) {
        int d = d4 * 4 + jj;
        short4 sv;
        sv.x = vr0[jj]; sv.y = vr1[jj]; sv.z = vr2[jj]; sv.w = vr3[jj];
        *(short4*)&sm.Vt[d * 64 + ((kg ^ (d & 7)) << 3) + k7b] = sv;
      }
    }
    __syncthreads();
    f32x4 sc[4];
#pragma unroll
    for (int nt = 0; nt < 4; ++nt) sc[nt] = (f32x4){0.f, 0.f, 0.f, 0.f};
#pragma unroll
    for (int s = 0; s < 2; ++s) {
#pragma unroll
      for (int nt = 0; nt < 4; ++nt) {
        int key = nt * 16 + l15;
        bf16x8 kf = *(bf16x8*)&sm.Kl[key * 64 + (((4 * s + quad) ^ (key & 7)) << 3)];
        sc[nt] = __builtin_amdgcn_mfma_f32_16x16x32_bf16(qf[s], kf, sc[nt], 0, 0, 0);
      }
    }
    bool diag = (kt == qb);
#pragma unroll
    for (int r = 0; r < 4; ++r) {
      float sv[4];
#pragma unroll
      for (int nt = 0; nt < 4; ++nt) {
        float v = sc[nt][r] * 0.125f;
        if (diag && (nt * 16 + l15 > wave * 16 + quad * 4 + r)) v = -1e30f;
        sv[nt] = v;
      }
      float mx = fmaxf(fmaxf(sv[0], sv[1]), fmaxf(sv[2], sv[3]));
      mx = fmaxf(mx, __shfl_xor(mx, 1));
      mx = fmaxf(mx, __shfl_xor(mx, 2));
      mx = fmaxf(mx, __shfl_xor(mx, 4));
      mx = fmaxf(mx, __shfl_xor(mx, 8));
      float mnew = fmaxf(mrow[r], mx);
      float al = __expf(mrow[r] - mnew);
      mrow[r] = mnew;
      alpha[r] = al;
      int prow = wave * 16 + quad * 4 + r;
      int r7 = prow & 7;
      float ps = 0.f;
#pragma unroll
      for (int nt = 0; nt < 4; ++nt) {
        float p = __expf(sv[nt] - mnew);
        ps += p;
        sm.Pl[prow * 64 + ((((nt << 1) + (l15 >> 3)) ^ r7) << 3) + (l15 & 7)] = f2b(p);
      }
      ps += __shfl_xor(ps, 1);
      ps += __shfl_xor(ps, 2);
      ps += __shfl_xor(ps, 4);
      ps += __shfl_xor(ps, 8);
      lrow[r] = lrow[r] * al + ps;
    }
#pragma unroll
    for (int dt = 0; dt < 4; ++dt)
#pragma unroll
      for (int r = 0; r < 4; ++r) Of[dt][r] *= alpha[r];
#pragma unroll
    for (int s = 0; s < 2; ++s) {
      bf16x8 pf = *(bf16x8*)&sm.Pl[(wave * 16 + l15) * 64 + (((4 * s + quad) ^ (l15 & 7)) << 3)];
#pragma unroll
      for (int dt = 0; dt < 4; ++dt) {
        int d = dt * 16 + l15;
        bf16x8 vf = *(bf16x8*)&sm.Vt[d * 64 + (((4 * s + quad) ^ (d & 7)) << 3)];
        Of[dt] = __builtin_amdgcn_mfma_f32_16x16x32_bf16(pf, vf, Of[dt], 0, 0, 0);
      }
    }
  }
#pragma unroll
  for (int r = 0; r < 4; ++r) alpha[r] = 1.f / lrow[r];
  int orow = qb * 64 + wave * 16 + quad * 4;
#pragma unroll
  for (int dt = 0; dt < 4; ++dt)
#pragma unroll
    for (int r = 0; r < 4; ++r)
      outp_h[(size_t)(b * L_ + orow + r) * 1024 + h * 64 + dt * 16 + l15] = f2b(Of[dt][r] * alpha[r]);
}

// blocks [0,512): delta scan. blocks [512,1536): attention. LDS overlaid.
__global__ __launch_bounds__(256) void attn_delta_fused(
    const short* __restrict__ qkv, short* __restrict__ attnO_h,
    const float* __restrict__ dq, const float* __restrict__ dk,
    const float* __restrict__ dv, const float* __restrict__ beta,
    const float* __restrict__ MK_g, const float* __restrict__ BqM_g,
    const float* __restrict__ denB_g, const float* __restrict__ zinc_g,
    short* __restrict__ ys_h, float* __restrict__ outS, float* __restrict__ outZ) {
  __shared__ __align__(16) char smem[sizeof(DeltaSmem)];
  static_assert(sizeof(DeltaSmem) >= sizeof(AttnSmem), "overlay");
  if (blockIdx.x < 512)
    delta_body(smem, blockIdx.x, dq, dk, dv, beta, MK_g, BqM_g, denB_g, zinc_g, ys_h, outS, outZ);
  else
    attn_body(smem, blockIdx.x - 512, qkv, attnO_h);
}

// ---------------- fused: LN(fo) + LN(LN(do1)) + gate mix ----------------
__global__ __launch_bounds__(256) void ln2mix_f(const float* __restrict__ X,
                                                const float* __restrict__ g1, const float* __restrict__ b1,
                                                const float* __restrict__ g2, const float* __restrict__ b2,
                                                const float* __restrict__ gpre, const float* __restrict__ bgate,
                                                const float* __restrict__ foraw,
                                                const float* __restrict__ fng, const float* __restrict__ fnb,
                                                float* __restrict__ outp) {
  int row = blockIdx.x, tid = threadIdx.x;
  const float* xr = X + (size_t)row * D_;
  const float* fr = foraw + (size_t)row * D_;
  __shared__ float rs[4], rss[4], frs[4], frss[4];
  float v[4], f[4];
  float s = 0.f, ss = 0.f, fs = 0.f, fss = 0.f;
#pragma unroll
  for (int i = 0; i < 4; ++i) {
    v[i] = xr[tid + i * 256]; s += v[i]; ss += v[i] * v[i];
    f[i] = fr[tid + i * 256]; fs += f[i]; fss += f[i] * f[i];
  }
#pragma unroll
  for (int off = 32; off; off >>= 1) {
    s += __shfl_xor(s, off); ss += __shfl_xor(ss, off);
    fs += __shfl_xor(fs, off); fss += __shfl_xor(fss, off);
  }
  if ((tid & 63) == 0) { rs[tid >> 6] = s; rss[tid >> 6] = ss; frs[tid >> 6] = fs; frss[tid >> 6] = fss; }
  __syncthreads();
  float S = rs[0] + rs[1] + rs[2] + rs[3];
  float SS = rss[0] + rss[1] + rss[2] + rss[3];
  float FS = frs[0] + frs[1] + frs[2] + frs[3];
  float FSS = frss[0] + frss[1] + frss[2] + frss[3];
  float mean = S * (1.f / 1024.f);
  float var = SS * (1.f / 1024.f) - mean * mean;
  float inv = rsqrtf(var + 1e-5f);
  float fmean = FS * (1.f / 1024.f);
  float fvar = FSS * (1.f / 1024.f) - fmean * fmean;
  float finv = rsqrtf(fvar + 1e-5f);
  s = 0.f; ss = 0.f;
#pragma unroll
  for (int i = 0; i < 4; ++i) {
    int c = tid + i * 256;
    v[i] = (v[i] - mean) * inv * g1[c] + b1[c];
    s += v[i]; ss += v[i] * v[i];
  }
#pragma unroll
  for (int off = 32; off; off >>= 1) { s += __shfl_xor(s, off); ss += __shfl_xor(ss, off); }
  __syncthreads();
  if ((tid & 63) == 0) { rs[tid >> 6] = s; rss[tid >> 6] = ss; }
  __syncthreads();
  S = rs[0] + rs[1] + rs[2] + rs[3];
  SS = rss[0] + rss[1] + rss[2] + rss[3];
  mean = S * (1.f / 1024.f);
  var = SS * (1.f / 1024.f) - mean * mean;
  inv = rsqrtf(var + 1e-5f);
#pragma unroll
  for (int i = 0; i < 4; ++i) {
    int c = tid + i * 256;
    size_t idx = (size_t)row * D_ + c;
    float w = (v[i] - mean) * inv * g2[c] + b2[c];
    float fl = (f[i] - fmean) * finv * fng[c] + fnb[c];
    float gg = 1.f / (1.f + __expf(-(gpre[idx] + bgate[c])));
    outp[idx] = gg * fl + (1.f - gg) * w;
  }
}

// ---------------- fused conv (q) / conv+L2norm (k) ----------------
__global__ __launch_bounds__(256) void convnorm_kernel(const float* __restrict__ qin, const float* __restrict__ kin,
                                                       const float* __restrict__ qw, const float* __restrict__ qb,
                                                       const float* __restrict__ kw, const float* __restrict__ kb,
                                                       float* __restrict__ qout, float* __restrict__ kout) {
  int path = blockIdx.y;
  int row = blockIdx.x * 4 + (threadIdx.x >> 6);
  int lane = threadIdx.x & 63;
  int bl = row >> 4, h = row & 15;
  int t = bl & (L_ - 1);
  int d = h * 64 + lane;
  size_t idx = (size_t)bl * D_ + d;
  const float* xin = path ? kin : qin;
  const float* w = path ? kw : qw;
  const float* bias = path ? kb : qb;
  float acc = bias[d];
#pragma unroll
  for (int j = 0; j < 4; ++j) {
    int tt = t - 3 + j;
    if (tt >= 0) acc += w[d * 4 + j] * xin[idx + (size_t)(j - 3) * D_];
  }
  if (path) {
    float n2 = acc * acc;
#pragma unroll
    for (int off = 32; off; off >>= 1) n2 += __shfl_xor(n2, off);
    acc = acc / fmaxf(sqrtf(n2), 1e-12f);
    kout[idx] = acc;
  } else {
    qout[idx] = acc;
  }
}

// ---------------- beta = sigmoid(x @ Wbeta + bbeta) ----------------
__global__ __launch_bounds__(256) void beta_kernel(const float* __restrict__ xf, const float* __restrict__ Wb,
                                                   const float* __restrict__ bb, float* __restrict__ beta) {
  int row = blockIdx.x, tid = threadIdx.x;
  int h = tid & 15, seg = tid >> 4;
  const float* xr = xf + (size_t)row * D_ + seg * 64;
  const float* wp = Wb + (seg * 64) * H_ + h;
  float p = 0.f;
  for (int k = 0; k < 64; ++k) p += xr[k] * wp[k * H_];
  __shared__ float red[16][17];
  red[seg][h] = p;
  __syncthreads();
  if (tid < 16) {
    float s = bb[tid];
#pragma unroll
    for (int s2 = 0; s2 < 16; ++s2) s += red[s2][tid];
    beta[(size_t)row * H_ + tid] = 1.f / (1.f + __expf(-s));
  }
}

// ================= chunked delta scan prep =================
__global__ __launch_bounds__(256) void prep_kernel(const float* __restrict__ dq, const float* __restrict__ dk,
                                                   const float* __restrict__ beta,
                                                   float* __restrict__ MK_g, float* __restrict__ BqM_g,
                                                   float* __restrict__ denB_g, float* __restrict__ zinc_g) {
  __shared__ __align__(16) float Kl[32 * 68];
  __shared__ __align__(16) float Ql[32 * 68];
  __shared__ __align__(16) float Ml[32 * 36];
  __shared__ __align__(16) float Xl[32 * 36];
  __shared__ __align__(16) float Bql[32 * 36];
  __shared__ __align__(16) float bl[32];
  int c = blockIdx.x, bh = blockIdx.y;
  int b = bh >> 4, h = bh & 15;
  int t0 = c * 32;
  int tid = threadIdx.x;
#pragma unroll
  for (int rep = 0; rep < 2; ++rep) {
    int id = tid * 2 + rep;
    int r = id >> 4, j4 = id & 15;
    size_t gi = (size_t)(b * L_ + t0 + r) * 1024 + h * 64 + j4 * 4;
    *(float4*)&Kl[r * 68 + j4 * 4] = *(const float4*)&dk[gi];
    *(float4*)&Ql[r * 68 + j4 * 4] = *(const float4*)&dq[gi];
  }
  if (tid < 32) bl[tid] = beta[(size_t)(b * L_ + t0 + tid) * 16 + h];
  __syncthreads();
  int t = tid >> 3, s0 = (tid & 7) * 4;
  float accA[4] = {0.f, 0.f, 0.f, 0.f}, accB[4] = {0.f, 0.f, 0.f, 0.f};
#pragma unroll
  for (int k4 = 0; k4 < 16; ++k4) {
    float4 kt = *(float4*)&Kl[t * 68 + k4 * 4];
    float4 qt = *(float4*)&Ql[t * 68 + k4 * 4];
#pragma unroll
    for (int j = 0; j < 4; ++j) {
      float4 ks = *(float4*)&Kl[(s0 + j) * 68 + k4 * 4];
      accA[j] += dot4(kt, ks);
      accB[j] += dot4(qt, ks);
    }
  }
#pragma unroll
  for (int j = 0; j < 4; ++j) {
    int s = s0 + j;
    Ml[t * 36 + s] = (s < t) ? bl[t] * accA[j] : ((s == t) ? 1.f : 0.f);
    Bql[t * 36 + s] = (s < t) ? accB[j] : 0.f;
  }
  __syncthreads();
  if (tid < 32) {
    int col = tid;
    float xr[32];
#pragma unroll
    for (int tt = 0; tt < 32; ++tt) {
      float x = (tt == col) ? 1.f : 0.f;
#pragma unroll
      for (int s = 0; s < tt; ++s) x -= Ml[tt * 36 + s] * xr[s];
      xr[tt] = x;
      Xl[tt * 36 + col] = x;
    }
  }
  __syncthreads();
  size_t cb = (size_t)(bh * 64 + c);
  {
    int s = tid >> 3, j8 = (tid & 7) * 8;
    float4 m0 = make_float4(0.f, 0.f, 0.f, 0.f);
    float4 m1 = make_float4(0.f, 0.f, 0.f, 0.f);
#pragma unroll
    for (int t2 = 0; t2 < 32; ++t2) {
      float xv = Xl[t2 * 36 + s];
      float4 k0 = *(float4*)&Kl[t2 * 68 + j8];
      float4 k1 = *(float4*)&Kl[t2 * 68 + j8 + 4];
      m0.x += xv * k0.x; m0.y += xv * k0.y; m0.z += xv * k0.z; m0.w += xv * k0.w;
      m1.x += xv * k1.x; m1.y += xv * k1.y; m1.z += xv * k1.z; m1.w += xv * k1.w;
    }
    float* mkp = MK_g + (cb * 32 + s) * 64 + j8;
    *(float4*)mkp = m0;
    *(float4*)(mkp + 4) = m1;
  }
  {
    int tt = tid >> 3, s4 = (tid & 7) * 4;
    float4 acc = make_float4(0.f, 0.f, 0.f, 0.f);
#pragma unroll
    for (int u4 = 0; u4 < 8; ++u4) {
      float4 bq = *(float4*)&Bql[tt * 36 + u4 * 4];
      float4 x0 = *(float4*)&Xl[(u4 * 4 + 0) * 36 + s4];
      float4 x1 = *(float4*)&Xl[(u4 * 4 + 1) * 36 + s4];
      float4 x2 = *(float4*)&Xl[(u4 * 4 + 2) * 36 + s4];
      float4 x3 = *(float4*)&Xl[(u4 * 4 + 3) * 36 + s4];
      acc.x += bq.x * x0.x + bq.y * x1.x + bq.z * x2.x + bq.w * x3.x;
      acc.y += bq.x * x0.y + bq.y * x1.y + bq.z * x2.y + bq.w * x3.y;
      acc.z += bq.x * x0.z + bq.y * x1.z + bq.z * x2.z + bq.w * x3.z;
      acc.w += bq.x * x0.w + bq.y * x1.w + bq.z * x2.w + bq.w * x3.w;
    }
    *(float4*)&BqM_g[cb * 1024 + tt * 32 + s4] = acc;
  }
  if (tid < 32) {
    float a = 0.f;
#pragma unroll
    for (int s4i = 0; s4i < 8; ++s4i)
      a += dot4(*(float4*)&Bql[tid * 36 + s4i * 4], *(float4*)&bl[s4i * 4]);
    denB_g[cb * 32 + tid] = a;
  }
  if (tid >= 64 && tid < 128) {
    int j = tid - 64;
    float a = 0.f;
#pragma unroll
    for (int s = 0; s < 32; ++s) a += bl[s] * Kl[s * 68 + j];
    zinc_g[cb * 64 + j] = a;
  }
}

extern "C" void kernel_launch(void* const* d_in, const int* in_sizes, int n_in,
                              void* d_out, int out_size, void* d_ws, size_t ws_size,
                              hipStream_t stream) {
  const float* x     = (const float*)d_in[0];
  const float* Wqkv  = (const float*)d_in[1];
  const float* Wout  = (const float*)d_in[2];
  const float* Wgate = (const float*)d_in[3];
  const float* bgate = (const float*)d_in[4];
  const float* fn_g  = (const float*)d_in[5];
  const float* fn_b  = (const float*)d_in[6];
  const float* dn_g  = (const float*)d_in[7];
  const float* dn_b  = (const float*)d_in[8];
  const float* dWq   = (const float*)d_in[9];
  const float* dWk   = (const float*)d_in[10];
  const float* dWv   = (const float*)d_in[11];
  const float* dWo   = (const float*)d_in[12];
  const float* Wbeta = (const float*)d_in[13];
  const float* bbeta = (const float*)d_in[14];
  const float* cq_w  = (const float*)d_in[15];
  const float* cq_b  = (const float*)d_in[16];
  const float* ck_w  = (const float*)d_in[17];
  const float* ck_b  = (const float*)d_in[18];
  const float* ln_g  = (const float*)d_in[19];
  const float* ln_b  = (const float*)d_in[20];

  float* ws = (float*)d_ws;
  // persistent-ish regions (floats)
  float* dqc    = ws;                         // [0,4M)        s3 -> s10
  float* dkc    = ws + 4194304;               // [4M,8M)       s3 -> s10
  float* dv     = ws + 8388608;               // [8M,12M)      s6 -> s10
  float* gpre   = ws + 12582912;              // [12M,16M)     s6 -> s13
  float* MK_g   = ws + 16777216;              // [16M,20M)     s9 -> s10
  float* BqM_g  = ws + 20971520;              // [20M,22M)     s9 -> s10
  float* denB_g = ws + 23068672;              // [22M,+64K)    s9 -> s10
  float* zinc_g = ws + 23134208;              // [+64K,+192K)  s9 -> s10
  float* betab  = ws + 23265280;              // [+192K,+256K) s4 -> s10
  short* qkvh   = (short*)(ws + 23330816);    // [22.25M, +6.29M floats) s8 -> s10
  // transients
  short* Wqh = (short*)(ws + 16777216);       // [16M,16.5M)   s1 -> s2
  short* Wql = (short*)(ws + 17301504);       // [16.5M,17M)
  short* Wkh = (short*)(ws + 17825792);       // [17M,17.5M)
  short* Wkl = (short*)(ws + 18350080);       // [17.5M,18M)
  float* dqp = ws + 18874368;                 // [18M,22M)     s2 -> s3
  float* dkp = ws + 23330816;                 // [22.25M,26.25M) s2 -> s3 (qkvh region, dead before s8)
  short* Wvt = (short*)(ws + 16777216);       // [16M,16.5M)   s5 -> s6 (Wqh dead)
  short* wtg = (short*)(ws + 17301504);       // [16.5M,17M)
  short* Wqkvt = (short*)(ws + 16777216);     // [16M,17.57M)  s7 -> s8 (Wvt dead; MK written s9)
  short* Woutt = (short*)(ws + 4194304);      // [4M,4.5M)     s11 -> s12 (dkc dead)
  short* Wot   = (short*)(ws + 4718592);      // [4.5M,5M)
  float* fo    = ws + 16777216;               // [16M,20M)     s12 -> s13 (MK dead)
  float* do1   = ws + 8388608;                // [8M,12M)      s12 -> s13 (dv dead)

  float* out  = (float*)d_out;
  float* outS = out + 4194304;
  float* outZ = out + 4325376;
  short* ysb_h   = (short*)out;               // d_out[0,2M floats) scratch, consumed s12, overwritten s13
  short* attnO_h = (short*)(out + 2097152);   // d_out[2M,4M floats) scratch, consumed s12

  // ---- delta-branch frontend ----
  tcast_split2<<<dim3(16, 16, 2), 256, 0, stream>>>(dWq, dWk, Wqh, Wql, Wkh, Wkl);           // s1
  gemm_bt_split2<<<dim3(16, 32, 2), 256, 0, stream>>>(x, Wqh, Wql, Wkh, Wkl, dqp, dkp);      // s2
  convnorm_kernel<<<dim3(16384, 2), 256, 0, stream>>>(dqp, dkp, cq_w, cq_b, ck_w, ck_b, dqc, dkc); // s3
  beta_kernel<<<4096, 256, 0, stream>>>(x, Wbeta, bbeta, betab);                             // s4
  tcast2<<<dim3(16, 16, 2), 256, 0, stream>>>(dWv, Wgate, Wvt, wtg);                         // s5
  gemm_bt2<<<dim3(16, 32, 2), 256, 0, stream>>>(x, Wvt, wtg, dv, gpre);                      // s6
  // ---- flash-branch frontend ----
  tcast<<<dim3(48, 16), 256, 0, stream>>>(Wqkv, Wqkvt, 3072, 1024);                          // s7
  gemm_bt_h<<<dim3(24, 32), 256, 0, stream>>>(x, Wqkvt, qkvh, 3072, 1024);                   // s8
  prep_kernel<<<dim3(64, 32), 256, 0, stream>>>(dqc, dkc, betab, MK_g, BqM_g, denB_g, zinc_g); // s9
  // ---- fused: delta scan (blocks 0-511) || attention (blocks 512-1535) ----
  attn_delta_fused<<<1536, 256, 0, stream>>>(qkvh, attnO_h, dqc, dkc, dv, betab,
                                             MK_g, BqM_g, denB_g, zinc_g, ysb_h, outS, outZ); // s10
  // ---- backend ----
  tcast2<<<dim3(16, 16, 2), 256, 0, stream>>>(Wout, dWo, Woutt, Wot);                        // s11
  gemm_bt2_hA<<<dim3(16, 32, 2), 256, 0, stream>>>(attnO_h, Woutt, ysb_h, Wot, fo, do1);     // s12
  ln2mix_f<<<4096, 256, 0, stream>>>(do1, ln_g, ln_b, dn_g, dn_b, gpre, bgate, fo, fn_g, fn_b, out); // s13
}

// Round 8
// 698.478 us; speedup vs baseline: 1.1326x; 1.0046x over previous
//
#include <hip/hip_runtime.h>
#include <hip/hip_bf16.h>

constexpr int B_ = 2, L_ = 2048, D_ = 1024, H_ = 16;

using bf16x8 = __attribute__((ext_vector_type(8))) short;
using f32x4  = __attribute__((ext_vector_type(4))) float;

__device__ __forceinline__ short f2b(float f) {
  union { float f; unsigned int u; } v; v.f = f;
  unsigned int r = (v.u + 0x7FFFu + ((v.u >> 16) & 1u)) >> 16;
  return (short)r;
}
__device__ __forceinline__ float b2f(unsigned short h) {
  union { unsigned int u; float f; } v; v.u = ((unsigned int)h) << 16; return v.f;
}
__device__ __forceinline__ void split2(float x, float y, unsigned int& h, unsigned int& l) {
  unsigned short hx = (unsigned short)f2b(x), hy = (unsigned short)f2b(y);
  h = (unsigned int)hx | ((unsigned int)hy << 16);
  unsigned short lx = (unsigned short)f2b(x - b2f(hx)), ly = (unsigned short)f2b(y - b2f(hy));
  l = (unsigned int)lx | ((unsigned int)ly << 16);
}
__device__ __forceinline__ float dot4(float4 a, float4 b) {
  return a.x * b.x + a.y * b.y + a.z * b.z + a.w * b.w;
}

// ---------------- merged weight preprocessing: all transpose+casts in one dispatch ----------------
// idx<768: Wqkv[1024,3072]->Wqkvt ; 768..1279: dWq/dWk split hi/lo ; 1280..1791: dWv/Wgate
__global__ __launch_bounds__(256) void tcast_all(const float* __restrict__ Wqkv,
                                                 const float* __restrict__ dWq, const float* __restrict__ dWk,
                                                 const float* __restrict__ dWv, const float* __restrict__ Wgate,
                                                 short* __restrict__ Wqkvt,
                                                 short* __restrict__ Wqh, short* __restrict__ Wql,
                                                 short* __restrict__ Wkh, short* __restrict__ Wkl,
                                                 short* __restrict__ Wvt, short* __restrict__ wtg) {
  __shared__ float T[64][65];
  int idx = blockIdx.x;
  const float* W;
  short* O1;
  short* O2 = nullptr;
  int N, bx, by;
  if (idx < 768) {
    W = Wqkv; O1 = Wqkvt; N = 3072; bx = idx % 48; by = idx / 48;
  } else if (idx < 1280) {
    int rem = idx - 768; int z = rem >> 8;
    W = z ? dWk : dWq; O1 = z ? Wkh : Wqh; O2 = z ? Wkl : Wql; N = 1024;
    bx = rem & 15; by = (rem >> 4) & 15;
  } else {
    int rem = idx - 1280; int z = rem >> 8;
    W = z ? Wgate : dWv; O1 = z ? wtg : Wvt; N = 1024;
    bx = rem & 15; by = (rem >> 4) & 15;
  }
  int n0 = bx * 64, k0 = by * 64;
  int tid = threadIdx.x;
#pragma unroll
  for (int i = 0; i < 16; ++i) {
    int id2 = i * 256 + tid;
    int r = id2 >> 6, c = id2 & 63;
    T[r][c] = W[(size_t)(k0 + r) * N + n0 + c];
  }
  __syncthreads();
#pragma unroll
  for (int i = 0; i < 16; ++i) {
    int id2 = i * 256 + tid;
    int rr = id2 >> 6, cc = id2 & 63;
    float w = T[cc][rr];
    short h = f2b(w);
    size_t o = (size_t)(n0 + rr) * 1024 + k0 + cc;  // K=1024 for all
    O1[o] = h;
    if (O2) O2[o] = f2b(w - b2f((unsigned short)h));
  }
}

// two-weight tcast (1024x1024 each), blockIdx.z selects  (backend: Wout/dWo)
__global__ __launch_bounds__(256) void tcast2(const float* __restrict__ W1, const float* __restrict__ W2,
                                              short* __restrict__ Wt1, short* __restrict__ Wt2) {
  __shared__ float T[64][65];
  const float* W = blockIdx.z ? W2 : W1;
  short* Wt = blockIdx.z ? Wt2 : Wt1;
  int n0 = blockIdx.x * 64, k0 = blockIdx.y * 64;
  int tid = threadIdx.x;
#pragma unroll
  for (int i = 0; i < 16; ++i) {
    int idx = i * 256 + tid;
    int r = idx >> 6, c = idx & 63;
    T[r][c] = W[(size_t)(k0 + r) * 1024 + n0 + c];
  }
  __syncthreads();
#pragma unroll
  for (int i = 0; i < 16; ++i) {
    int idx = i * 256 + tid;
    int rr = idx >> 6, cc = idx & 63;
    Wt[(size_t)(n0 + rr) * 1024 + k0 + cc] = f2b(T[cc][rr]);
  }
}

// ---------------- MFMA GEMM core (fp32 A), shared-mem passed in ----------------
template <int BN, typename CT>
__device__ __forceinline__ void gemm_bt_body(char* smraw, const float* __restrict__ A,
                                             const short* __restrict__ Wt, CT* __restrict__ C,
                                             int N, int K, int bx, int by) {
  constexpr int MT = (BN == 128) ? 4 : 2;
  constexpr int NT = 4;
  short* As = (short*)smraw;             // 128*32
  short* Bs = (short*)(smraw + 8192);    // BN*32
  int tid = threadIdx.x;
  int wave = tid >> 6, lane = tid & 63, quad = lane >> 4, l15 = lane & 15;
  int m0 = by * 128, n0 = bx * BN;
  int wm = (BN == 128) ? (wave >> 1) * 64 : wave * 32;
  int wn = (BN == 128) ? (wave & 1) * 64 : 0;
  f32x4 acc[MT][NT];
#pragma unroll
  for (int mt = 0; mt < MT; ++mt)
#pragma unroll
    for (int nt = 0; nt < NT; ++nt) acc[mt][nt] = (f32x4){0.f, 0.f, 0.f, 0.f};

  for (int k0 = 0; k0 < K; k0 += 32) {
    __syncthreads();
#pragma unroll
    for (int i = 0; i < 2; ++i) {
      int chunk = i * 256 + tid;
      int m = chunk >> 2, kc = (chunk & 3) * 8;
      const float* ap = A + (size_t)(m0 + m) * K + k0 + kc;
      float4 a0 = *(const float4*)ap;
      float4 a1 = *(const float4*)(ap + 4);
      __hip_bfloat162 c0 = __float22bfloat162_rn(make_float2(a0.x, a0.y));
      __hip_bfloat162 c1 = __float22bfloat162_rn(make_float2(a0.z, a0.w));
      __hip_bfloat162 c2 = __float22bfloat162_rn(make_float2(a1.x, a1.y));
      __hip_bfloat162 c3 = __float22bfloat162_rn(make_float2(a1.z, a1.w));
      uint4 u;
      u.x = *(unsigned int*)&c0; u.y = *(unsigned int*)&c1;
      u.z = *(unsigned int*)&c2; u.w = *(unsigned int*)&c3;
      *(uint4*)&As[m * 32 + kc] = u;
    }
#pragma unroll
    for (int i = 0; i < BN * 4 / 256; ++i) {
      int chunk = i * 256 + tid;
      int n = chunk >> 2, kc = (chunk & 3) * 8;
      uint4 w = *(const uint4*)(Wt + (size_t)(n0 + n) * K + k0 + kc);
      *(uint4*)&Bs[n * 32 + kc] = w;
    }
    __syncthreads();
    bf16x8 af[MT], bf[NT];
#pragma unroll
    for (int mt = 0; mt < MT; ++mt) af[mt] = *(bf16x8*)&As[(wm + mt * 16 + l15) * 32 + quad * 8];
#pragma unroll
    for (int nt = 0; nt < NT; ++nt) bf[nt] = *(bf16x8*)&Bs[(wn + nt * 16 + l15) * 32 + quad * 8];
#pragma unroll
    for (int mt = 0; mt < MT; ++mt)
#pragma unroll
      for (int nt = 0; nt < NT; ++nt)
        acc[mt][nt] = __builtin_amdgcn_mfma_f32_16x16x32_bf16(af[mt], bf[nt], acc[mt][nt], 0, 0, 0);
  }
#pragma unroll
  for (int mt = 0; mt < MT; ++mt)
#pragma unroll
    for (int nt = 0; nt < NT; ++nt)
#pragma unroll
      for (int r = 0; r < 4; ++r) {
        size_t idx = (size_t)(m0 + wm + mt * 16 + quad * 4 + r) * N + n0 + wn + nt * 16 + l15;
        if constexpr (sizeof(CT) == 2) C[idx] = f2b(acc[mt][nt][r]);
        else C[idx] = acc[mt][nt][r];
      }
}

// ---------------- beta body (shared-mem passed in) ----------------
__device__ __forceinline__ void beta_body(char* smraw, const float* __restrict__ xf,
                                          const float* __restrict__ Wb, const float* __restrict__ bb,
                                          float* __restrict__ beta, int row) {
  float (*red)[17] = (float(*)[17])smraw;
  int tid = threadIdx.x;
  int h = tid & 15, seg = tid >> 4;
  const float* xr = xf + (size_t)row * D_ + seg * 64;
  const float* wp = Wb + (seg * 64) * H_ + h;
  float p = 0.f;
  for (int k = 0; k < 64; ++k) p += xr[k] * wp[k * H_];
  red[seg][h] = p;
  __syncthreads();
  if (tid < 16) {
    float s = bb[tid];
#pragma unroll
    for (int s2 = 0; s2 < 16; ++s2) s += red[s2][tid];
    beta[(size_t)row * H_ + tid] = 1.f / (1.f + __expf(-s));
  }
}

// merged: qkv GEMM (768) + dual dv/gpre GEMM (1024) + beta (4096) in one dispatch
__global__ __launch_bounds__(256) void gemm3_beta(const float* __restrict__ x,
                                                  const short* __restrict__ Wqkvt, short* __restrict__ qkvh,
                                                  const short* __restrict__ Wvt, const short* __restrict__ wtg,
                                                  float* __restrict__ dv, float* __restrict__ gpre,
                                                  const float* __restrict__ Wb, const float* __restrict__ bb,
                                                  float* __restrict__ betab) {
  __shared__ __align__(16) char smem[16384];
  int idx = blockIdx.x;
  if (idx < 768) {
    gemm_bt_body<128, short>(smem, x, Wqkvt, qkvh, 3072, 1024, idx % 24, idx / 24);
  } else if (idx < 1792) {
    int rem = idx - 768;
    int z = rem >> 9;
    gemm_bt_body<64, float>(smem, x, z ? wtg : Wvt, z ? gpre : dv, 1024, 1024, rem & 15, (rem >> 4) & 31);
  } else {
    beta_body(smem, x, Wb, bb, betab, idx - 1792);
  }
}

// dual bf16-A GEMM: z=0: A1@Wt1->C1, z=1: A2@Wt2->C2 (1024x1024)
__global__ __launch_bounds__(256) void gemm_bt2_hA(const short* __restrict__ A1, const short* __restrict__ Wt1,
                                                   const short* __restrict__ A2, const short* __restrict__ Wt2,
                                                   float* __restrict__ C1, float* __restrict__ C2) {
  constexpr int K = 1024, N = 1024;
  const short* A = blockIdx.z ? A2 : A1;
  const short* Wt = blockIdx.z ? Wt2 : Wt1;
  float* C = blockIdx.z ? C2 : C1;
  __shared__ __align__(16) short As[128 * 32];
  __shared__ __align__(16) short Bs[64 * 32];
  int tid = threadIdx.x;
  int wave = tid >> 6, lane = tid & 63, quad = lane >> 4, l15 = lane & 15;
  int m0 = blockIdx.y * 128, n0 = blockIdx.x * 64;
  int wm = wave * 32;
  f32x4 acc[2][4];
#pragma unroll
  for (int mt = 0; mt < 2; ++mt)
#pragma unroll
    for (int nt = 0; nt < 4; ++nt) acc[mt][nt] = (f32x4){0.f, 0.f, 0.f, 0.f};
  for (int k0 = 0; k0 < K; k0 += 32) {
    __syncthreads();
#pragma unroll
    for (int i = 0; i < 2; ++i) {
      int chunk = i * 256 + tid;
      int m = chunk >> 2, kc = (chunk & 3) * 8;
      *(uint4*)&As[m * 32 + kc] = *(const uint4*)(A + (size_t)(m0 + m) * K + k0 + kc);
    }
    {
      int n = tid >> 2, kc = (tid & 3) * 8;
      *(uint4*)&Bs[n * 32 + kc] = *(const uint4*)(Wt + (size_t)(n0 + n) * K + k0 + kc);
    }
    __syncthreads();
    bf16x8 af[2], bf[4];
#pragma unroll
    for (int mt = 0; mt < 2; ++mt) af[mt] = *(bf16x8*)&As[(wm + mt * 16 + l15) * 32 + quad * 8];
#pragma unroll
    for (int nt = 0; nt < 4; ++nt) bf[nt] = *(bf16x8*)&Bs[(nt * 16 + l15) * 32 + quad * 8];
#pragma unroll
    for (int mt = 0; mt < 2; ++mt)
#pragma unroll
      for (int nt = 0; nt < 4; ++nt)
        acc[mt][nt] = __builtin_amdgcn_mfma_f32_16x16x32_bf16(af[mt], bf[nt], acc[mt][nt], 0, 0, 0);
  }
#pragma unroll
  for (int mt = 0; mt < 2; ++mt)
#pragma unroll
    for (int nt = 0; nt < 4; ++nt)
#pragma unroll
      for (int r = 0; r < 4; ++r) {
        size_t idx = (size_t)(m0 + wm + mt * 16 + quad * 4 + r) * N + n0 + nt * 16 + l15;
        C[idx] = acc[mt][nt][r];
      }
}

// ---------------- split-precision MFMA GEMM: C = A@W with ~fp32 accuracy ----------------
__global__ __launch_bounds__(256) void gemm_bt_split2(const float* __restrict__ A,
                                                      const short* __restrict__ Wh1, const short* __restrict__ Wl1,
                                                      const short* __restrict__ Wh2, const short* __restrict__ Wl2,
                                                      float* __restrict__ C1, float* __restrict__ C2) {
  constexpr int K = 1024, N = 1024;
  const short* Wh = blockIdx.z ? Wh2 : Wh1;
  const short* Wl = blockIdx.z ? Wl2 : Wl1;
  float* C = blockIdx.z ? C2 : C1;
  __shared__ __align__(16) short Ash[128 * 32];
  __shared__ __align__(16) short Asl[128 * 32];
  __shared__ __align__(16) short Bsh[64 * 32];
  __shared__ __align__(16) short Bsl[64 * 32];
  int tid = threadIdx.x;
  int wave = tid >> 6, lane = tid & 63, quad = lane >> 4, l15 = lane & 15;
  int m0 = blockIdx.y * 128, n0 = blockIdx.x * 64;
  int wm = wave * 32;
  f32x4 acc[2][4];
#pragma unroll
  for (int mt = 0; mt < 2; ++mt)
#pragma unroll
    for (int nt = 0; nt < 4; ++nt) acc[mt][nt] = (f32x4){0.f, 0.f, 0.f, 0.f};

  for (int k0 = 0; k0 < K; k0 += 32) {
    __syncthreads();
#pragma unroll
    for (int i = 0; i < 2; ++i) {
      int chunk = i * 256 + tid;
      int m = chunk >> 2, kc = (chunk & 3) * 8;
      const float* ap = A + (size_t)(m0 + m) * K + k0 + kc;
      float4 a0 = *(const float4*)ap;
      float4 a1 = *(const float4*)(ap + 4);
      uint4 uh, ul;
      split2(a0.x, a0.y, uh.x, ul.x);
      split2(a0.z, a0.w, uh.y, ul.y);
      split2(a1.x, a1.y, uh.z, ul.z);
      split2(a1.z, a1.w, uh.w, ul.w);
      *(uint4*)&Ash[m * 32 + kc] = uh;
      *(uint4*)&Asl[m * 32 + kc] = ul;
    }
    {
      int n = tid >> 2, kc = (tid & 3) * 8;
      size_t off = (size_t)(n0 + n) * K + k0 + kc;
      *(uint4*)&Bsh[n * 32 + kc] = *(const uint4*)(Wh + off);
      *(uint4*)&Bsl[n * 32 + kc] = *(const uint4*)(Wl + off);
    }
    __syncthreads();
    bf16x8 ah[2], al[2], bh[4], bl[4];
#pragma unroll
    for (int mt = 0; mt < 2; ++mt) {
      ah[mt] = *(bf16x8*)&Ash[(wm + mt * 16 + l15) * 32 + quad * 8];
      al[mt] = *(bf16x8*)&Asl[(wm + mt * 16 + l15) * 32 + quad * 8];
    }
#pragma unroll
    for (int nt = 0; nt < 4; ++nt) {
      bh[nt] = *(bf16x8*)&Bsh[(nt * 16 + l15) * 32 + quad * 8];
      bl[nt] = *(bf16x8*)&Bsl[(nt * 16 + l15) * 32 + quad * 8];
    }
#pragma unroll
    for (int mt = 0; mt < 2; ++mt)
#pragma unroll
      for (int nt = 0; nt < 4; ++nt) {
        f32x4 a = acc[mt][nt];
        a = __builtin_amdgcn_mfma_f32_16x16x32_bf16(al[mt], bh[nt], a, 0, 0, 0);
        a = __builtin_amdgcn_mfma_f32_16x16x32_bf16(ah[mt], bl[nt], a, 0, 0, 0);
        a = __builtin_amdgcn_mfma_f32_16x16x32_bf16(ah[mt], bh[nt], a, 0, 0, 0);
        acc[mt][nt] = a;
      }
  }
#pragma unroll
  for (int mt = 0; mt < 2; ++mt)
#pragma unroll
    for (int nt = 0; nt < 4; ++nt)
#pragma unroll
      for (int r = 0; r < 4; ++r) {
        size_t idx = (size_t)(m0 + wm + mt * 16 + quad * 4 + r) * N + n0 + nt * 16 + l15;
        C[idx] = acc[mt][nt][r];
      }
}

// ================= fused attn + delta (shared-LDS overlay, block-range split) =================
struct DeltaSmem {        // 22.4 KB (< AttnSmem): BqM read direct from global in P2
  float MKl[2][32 * 68];
  float Vl[2][32 * 5];
  float bll[2][32];
  float dnl[2][32];
  float zil[2][64];
  float S0l[4 * 68];
  float Y0l[32 * 5];
  float Rtl[4 * 36];
  float z0l[64];
  float qzl[32];
};
struct AttnSmem {         // 24.0 KB
  short Kl[64 * 64];
  short Vt[64 * 64];
  short Pl[64 * 64];
};
constexpr size_t SMEM_MAX = sizeof(DeltaSmem) > sizeof(AttnSmem) ? sizeof(DeltaSmem) : sizeof(AttnSmem);

__device__ __forceinline__ void delta_body(char* smraw, int bidx,
                                           const float* __restrict__ dq, const float* __restrict__ dk,
                                           const float* __restrict__ dv, const float* __restrict__ beta,
                                           const float* __restrict__ MK_g, const float* __restrict__ BqM_g,
                                           const float* __restrict__ denB_g, const float* __restrict__ zinc_g,
                                           short* __restrict__ ys_h, float* __restrict__ outS,
                                           float* __restrict__ outZ) {
  DeltaSmem& sm = *reinterpret_cast<DeltaSmem*>(smraw);
  int bh = bidx & 31, grp = bidx >> 5;  // same-bh groups share an XCD
  int b = bh >> 4, h = bh & 15;
  int i0 = grp * 4;
  int tid = threadIdx.x;
  int r = tid >> 3, j8 = (tid & 7) * 8;
  int js = tid & 7;
  size_t kqbase = (size_t)(b * L_) * 1024 + h * 64;

  for (int e = tid; e < 4 * 68; e += 256) sm.S0l[e] = 0.f;
  if (tid < 64) sm.z0l[tid] = 0.f;

  float4 kAc, kBc, qAc, qBc, kAn, kBn, qAn, qBn;
  float4 mA, mB;
  float vr = 0.f, blr = 0.f, dnb = 0.f, zi = 0.f;

#define KQLOAD(CN, KA, KB, QA, QB) { \
    size_t rb_ = kqbase + (size_t)((CN) * 32 + r) * 1024 + j8; \
    KA = ((const float4*)(dk + rb_))[0]; KB = ((const float4*)(dk + rb_))[1]; \
    QA = ((const float4*)(dq + rb_))[0]; QB = ((const float4*)(dq + rb_))[1]; \
  }
#define AUXLOAD(CN) { \
    size_t cb_ = (size_t)(bh * 64 + (CN)); \
    const float* mkp_ = MK_g + (cb_ * 32 + r) * 64 + j8; \
    mA = ((const float4*)mkp_)[0]; mB = ((const float4*)mkp_)[1]; \
    if (tid < 128) { \
      vr = dv[(size_t)(b * L_ + (CN) * 32 + (tid >> 2)) * 1024 + h * 64 + i0 + (tid & 3)]; \
    } \
    if (tid < 32) { blr = beta[(size_t)(b * L_ + (CN) * 32 + tid) * 16 + h]; dnb = denB_g[cb_ * 32 + tid]; } \
    if (tid < 64) zi = zinc_g[cb_ * 64 + tid]; \
  }
#define AUXSTORE(NX) { \
    *(float4*)&sm.MKl[NX][r * 68 + j8] = mA; *(float4*)&sm.MKl[NX][r * 68 + j8 + 4] = mB; \
    if (tid < 128) sm.Vl[NX][(tid >> 2) * 5 + (tid & 3)] = vr; \
    if (tid < 32) { sm.bll[NX][tid] = blr; sm.dnl[NX][tid] = dnb; } \
    if (tid < 64) sm.zil[NX][tid] = zi; \
  }

  KQLOAD(0, kAc, kBc, qAc, qBc);
  AUXLOAD(0);
  AUXSTORE(0);
  __syncthreads();

  for (int c = 0; c < 64; ++c) {
    int cur = c & 1, nxt = cur ^ 1;
    int cn = (c + 1 < 64) ? c + 1 : 63;
    KQLOAD(cn, kAn, kBn, qAn, qBn);   // HBM/L2 latency hides under P1
    AUXLOAD(cn);
    // ---- P1 ----
    {
      float aK[4], aY[4];
#pragma unroll
      for (int i = 0; i < 4; ++i) {
        float4 s0 = *(float4*)&sm.S0l[i * 68 + j8];
        float4 s1 = *(float4*)&sm.S0l[i * 68 + j8 + 4];
        aK[i] = dot4(kAc, s0) + dot4(kBc, s1);
        aY[i] = dot4(qAc, s0) + dot4(qBc, s1);
      }
      float4 z0 = *(float4*)&sm.z0l[j8];
      float4 z1 = *(float4*)&sm.z0l[j8 + 4];
      float aZ = dot4(qAc, z0) + dot4(qBc, z1);
#pragma unroll
      for (int off = 1; off <= 4; off <<= 1) {
#pragma unroll
        for (int i = 0; i < 4; ++i) {
          aK[i] += __shfl_xor(aK[i], off);
          aY[i] += __shfl_xor(aY[i], off);
        }
        aZ += __shfl_xor(aZ, off);
      }
      if (js == 0) {
        float be = sm.bll[cur][r];
#pragma unroll
        for (int i = 0; i < 4; ++i) {
          sm.Rtl[i * 36 + r] = be * (sm.Vl[cur][r * 5 + i] - aK[i]);
          sm.Y0l[r * 5 + i] = aY[i];
        }
        sm.qzl[r] = aZ;
      }
    }
    __syncthreads();
    // ---- P2: S-update + z (0-127) || y-out with BqM from global (128-255) ----
    if (tid < 128) {
      int i2 = tid >> 5;
      int j2 = (tid & 31) * 2;
      float a0 = sm.S0l[i2 * 68 + j2];
      float a1 = sm.S0l[i2 * 68 + j2 + 1];
#pragma unroll
      for (int s4i = 0; s4i < 8; ++s4i) {
        float4 rt = *(float4*)&sm.Rtl[i2 * 36 + s4i * 4];
        float2 m0 = *(float2*)&sm.MKl[cur][(s4i * 4 + 0) * 68 + j2];
        float2 m1 = *(float2*)&sm.MKl[cur][(s4i * 4 + 1) * 68 + j2];
        float2 m2 = *(float2*)&sm.MKl[cur][(s4i * 4 + 2) * 68 + j2];
        float2 m3 = *(float2*)&sm.MKl[cur][(s4i * 4 + 3) * 68 + j2];
        a0 += rt.x * m0.x + rt.y * m1.x + rt.z * m2.x + rt.w * m3.x;
        a1 += rt.x * m0.y + rt.y * m1.y + rt.z * m2.y + rt.w * m3.y;
      }
      sm.S0l[i2 * 68 + j2] = a0;
      sm.S0l[i2 * 68 + j2 + 1] = a1;
      if (tid < 64) sm.z0l[tid] += sm.zil[cur][tid];
    } else {
      size_t cbc = (size_t)(bh * 64 + c);
      int t = (tid >> 2) & 31;
      int i = tid & 3;
      const float* bqr = BqM_g + cbc * 1024 + t * 32;  // row t (L2-resident)
      float acc = sm.Y0l[t * 5 + i];
#pragma unroll
      for (int s4i = 0; s4i < 8; ++s4i)
        acc += dot4(*(const float4*)(bqr + s4i * 4), *(float4*)&sm.Rtl[i * 36 + s4i * 4]);
      float y = acc / (sm.qzl[t] + sm.dnl[cur][t] + 1e-6f);
      ys_h[(size_t)(b * L_ + c * 32 + t) * 1024 + h * 64 + i0 + i] = f2b(y);
    }
    AUXSTORE(nxt);
    kAc = kAn; kBc = kBn; qAc = qAn; qBc = qBn;
    __syncthreads();
  }
#undef KQLOAD
#undef AUXLOAD
#undef AUXSTORE
  {
    int i = tid >> 6, j = tid & 63;
    outS[((size_t)(bh * 64) + i0 + i) * 64 + j] = sm.S0l[i * 68 + j];
  }
  if (grp == 0 && tid < 64) outZ[bh * 64 + tid] = sm.z0l[tid];
}

__device__ __forceinline__ void attn_body(char* smraw, int idx, const short* __restrict__ qkv,
                                          short* __restrict__ outp_h) {
  AttnSmem& sm = *reinterpret_cast<AttnSmem*>(smraw);
  int qb = 31 - (idx & 31), h = (idx >> 5) & 15, b = idx >> 9;
  int tid = threadIdx.x;
  int wave = tid >> 6, lane = tid & 63;
  int quad = lane >> 4, l15 = lane & 15;
  int qrow = qb * 64 + wave * 16 + l15;
  bf16x8 qf[2];
  {
    const short* qbase = qkv + (size_t)(b * L_ + qrow) * 3072 + h * 64;
#pragma unroll
    for (int s = 0; s < 2; ++s) qf[s] = *(const bf16x8*)(qbase + s * 32 + quad * 8);
  }
  f32x4 Of[4];
  float mrow[4], lrow[4], alpha[4];
#pragma unroll
  for (int dt = 0; dt < 4; ++dt) Of[dt] = (f32x4){0.f, 0.f, 0.f, 0.f};
#pragma unroll
  for (int r = 0; r < 4; ++r) { mrow[r] = -1e30f; lrow[r] = 0.f; }

  for (int kt = 0; kt <= qb; ++kt) {
    __syncthreads();
#pragma unroll
    for (int it = 0; it < 2; ++it) {
      int e8 = tid + it * 256;
      int key = e8 >> 3, g = e8 & 7;
      const short* src = qkv + ((size_t)((b * L_ + kt * 64 + key) * 3) + 1) * 1024 + h * 64 + g * 8;
      *(bf16x8*)&sm.Kl[key * 64 + ((g ^ (key & 7)) << 3)] = *(const bf16x8*)src;
    }
    {
      int key4 = tid >> 4;
      int d4 = tid & 15;
      const short* vsrc = qkv + ((size_t)((b * L_ + kt * 64 + key4 * 4) * 3) + 2) * 1024 + h * 64 + d4 * 4;
      short4 v0 = *(const short4*)vsrc;
      short4 v1 = *(const short4*)(vsrc + 3072);
      short4 v2 = *(const short4*)(vsrc + 6144);
      short4 v3 = *(const short4*)(vsrc + 9216);
      short vr0[4] = {v0.x, v0.y, v0.z, v0.w};
      short vr1[4] = {v1.x, v1.y, v1.z, v1.w};
      short vr2[4] = {v2.x, v2.y, v2.z, v2.w};
      short vr3[4] = {v3.x, v3.y, v3.z, v3.w};
      int kg = key4 >> 1, k7b = (key4 & 1) * 4;
#pragma unroll
      for (int jj = 0; jj < 4; ++jj) {
        int d = d4 * 4 + jj;
        short4 sv;
        sv.x = vr0[jj]; sv.y = vr1[jj]; sv.z = vr2[jj]; sv.w = vr3[jj];
        *(short4*)&sm.Vt[d * 64 + ((kg ^ (d & 7)) << 3) + k7b] = sv;
      }
    }
    __syncthreads();
    f32x4 sc[4];
#pragma unroll
    for (int nt = 0; nt < 4; ++nt) sc[nt] = (f32x4){0.f, 0.f, 0.f, 0.f};
#pragma unroll
    for (int s = 0; s < 2; ++s) {
#pragma unroll
      for (int nt = 0; nt < 4; ++nt) {
        int key = nt * 16 + l15;
        bf16x8 kf = *(bf16x8*)&sm.Kl[key * 64 + (((4 * s + quad) ^ (key & 7)) << 3)];
        sc[nt] = __builtin_amdgcn_mfma_f32_16x16x32_bf16(qf[s], kf, sc[nt], 0, 0, 0);
      }
    }
    bool diag = (kt == qb);
#pragma unroll
    for (int r = 0; r < 4; ++r) {
      float sv[4];
#pragma unroll
      for (int nt = 0; nt < 4; ++nt) {
        float v = sc[nt][r] * 0.125f;
        if (diag && (nt * 16 + l15 > wave * 16 + quad * 4 + r)) v = -1e30f;
        sv[nt] = v;
      }
      float mx = fmaxf(fmaxf(sv[0], sv[1]), fmaxf(sv[2], sv[3]));
      mx = fmaxf(mx, __shfl_xor(mx, 1));
      mx = fmaxf(mx, __shfl_xor(mx, 2));
      mx = fmaxf(mx, __shfl_xor(mx, 4));
      mx = fmaxf(mx, __shfl_xor(mx, 8));
      float mnew = fmaxf(mrow[r], mx);
      float al = __expf(mrow[r] - mnew);
      mrow[r] = mnew;
      alpha[r] = al;
      int prow = wave * 16 + quad * 4 + r;
      int r7 = prow & 7;
      float ps = 0.f;
#pragma unroll
      for (int nt = 0; nt < 4; ++nt) {
        float p = __expf(sv[nt] - mnew);
        ps += p;
        sm.Pl[prow * 64 + ((((nt << 1) + (l15 >> 3)) ^ r7) << 3) + (l15 & 7)] = f2b(p);
      }
      ps += __shfl_xor(ps, 1);
      ps += __shfl_xor(ps, 2);
      ps += __shfl_xor(ps, 4);
      ps += __shfl_xor(ps, 8);
      lrow[r] = lrow[r] * al + ps;
    }
#pragma unroll
    for (int dt = 0; dt < 4; ++dt)
#pragma unroll
      for (int r = 0; r < 4; ++r) Of[dt][r] *= alpha[r];
#pragma unroll
    for (int s = 0; s < 2; ++s) {
      bf16x8 pf = *(bf16x8*)&sm.Pl[(wave * 16 + l15) * 64 + (((4 * s + quad) ^ (l15 & 7)) << 3)];
#pragma unroll
      for (int dt = 0; dt < 4; ++dt) {
        int d = dt * 16 + l15;
        bf16x8 vf = *(bf16x8*)&sm.Vt[d * 64 + (((4 * s + quad) ^ (d & 7)) << 3)];
        Of[dt] = __builtin_amdgcn_mfma_f32_16x16x32_bf16(pf, vf, Of[dt], 0, 0, 0);
      }
    }
  }
#pragma unroll
  for (int r = 0; r < 4; ++r) alpha[r] = 1.f / lrow[r];
  int orow = qb * 64 + wave * 16 + quad * 4;
#pragma unroll
  for (int dt = 0; dt < 4; ++dt)
#pragma unroll
    for (int r = 0; r < 4; ++r)
      outp_h[(size_t)(b * L_ + orow + r) * 1024 + h * 64 + dt * 16 + l15] = f2b(Of[dt][r] * alpha[r]);
}

// blocks [0,512): delta scan. blocks [512,1536): attention. LDS overlaid.
__global__ __launch_bounds__(256) void attn_delta_fused(
    const short* __restrict__ qkv, short* __restrict__ attnO_h,
    const float* __restrict__ dq, const float* __restrict__ dk,
    const float* __restrict__ dv, const float* __restrict__ beta,
    const float* __restrict__ MK_g, const float* __restrict__ BqM_g,
    const float* __restrict__ denB_g, const float* __restrict__ zinc_g,
    short* __restrict__ ys_h, float* __restrict__ outS, float* __restrict__ outZ) {
  __shared__ __align__(16) char smem[SMEM_MAX];
  if (blockIdx.x < 512)
    delta_body(smem, blockIdx.x, dq, dk, dv, beta, MK_g, BqM_g, denB_g, zinc_g, ys_h, outS, outZ);
  else
    attn_body(smem, blockIdx.x - 512, qkv, attnO_h);
}

// ---------------- fused: LN(fo) + LN(LN(do1)) + gate mix ----------------
__global__ __launch_bounds__(256) void ln2mix_f(const float* __restrict__ X,
                                                const float* __restrict__ g1, const float* __restrict__ b1,
                                                const float* __restrict__ g2, const float* __restrict__ b2,
                                                const float* __restrict__ gpre, const float* __restrict__ bgate,
                                                const float* __restrict__ foraw,
                                                const float* __restrict__ fng, const float* __restrict__ fnb,
                                                float* __restrict__ outp) {
  int row = blockIdx.x, tid = threadIdx.x;
  const float* xr = X + (size_t)row * D_;
  const float* fr = foraw + (size_t)row * D_;
  __shared__ float rs[4], rss[4], frs[4], frss[4];
  float v[4], f[4];
  float s = 0.f, ss = 0.f, fs = 0.f, fss = 0.f;
#pragma unroll
  for (int i = 0; i < 4; ++i) {
    v[i] = xr[tid + i * 256]; s += v[i]; ss += v[i] * v[i];
    f[i] = fr[tid + i * 256]; fs += f[i]; fss += f[i] * f[i];
  }
#pragma unroll
  for (int off = 32; off; off >>= 1) {
    s += __shfl_xor(s, off); ss += __shfl_xor(ss, off);
    fs += __shfl_xor(fs, off); fss += __shfl_xor(fss, off);
  }
  if ((tid & 63) == 0) { rs[tid >> 6] = s; rss[tid >> 6] = ss; frs[tid >> 6] = fs; frss[tid >> 6] = fss; }
  __syncthreads();
  float S = rs[0] + rs[1] + rs[2] + rs[3];
  float SS = rss[0] + rss[1] + rss[2] + rss[3];
  float FS = frs[0] + frs[1] + frs[2] + frs[3];
  float FSS = frss[0] + frss[1] + frss[2] + frss[3];
  float mean = S * (1.f / 1024.f);
  float var = SS * (1.f / 1024.f) - mean * mean;
  float inv = rsqrtf(var + 1e-5f);
  float fmean = FS * (1.f / 1024.f);
  float fvar = FSS * (1.f / 1024.f) - fmean * fmean;
  float finv = rsqrtf(fvar + 1e-5f);
  s = 0.f; ss = 0.f;
#pragma unroll
  for (int i = 0; i < 4; ++i) {
    int c = tid + i * 256;
    v[i] = (v[i] - mean) * inv * g1[c] + b1[c];
    s += v[i]; ss += v[i] * v[i];
  }
#pragma unroll
  for (int off = 32; off; off >>= 1) { s += __shfl_xor(s, off); ss += __shfl_xor(ss, off); }
  __syncthreads();
  if ((tid & 63) == 0) { rs[tid >> 6] = s; rss[tid >> 6] = ss; }
  __syncthreads();
  S = rs[0] + rs[1] + rs[2] + rs[3];
  SS = rss[0] + rss[1] + rss[2] + rss[3];
  mean = S * (1.f / 1024.f);
  var = SS * (1.f / 1024.f) - mean * mean;
  inv = rsqrtf(var + 1e-5f);
#pragma unroll
  for (int i = 0; i < 4; ++i) {
    int c = tid + i * 256;
    size_t idx = (size_t)row * D_ + c;
    float w = (v[i] - mean) * inv * g2[c] + b2[c];
    float fl = (f[i] - fmean) * finv * fng[c] + fnb[c];
    float gg = 1.f / (1.f + __expf(-(gpre[idx] + bgate[c])));
    outp[idx] = gg * fl + (1.f - gg) * w;
  }
}

// ---------------- fused conv (q) / conv+L2norm (k) ----------------
__global__ __launch_bounds__(256) void convnorm_kernel(const float* __restrict__ qin, const float* __restrict__ kin,
                                                       const float* __restrict__ qw, const float* __restrict__ qb,
                                                       const float* __restrict__ kw, const float* __restrict__ kb,
                                                       float* __restrict__ qout, float* __restrict__ kout) {
  int path = blockIdx.y;
  int row = blockIdx.x * 4 + (threadIdx.x >> 6);
  int lane = threadIdx.x & 63;
  int bl = row >> 4, h = row & 15;
  int t = bl & (L_ - 1);
  int d = h * 64 + lane;
  size_t idx = (size_t)bl * D_ + d;
  const float* xin = path ? kin : qin;
  const float* w = path ? kw : qw;
  const float* bias = path ? kb : qb;
  float acc = bias[d];
#pragma unroll
  for (int j = 0; j < 4; ++j) {
    int tt = t - 3 + j;
    if (tt >= 0) acc += w[d * 4 + j] * xin[idx + (size_t)(j - 3) * D_];
  }
  if (path) {
    float n2 = acc * acc;
#pragma unroll
    for (int off = 32; off; off >>= 1) n2 += __shfl_xor(n2, off);
    acc = acc / fmaxf(sqrtf(n2), 1e-12f);
    kout[idx] = acc;
  } else {
    qout[idx] = acc;
  }
}

// ================= chunked delta scan prep =================
__global__ __launch_bounds__(256) void prep_kernel(const float* __restrict__ dq, const float* __restrict__ dk,
                                                   const float* __restrict__ beta,
                                                   float* __restrict__ MK_g, float* __restrict__ BqM_g,
                                                   float* __restrict__ denB_g, float* __restrict__ zinc_g) {
  __shared__ __align__(16) float Kl[32 * 68];
  __shared__ __align__(16) float Ql[32 * 68];
  __shared__ __align__(16) float Ml[32 * 36];
  __shared__ __align__(16) float Xl[32 * 36];
  __shared__ __align__(16) float Bql[32 * 36];
  __shared__ __align__(16) float bl[32];
  int c = blockIdx.x, bh = blockIdx.y;
  int b = bh >> 4, h = bh & 15;
  int t0 = c * 32;
  int tid = threadIdx.x;
#pragma unroll
  for (int rep = 0; rep < 2; ++rep) {
    int id = tid * 2 + rep;
    int r = id >> 4, j4 = id & 15;
    size_t gi = (size_t)(b * L_ + t0 + r) * 1024 + h * 64 + j4 * 4;
    *(float4*)&Kl[r * 68 + j4 * 4] = *(const float4*)&dk[gi];
    *(float4*)&Ql[r * 68 + j4 * 4] = *(const float4*)&dq[gi];
  }
  if (tid < 32) bl[tid] = beta[(size_t)(b * L_ + t0 + tid) * 16 + h];
  __syncthreads();
  int t = tid >> 3, s0 = (tid & 7) * 4;
  float accA[4] = {0.f, 0.f, 0.f, 0.f}, accB[4] = {0.f, 0.f, 0.f, 0.f};
#pragma unroll
  for (int k4 = 0; k4 < 16; ++k4) {
    float4 kt = *(float4*)&Kl[t * 68 + k4 * 4];
    float4 qt = *(float4*)&Ql[t * 68 + k4 * 4];
#pragma unroll
    for (int j = 0; j < 4; ++j) {
      float4 ks = *(float4*)&Kl[(s0 + j) * 68 + k4 * 4];
      accA[j] += dot4(kt, ks);
      accB[j] += dot4(qt, ks);
    }
  }
#pragma unroll
  for (int j = 0; j < 4; ++j) {
    int s = s0 + j;
    Ml[t * 36 + s] = (s < t) ? bl[t] * accA[j] : ((s == t) ? 1.f : 0.f);
    Bql[t * 36 + s] = (s < t) ? accB[j] : 0.f;
  }
  __syncthreads();
  if (tid < 32) {
    int col = tid;
    float xr[32];
#pragma unroll
    for (int tt = 0; tt < 32; ++tt) {
      float x = (tt == col) ? 1.f : 0.f;
#pragma unroll
      for (int s = 0; s < tt; ++s) x -= Ml[tt * 36 + s] * xr[s];
      xr[tt] = x;
      Xl[tt * 36 + col] = x;
    }
  }
  __syncthreads();
  size_t cb = (size_t)(bh * 64 + c);
  {
    int s = tid >> 3, j8 = (tid & 7) * 8;
    float4 m0 = make_float4(0.f, 0.f, 0.f, 0.f);
    float4 m1 = make_float4(0.f, 0.f, 0.f, 0.f);
#pragma unroll
    for (int t2 = 0; t2 < 32; ++t2) {
      float xv = Xl[t2 * 36 + s];
      float4 k0 = *(float4*)&Kl[t2 * 68 + j8];
      float4 k1 = *(float4*)&Kl[t2 * 68 + j8 + 4];
      m0.x += xv * k0.x; m0.y += xv * k0.y; m0.z += xv * k0.z; m0.w += xv * k0.w;
      m1.x += xv * k1.x; m1.y += xv * k1.y; m1.z += xv * k1.z; m1.w += xv * k1.w;
    }
    float* mkp = MK_g + (cb * 32 + s) * 64 + j8;
    *(float4*)mkp = m0;
    *(float4*)(mkp + 4) = m1;
  }
  {
    int tt = tid >> 3, s4 = (tid & 7) * 4;
    float4 acc = make_float4(0.f, 0.f, 0.f, 0.f);
#pragma unroll
    for (int u4 = 0; u4 < 8; ++u4) {
      float4 bq = *(float4*)&Bql[tt * 36 + u4 * 4];
      float4 x0 = *(float4*)&Xl[(u4 * 4 + 0) * 36 + s4];
      float4 x1 = *(float4*)&Xl[(u4 * 4 + 1) * 36 + s4];
      float4 x2 = *(float4*)&Xl[(u4 * 4 + 2) * 36 + s4];
      float4 x3 = *(float4*)&Xl[(u4 * 4 + 3) * 36 + s4];
      acc.x += bq.x * x0.x + bq.y * x1.x + bq.z * x2.x + bq.w * x3.x;
      acc.y += bq.x * x0.y + bq.y * x1.y + bq.z * x2.y + bq.w * x3.y;
      acc.z += bq.x * x0.z + bq.y * x1.z + bq.z * x2.z + bq.w * x3.z;
      acc.w += bq.x * x0.w + bq.y * x1.w + bq.z * x2.w + bq.w * x3.w;
    }
    *(float4*)&BqM_g[cb * 1024 + tt * 32 + s4] = acc;
  }
  if (tid < 32) {
    float a = 0.f;
#pragma unroll
    for (int s4i = 0; s4i < 8; ++s4i)
      a += dot4(*(float4*)&Bql[tid * 36 + s4i * 4], *(float4*)&bl[s4i * 4]);
    denB_g[cb * 32 + tid] = a;
  }
  if (tid >= 64 && tid < 128) {
    int j = tid - 64;
    float a = 0.f;
#pragma unroll
    for (int s = 0; s < 32; ++s) a += bl[s] * Kl[s * 68 + j];
    zinc_g[cb * 64 + j] = a;
  }
}

extern "C" void kernel_launch(void* const* d_in, const int* in_sizes, int n_in,
                              void* d_out, int out_size, void* d_ws, size_t ws_size,
                              hipStream_t stream) {
  const float* x     = (const float*)d_in[0];
  const float* Wqkv  = (const float*)d_in[1];
  const float* Wout  = (const float*)d_in[2];
  const float* Wgate = (const float*)d_in[3];
  const float* bgate = (const float*)d_in[4];
  const float* fn_g  = (const float*)d_in[5];
  const float* fn_b  = (const float*)d_in[6];
  const float* dn_g  = (const float*)d_in[7];
  const float* dn_b  = (const float*)d_in[8];
  const float* dWq   = (const float*)d_in[9];
  const float* dWk   = (const float*)d_in[10];
  const float* dWv   = (const float*)d_in[11];
  const float* dWo   = (const float*)d_in[12];
  const float* Wbeta = (const float*)d_in[13];
  const float* bbeta = (const float*)d_in[14];
  const float* cq_w  = (const float*)d_in[15];
  const float* cq_b  = (const float*)d_in[16];
  const float* ck_w  = (const float*)d_in[17];
  const float* ck_b  = (const float*)d_in[18];
  const float* ln_g  = (const float*)d_in[19];
  const float* ln_b  = (const float*)d_in[20];

  float* ws = (float*)d_ws;
  // ---- layout (floats); lifetimes annotated s1..s9 ----
  float* dqc    = ws;                      // [0, 4.19M)       s3->s6
  float* dkc    = ws + 4194304;            // [4.19M, 8.39M)   s3->s6
  float* dv     = ws + 8388608;            // [8.39M,12.58M)   s4->s6
  float* gpre   = ws + 12582912;           // [12.58M,16.78M)  s4->s9
  float* betab  = ws + 16777216;           // 64K, s4->s6 (old Wqh space, time-disjoint)
  float* denB_g = ws + 16842752;           // 64K, s5->s6
  float* zinc_g = ws + 16908288;           // 128K, s5->s6
  float* MK_g   = ws + 17039360;           // 4M,  s5->s6 (old Wql..Wqkvt space)
  short* Wqh    = (short*)(ws + 16777216); // s1->s2
  short* Wql    = (short*)(ws + 17301504); // s1->s2
  short* Wkh    = (short*)(ws + 17825792); // s1->s2
  short* Wkl    = (short*)(ws + 18350080); // s1->s2
  short* Wvt    = (short*)(ws + 18874368); // s1->s4
  short* wtg    = (short*)(ws + 19398656); // s1->s4
  short* Wqkvt  = (short*)(ws + 19922944); // 1.5M floats, s1->s4
  float* dqp    = ws + 21495808;           // 4M, s2->s3
  float* dkp    = ws + 25690112;           // 4M, s2->s3 (peak 29884416 floats = 119.5MB)
  short* qkvh   = (short*)(ws + 21495808); // 6.29M floats, s4->s6 (dqp/dkp dead)
  float* BqM_g  = ws + 27787264;           // 2M, s5->s6 (dkp tail dead, past qkvh end)
  short* Woutt  = (short*)ws;              // [0,0.52M) s7->s8 (dqc dead)
  short* Wot    = (short*)(ws + 524288);   // s7->s8
  float* do1    = ws + 4194304;            // s8->s9 (dkc dead)
  float* fo     = ws + 8388608;            // s8->s9 (dv dead)

  float* out  = (float*)d_out;
  float* outS = out + 4194304;
  float* outZ = out + 4325376;
  short* ysb_h   = (short*)out;             // d_out[0,2.1M floats) scratch, consumed s8
  short* attnO_h = (short*)(out + 2097152); // d_out[2.1M,4.19M floats) scratch, consumed s8

  // s1: all weight preprocessing in one dispatch
  tcast_all<<<1792, 256, 0, stream>>>(Wqkv, dWq, dWk, dWv, Wgate, Wqkvt, Wqh, Wql, Wkh, Wkl, Wvt, wtg);
  // s2: split-precision dq/dk GEMM
  gemm_bt_split2<<<dim3(16, 32, 2), 256, 0, stream>>>(x, Wqh, Wql, Wkh, Wkl, dqp, dkp);
  // s3: causal conv + L2norm
  convnorm_kernel<<<dim3(16384, 2), 256, 0, stream>>>(dqp, dkp, cq_w, cq_b, ck_w, ck_b, dqc, dkc);
  // s4: qkv GEMM + dv/gate GEMM + beta, one dispatch
  gemm3_beta<<<5888, 256, 0, stream>>>(x, Wqkvt, qkvh, Wvt, wtg, dv, gpre, Wbeta, bbeta, betab);
  // s5: per-chunk prep (Minv hoisted products)
  prep_kernel<<<dim3(64, 32), 256, 0, stream>>>(dqc, dkc, betab, MK_g, BqM_g, denB_g, zinc_g);
  // s6: fused delta scan (blocks 0-511) || attention (blocks 512-1535)
  attn_delta_fused<<<1536, 256, 0, stream>>>(qkvh, attnO_h, dqc, dkc, dv, betab,
                                             MK_g, BqM_g, denB_g, zinc_g, ysb_h, outS, outZ);
  // s7: backend weight tcast
  tcast2<<<dim3(16, 16, 2), 256, 0, stream>>>(Wout, dWo, Woutt, Wot);
  // s8: dual output GEMM (bf16 A)
  gemm_bt2_hA<<<dim3(16, 32, 2), 256, 0, stream>>>(attnO_h, Woutt, ysb_h, Wot, fo, do1);
  // s9: final LN/LN/gate mix
  ln2mix_f<<<4096, 256, 0, stream>>>(do1, ln_g, ln_b, dn_g, dn_b, gpre, bgate, fo, fn_g, fn_b, out);
}

// Round 10
// 685.427 us; speedup vs baseline: 1.1542x; 1.0190x over previous
//
#include <hip/hip_runtime.h>
#include <hip/hip_bf16.h>

constexpr int B_ = 2, L_ = 2048, D_ = 1024, H_ = 16;

using bf16x8 = __attribute__((ext_vector_type(8))) short;
using f32x4  = __attribute__((ext_vector_type(4))) float;

__device__ __forceinline__ short f2b(float f) {
  union { float f; unsigned int u; } v; v.f = f;
  unsigned int r = (v.u + 0x7FFFu + ((v.u >> 16) & 1u)) >> 16;
  return (short)r;
}
__device__ __forceinline__ float b2f(unsigned short h) {
  union { unsigned int u; float f; } v; v.u = ((unsigned int)h) << 16; return v.f;
}
__device__ __forceinline__ void split2(float x, float y, unsigned int& h, unsigned int& l) {
  unsigned short hx = (unsigned short)f2b(x), hy = (unsigned short)f2b(y);
  h = (unsigned int)hx | ((unsigned int)hy << 16);
  unsigned short lx = (unsigned short)f2b(x - b2f(hx)), ly = (unsigned short)f2b(y - b2f(hy));
  l = (unsigned int)lx | ((unsigned int)ly << 16);
}
__device__ __forceinline__ float dot4(float4 a, float4 b) {
  return a.x * b.x + a.y * b.y + a.z * b.z + a.w * b.w;
}

// ---------------- merged weight preprocessing + x hi/lo split ----------------
// [0,768): Wqkv->Wqkvt ; [768,1280): dWq/dWk split ; [1280,1792): dWv/Wgate ; [1792,2816): xsplit
__global__ __launch_bounds__(256) void tcast_all(const float* __restrict__ Wqkv,
                                                 const float* __restrict__ dWq, const float* __restrict__ dWk,
                                                 const float* __restrict__ dWv, const float* __restrict__ Wgate,
                                                 const float* __restrict__ x,
                                                 short* __restrict__ Wqkvt,
                                                 short* __restrict__ Wqh, short* __restrict__ Wql,
                                                 short* __restrict__ Wkh, short* __restrict__ Wkl,
                                                 short* __restrict__ Wvt, short* __restrict__ wtg,
                                                 short* __restrict__ xh, short* __restrict__ xl) {
  int idx = blockIdx.x;
  int tid = threadIdx.x;
  if (idx >= 1792) {
    // xsplit: 1024 blocks x 256 threads x 8 floats = 2M elements... (4096x1024 = 4.19M; 2 elems per thread pair)
    // each block handles 4096 floats? No: 4,194,304 / 1024 blocks = 4096 floats/block; 256 threads x 16 floats.
    size_t base = (size_t)(idx - 1792) * 4096 + tid * 16;
#pragma unroll
    for (int rep = 0; rep < 2; ++rep) {
      size_t o = base + rep * 8;
      float4 a0 = *(const float4*)(x + o);
      float4 a1 = *(const float4*)(x + o + 4);
      uint4 uh, ul;
      split2(a0.x, a0.y, uh.x, ul.x);
      split2(a0.z, a0.w, uh.y, ul.y);
      split2(a1.x, a1.y, uh.z, ul.z);
      split2(a1.z, a1.w, uh.w, ul.w);
      *(uint4*)(xh + o) = uh;
      *(uint4*)(xl + o) = ul;
    }
    return;
  }
  __shared__ float T[64][65];
  const float* W;
  short* O1;
  short* O2 = nullptr;
  int N, bx, by;
  if (idx < 768) {
    W = Wqkv; O1 = Wqkvt; N = 3072; bx = idx % 48; by = idx / 48;
  } else if (idx < 1280) {
    int rem = idx - 768; int z = rem >> 8; rem &= 255;
    W = z ? dWk : dWq; O1 = z ? Wkh : Wqh; O2 = z ? Wkl : Wql; N = 1024;
    bx = rem & 15; by = rem >> 4;
  } else {
    int rem = idx - 1280; int z = rem >> 8; rem &= 255;
    W = z ? Wgate : dWv; O1 = z ? wtg : Wvt; N = 1024;
    bx = rem & 15; by = rem >> 4;
  }
  int n0 = bx * 64, k0 = by * 64;
#pragma unroll
  for (int i = 0; i < 16; ++i) {
    int id2 = i * 256 + tid;
    int r = id2 >> 6, c = id2 & 63;
    T[r][c] = W[(size_t)(k0 + r) * N + n0 + c];
  }
  __syncthreads();
#pragma unroll
  for (int i = 0; i < 16; ++i) {
    int id2 = i * 256 + tid;
    int rr = id2 >> 6, cc = id2 & 63;
    float w = T[cc][rr];
    short h = f2b(w);
    size_t o = (size_t)(n0 + rr) * 1024 + k0 + cc;  // K=1024 for all
    O1[o] = h;
    if (O2) O2[o] = f2b(w - b2f((unsigned short)h));
  }
}

// two-weight tcast (1024x1024 each), blockIdx.z selects  (backend: Wout/dWo)
__global__ __launch_bounds__(256) void tcast2(const float* __restrict__ W1, const float* __restrict__ W2,
                                              short* __restrict__ Wt1, short* __restrict__ Wt2) {
  __shared__ float T[64][65];
  const float* W = blockIdx.z ? W2 : W1;
  short* Wt = blockIdx.z ? Wt2 : Wt1;
  int n0 = blockIdx.x * 64, k0 = blockIdx.y * 64;
  int tid = threadIdx.x;
#pragma unroll
  for (int i = 0; i < 16; ++i) {
    int idx = i * 256 + tid;
    int r = idx >> 6, c = idx & 63;
    T[r][c] = W[(size_t)(k0 + r) * 1024 + n0 + c];
  }
  __syncthreads();
#pragma unroll
  for (int i = 0; i < 16; ++i) {
    int idx = i * 256 + tid;
    int rr = idx >> 6, cc = idx & 63;
    Wt[(size_t)(n0 + rr) * 1024 + k0 + cc] = f2b(T[cc][rr]);
  }
}

// ---------------- MFMA GEMM core, bf16 A from global, shared-mem passed in ----------------
template <int BN, typename CT>
__device__ __forceinline__ void gemm_bt_body_hA(char* smraw, const short* __restrict__ A,
                                                const short* __restrict__ Wt, CT* __restrict__ C,
                                                int N, int K, int bx, int by) {
  constexpr int MT = (BN == 128) ? 4 : 2;
  constexpr int NT = 4;
  short* As = (short*)smraw;             // 128*32
  short* Bs = (short*)(smraw + 8192);    // BN*32
  int tid = threadIdx.x;
  int wave = tid >> 6, lane = tid & 63, quad = lane >> 4, l15 = lane & 15;
  int m0 = by * 128, n0 = bx * BN;
  int wm = (BN == 128) ? (wave >> 1) * 64 : wave * 32;
  int wn = (BN == 128) ? (wave & 1) * 64 : 0;
  f32x4 acc[MT][NT];
#pragma unroll
  for (int mt = 0; mt < MT; ++mt)
#pragma unroll
    for (int nt = 0; nt < NT; ++nt) acc[mt][nt] = (f32x4){0.f, 0.f, 0.f, 0.f};

  for (int k0 = 0; k0 < K; k0 += 32) {
    __syncthreads();
#pragma unroll
    for (int i = 0; i < 2; ++i) {
      int chunk = i * 256 + tid;
      int m = chunk >> 2, kc = (chunk & 3) * 8;
      *(uint4*)&As[m * 32 + kc] = *(const uint4*)(A + (size_t)(m0 + m) * K + k0 + kc);
    }
#pragma unroll
    for (int i = 0; i < BN * 4 / 256; ++i) {
      int chunk = i * 256 + tid;
      int n = chunk >> 2, kc = (chunk & 3) * 8;
      *(uint4*)&Bs[n * 32 + kc] = *(const uint4*)(Wt + (size_t)(n0 + n) * K + k0 + kc);
    }
    __syncthreads();
    bf16x8 af[MT], bf[NT];
#pragma unroll
    for (int mt = 0; mt < MT; ++mt) af[mt] = *(bf16x8*)&As[(wm + mt * 16 + l15) * 32 + quad * 8];
#pragma unroll
    for (int nt = 0; nt < NT; ++nt) bf[nt] = *(bf16x8*)&Bs[(wn + nt * 16 + l15) * 32 + quad * 8];
#pragma unroll
    for (int mt = 0; mt < MT; ++mt)
#pragma unroll
      for (int nt = 0; nt < NT; ++nt)
        acc[mt][nt] = __builtin_amdgcn_mfma_f32_16x16x32_bf16(af[mt], bf[nt], acc[mt][nt], 0, 0, 0);
  }
#pragma unroll
  for (int mt = 0; mt < MT; ++mt)
#pragma unroll
    for (int nt = 0; nt < NT; ++nt)
#pragma unroll
      for (int r = 0; r < 4; ++r) {
        size_t idx = (size_t)(m0 + wm + mt * 16 + quad * 4 + r) * N + n0 + wn + nt * 16 + l15;
        if constexpr (sizeof(CT) == 2) C[idx] = f2b(acc[mt][nt][r]);
        else C[idx] = acc[mt][nt][r];
      }
}

// ---------------- beta body (shared-mem passed in) ----------------
__device__ __forceinline__ void beta_body(char* smraw, const float* __restrict__ xf,
                                          const float* __restrict__ Wb, const float* __restrict__ bb,
                                          float* __restrict__ beta, int row) {
  float (*red)[17] = (float(*)[17])smraw;
  int tid = threadIdx.x;
  int h = tid & 15, seg = tid >> 4;
  const float* xr = xf + (size_t)row * D_ + seg * 64;
  const float* wp = Wb + (seg * 64) * H_ + h;
  float p = 0.f;
  for (int k = 0; k < 64; ++k) p += xr[k] * wp[k * H_];
  red[seg][h] = p;
  __syncthreads();
  if (tid < 16) {
    float s = bb[tid];
#pragma unroll
    for (int s2 = 0; s2 < 16; ++s2) s += red[s2][tid];
    beta[(size_t)row * H_ + tid] = 1.f / (1.f + __expf(-s));
  }
}

// merged: qkv GEMM (768, bf16 A) + dual dv/gpre GEMM (1024, bf16 A) + beta (4096, fp32 x)
__global__ __launch_bounds__(256) void gemm3_beta(const short* __restrict__ xh, const float* __restrict__ x,
                                                  const short* __restrict__ Wqkvt, short* __restrict__ qkvh,
                                                  const short* __restrict__ Wvt, const short* __restrict__ wtg,
                                                  float* __restrict__ dv, float* __restrict__ gpre,
                                                  const float* __restrict__ Wb, const float* __restrict__ bb,
                                                  float* __restrict__ betab) {
  __shared__ __align__(16) char smem[16384];
  int idx = blockIdx.x;
  if (idx < 768) {
    gemm_bt_body_hA<128, short>(smem, xh, Wqkvt, qkvh, 3072, 1024, idx % 24, idx / 24);
  } else if (idx < 1792) {
    int rem = idx - 768;
    int z = rem >> 9;
    gemm_bt_body_hA<64, float>(smem, xh, z ? wtg : Wvt, z ? gpre : dv, 1024, 1024, rem & 15, (rem >> 4) & 31);
  } else {
    beta_body(smem, x, Wb, bb, betab, idx - 1792);
  }
}

// dual bf16-A GEMM: z=0: A1@Wt1->C1, z=1: A2@Wt2->C2 (1024x1024)
__global__ __launch_bounds__(256) void gemm_bt2_hA(const short* __restrict__ A1, const short* __restrict__ Wt1,
                                                   const short* __restrict__ A2, const short* __restrict__ Wt2,
                                                   float* __restrict__ C1, float* __restrict__ C2) {
  __shared__ __align__(16) char smem[12288];
  gemm_bt_body_hA<64, float>(smem, blockIdx.z ? A2 : A1, blockIdx.z ? Wt2 : Wt1,
                             blockIdx.z ? C2 : C1, 1024, 1024, blockIdx.x, blockIdx.y);
}

// ---------------- split-precision MFMA GEMM with PRE-SPLIT bf16 A ----------------
// C = (Ah+Al)@(Wh+Wl) dropping Al@Wl  (~fp32 accuracy)
__global__ __launch_bounds__(256) void gemm_bt3_hA(const short* __restrict__ xh, const short* __restrict__ xl,
                                                   const short* __restrict__ Wh1, const short* __restrict__ Wl1,
                                                   const short* __restrict__ Wh2, const short* __restrict__ Wl2,
                                                   float* __restrict__ C1, float* __restrict__ C2) {
  constexpr int K = 1024, N = 1024;
  const short* Wh = blockIdx.z ? Wh2 : Wh1;
  const short* Wl = blockIdx.z ? Wl2 : Wl1;
  float* C = blockIdx.z ? C2 : C1;
  __shared__ __align__(16) short Ash[128 * 32];
  __shared__ __align__(16) short Asl[128 * 32];
  __shared__ __align__(16) short Bsh[64 * 32];
  __shared__ __align__(16) short Bsl[64 * 32];
  int tid = threadIdx.x;
  int wave = tid >> 6, lane = tid & 63, quad = lane >> 4, l15 = lane & 15;
  int m0 = blockIdx.y * 128, n0 = blockIdx.x * 64;
  int wm = wave * 32;
  f32x4 acc[2][4];
#pragma unroll
  for (int mt = 0; mt < 2; ++mt)
#pragma unroll
    for (int nt = 0; nt < 4; ++nt) acc[mt][nt] = (f32x4){0.f, 0.f, 0.f, 0.f};

  for (int k0 = 0; k0 < K; k0 += 32) {
    __syncthreads();
#pragma unroll
    for (int i = 0; i < 2; ++i) {
      int chunk = i * 256 + tid;
      int m = chunk >> 2, kc = (chunk & 3) * 8;
      size_t off = (size_t)(m0 + m) * K + k0 + kc;
      *(uint4*)&Ash[m * 32 + kc] = *(const uint4*)(xh + off);
      *(uint4*)&Asl[m * 32 + kc] = *(const uint4*)(xl + off);
    }
    {
      int n = tid >> 2, kc = (tid & 3) * 8;
      size_t off = (size_t)(n0 + n) * K + k0 + kc;
      *(uint4*)&Bsh[n * 32 + kc] = *(const uint4*)(Wh + off);
      *(uint4*)&Bsl[n * 32 + kc] = *(const uint4*)(Wl + off);
    }
    __syncthreads();
    bf16x8 ah[2], al[2], bh[4], bl[4];
#pragma unroll
    for (int mt = 0; mt < 2; ++mt) {
      ah[mt] = *(bf16x8*)&Ash[(wm + mt * 16 + l15) * 32 + quad * 8];
      al[mt] = *(bf16x8*)&Asl[(wm + mt * 16 + l15) * 32 + quad * 8];
    }
#pragma unroll
    for (int nt = 0; nt < 4; ++nt) {
      bh[nt] = *(bf16x8*)&Bsh[(nt * 16 + l15) * 32 + quad * 8];
      bl[nt] = *(bf16x8*)&Bsl[(nt * 16 + l15) * 32 + quad * 8];
    }
#pragma unroll
    for (int mt = 0; mt < 2; ++mt)
#pragma unroll
      for (int nt = 0; nt < 4; ++nt) {
        f32x4 a = acc[mt][nt];
        a = __builtin_amdgcn_mfma_f32_16x16x32_bf16(al[mt], bh[nt], a, 0, 0, 0);
        a = __builtin_amdgcn_mfma_f32_16x16x32_bf16(ah[mt], bl[nt], a, 0, 0, 0);
        a = __builtin_amdgcn_mfma_f32_16x16x32_bf16(ah[mt], bh[nt], a, 0, 0, 0);
        acc[mt][nt] = a;
      }
  }
#pragma unroll
  for (int mt = 0; mt < 2; ++mt)
#pragma unroll
    for (int nt = 0; nt < 4; ++nt)
#pragma unroll
      for (int r = 0; r < 4; ++r) {
        size_t idx = (size_t)(m0 + wm + mt * 16 + quad * 4 + r) * N + n0 + nt * 16 + l15;
        C[idx] = acc[mt][nt][r];
      }
}

// ================= fused attn + delta (shared-LDS overlay, block-range split) =================
struct DeltaSmem {        // 22.4 KB: BqM read direct from global in P2
  float MKl[2][32 * 68];
  float Vl[2][32 * 5];
  float bll[2][32];
  float dnl[2][32];
  float zil[2][64];
  float S0l[4 * 68];
  float Y0l[32 * 5];
  float Rtl[4 * 36];
  float z0l[64];
  float qzl[32];
};
struct AttnSmem {         // 24.0 KB
  short Kl[64 * 64];
  short Vt[64 * 64];
  short Pl[64 * 64];
};
constexpr size_t SMEM_MAX = sizeof(DeltaSmem) > sizeof(AttnSmem) ? sizeof(DeltaSmem) : sizeof(AttnSmem);

__device__ __forceinline__ void delta_body(char* smraw, int bidx,
                                           const float* __restrict__ dq, const float* __restrict__ dk,
                                           const float* __restrict__ dv, const float* __restrict__ beta,
                                           const float* __restrict__ MK_g, const float* __restrict__ BqM_g,
                                           const float* __restrict__ denB_g, const float* __restrict__ zinc_g,
                                           short* __restrict__ ys_h, float* __restrict__ outS,
                                           float* __restrict__ outZ) {
  DeltaSmem& sm = *reinterpret_cast<DeltaSmem*>(smraw);
  int bh = bidx & 31, grp = bidx >> 5;  // same-bh groups share an XCD
  int b = bh >> 4, h = bh & 15;
  int i0 = grp * 4;
  int tid = threadIdx.x;
  int r = tid >> 3, j8 = (tid & 7) * 8;
  int js = tid & 7;
  size_t kqbase = (size_t)(b * L_) * 1024 + h * 64;

  for (int e = tid; e < 4 * 68; e += 256) sm.S0l[e] = 0.f;
  if (tid < 64) sm.z0l[tid] = 0.f;

  float4 kAc, kBc, qAc, qBc, kAn, kBn, qAn, qBn;
  float4 mA, mB;
  float vr = 0.f, blr = 0.f, dnb = 0.f, zi = 0.f;

#define KQLOAD(CN, KA, KB, QA, QB) { \
    size_t rb_ = kqbase + (size_t)((CN) * 32 + r) * 1024 + j8; \
    KA = ((const float4*)(dk + rb_))[0]; KB = ((const float4*)(dk + rb_))[1]; \
    QA = ((const float4*)(dq + rb_))[0]; QB = ((const float4*)(dq + rb_))[1]; \
  }
#define AUXLOAD(CN) { \
    size_t cb_ = (size_t)(bh * 64 + (CN)); \
    const float* mkp_ = MK_g + (cb_ * 32 + r) * 64 + j8; \
    mA = ((const float4*)mkp_)[0]; mB = ((const float4*)mkp_)[1]; \
    if (tid < 128) { \
      vr = dv[(size_t)(b * L_ + (CN) * 32 + (tid >> 2)) * 1024 + h * 64 + i0 + (tid & 3)]; \
    } \
    if (tid < 32) { blr = beta[(size_t)(b * L_ + (CN) * 32 + tid) * 16 + h]; dnb = denB_g[cb_ * 32 + tid]; } \
    if (tid < 64) zi = zinc_g[cb_ * 64 + tid]; \
  }
#define AUXSTORE(NX) { \
    *(float4*)&sm.MKl[NX][r * 68 + j8] = mA; *(float4*)&sm.MKl[NX][r * 68 + j8 + 4] = mB; \
    if (tid < 128) sm.Vl[NX][(tid >> 2) * 5 + (tid & 3)] = vr; \
    if (tid < 32) { sm.bll[NX][tid] = blr; sm.dnl[NX][tid] = dnb; } \
    if (tid < 64) sm.zil[NX][tid] = zi; \
  }

  KQLOAD(0, kAc, kBc, qAc, qBc);
  AUXLOAD(0);
  AUXSTORE(0);
  __syncthreads();

  for (int c = 0; c < 64; ++c) {
    int cur = c & 1, nxt = cur ^ 1;
    int cn = (c + 1 < 64) ? c + 1 : 63;
    KQLOAD(cn, kAn, kBn, qAn, qBn);   // HBM/L2 latency hides under P1
    AUXLOAD(cn);
    // ---- P1 ----
    {
      float aK[4], aY[4];
#pragma unroll
      for (int i = 0; i < 4; ++i) {
        float4 s0 = *(float4*)&sm.S0l[i * 68 + j8];
        float4 s1 = *(float4*)&sm.S0l[i * 68 + j8 + 4];
        aK[i] = dot4(kAc, s0) + dot4(kBc, s1);
        aY[i] = dot4(qAc, s0) + dot4(qBc, s1);
      }
      float4 z0 = *(float4*)&sm.z0l[j8];
      float4 z1 = *(float4*)&sm.z0l[j8 + 4];
      float aZ = dot4(qAc, z0) + dot4(qBc, z1);
#pragma unroll
      for (int off = 1; off <= 4; off <<= 1) {
#pragma unroll
        for (int i = 0; i < 4; ++i) {
          aK[i] += __shfl_xor(aK[i], off);
          aY[i] += __shfl_xor(aY[i], off);
        }
        aZ += __shfl_xor(aZ, off);
      }
      if (js == 0) {
        float be = sm.bll[cur][r];
#pragma unroll
        for (int i = 0; i < 4; ++i) {
          sm.Rtl[i * 36 + r] = be * (sm.Vl[cur][r * 5 + i] - aK[i]);
          sm.Y0l[r * 5 + i] = aY[i];
        }
        sm.qzl[r] = aZ;
      }
    }
    __syncthreads();
    // ---- P2: S-update + z (0-127) || y-out with BqM from global (128-255) ----
    if (tid < 128) {
      int i2 = tid >> 5;
      int j2 = (tid & 31) * 2;
      float a0 = sm.S0l[i2 * 68 + j2];
      float a1 = sm.S0l[i2 * 68 + j2 + 1];
#pragma unroll
      for (int s4i = 0; s4i < 8; ++s4i) {
        float4 rt = *(float4*)&sm.Rtl[i2 * 36 + s4i * 4];
        float2 m0 = *(float2*)&sm.MKl[cur][(s4i * 4 + 0) * 68 + j2];
        float2 m1 = *(float2*)&sm.MKl[cur][(s4i * 4 + 1) * 68 + j2];
        float2 m2 = *(float2*)&sm.MKl[cur][(s4i * 4 + 2) * 68 + j2];
        float2 m3 = *(float2*)&sm.MKl[cur][(s4i * 4 + 3) * 68 + j2];
        a0 += rt.x * m0.x + rt.y * m1.x + rt.z * m2.x + rt.w * m3.x;
        a1 += rt.x * m0.y + rt.y * m1.y + rt.z * m2.y + rt.w * m3.y;
      }
      sm.S0l[i2 * 68 + j2] = a0;
      sm.S0l[i2 * 68 + j2 + 1] = a1;
      if (tid < 64) sm.z0l[tid] += sm.zil[cur][tid];
    } else {
      size_t cbc = (size_t)(bh * 64 + c);
      int t = (tid >> 2) & 31;
      int i = tid & 3;
      const float* bqr = BqM_g + cbc * 1024 + t * 32;  // row t (L2-resident)
      float acc = sm.Y0l[t * 5 + i];
#pragma unroll
      for (int s4i = 0; s4i < 8; ++s4i)
        acc += dot4(*(const float4*)(bqr + s4i * 4), *(float4*)&sm.Rtl[i * 36 + s4i * 4]);
      float y = acc / (sm.qzl[t] + sm.dnl[cur][t] + 1e-6f);
      ys_h[(size_t)(b * L_ + c * 32 + t) * 1024 + h * 64 + i0 + i] = f2b(y);
    }
    AUXSTORE(nxt);
    kAc = kAn; kBc = kBn; qAc = qAn; qBc = qBn;
    __syncthreads();
  }
#undef KQLOAD
#undef AUXLOAD
#undef AUXSTORE
  {
    int i = tid >> 6, j = tid & 63;
    outS[((size_t)(bh * 64) + i0 + i) * 64 + j] = sm.S0l[i * 68 + j];
  }
  if (grp == 0 && tid < 64) outZ[bh * 64 + tid] = sm.z0l[tid];
}

__device__ __forceinline__ void attn_body(char* smraw, int idx, const short* __restrict__ qkv,
                                          short* __restrict__ outp_h) {
  AttnSmem& sm = *reinterpret_cast<AttnSmem*>(smraw);
  int qb = 31 - (idx & 31), h = (idx >> 5) & 15, b = idx >> 9;
  int tid = threadIdx.x;
  int wave = tid >> 6, lane = tid & 63;
  int quad = lane >> 4, l15 = lane & 15;
  int qrow = qb * 64 + wave * 16 + l15;
  bf16x8 qf[2];
  {
    const short* qbase = qkv + (size_t)(b * L_ + qrow) * 3072 + h * 64;
#pragma unroll
    for (int s = 0; s < 2; ++s) qf[s] = *(const bf16x8*)(qbase + s * 32 + quad * 8);
  }
  f32x4 Of[4];
  float mrow[4], lrow[4], alpha[4];
#pragma unroll
  for (int dt = 0; dt < 4; ++dt) Of[dt] = (f32x4){0.f, 0.f, 0.f, 0.f};
#pragma unroll
  for (int r = 0; r < 4; ++r) { mrow[r] = -1e30f; lrow[r] = 0.f; }

  for (int kt = 0; kt <= qb; ++kt) {
    __syncthreads();
#pragma unroll
    for (int it = 0; it < 2; ++it) {
      int e8 = tid + it * 256;
      int key = e8 >> 3, g = e8 & 7;
      const short* src = qkv + ((size_t)((b * L_ + kt * 64 + key) * 3) + 1) * 1024 + h * 64 + g * 8;
      *(bf16x8*)&sm.Kl[key * 64 + ((g ^ (key & 7)) << 3)] = *(const bf16x8*)src;
    }
    {
      int key4 = tid >> 4;
      int d4 = tid & 15;
      const short* vsrc = qkv + ((size_t)((b * L_ + kt * 64 + key4 * 4) * 3) + 2) * 1024 + h * 64 + d4 * 4;
      short4 v0 = *(const short4*)vsrc;
      short4 v1 = *(const short4*)(vsrc + 3072);
      short4 v2 = *(const short4*)(vsrc + 6144);
      short4 v3 = *(const short4*)(vsrc + 9216);
      short vr0[4] = {v0.x, v0.y, v0.z, v0.w};
      short vr1[4] = {v1.x, v1.y, v1.z, v1.w};
      short vr2[4] = {v2.x, v2.y, v2.z, v2.w};
      short vr3[4] = {v3.x, v3.y, v3.z, v3.w};
      int kg = key4 >> 1, k7b = (key4 & 1) * 4;
#pragma unroll
      for (int jj = 0; jj < 4; ++jj) {
        int d = d4 * 4 + jj;
        short4 sv;
        sv.x = vr0[jj]; sv.y = vr1[jj]; sv.z = vr2[jj]; sv.w = vr3[jj];
        *(short4*)&sm.Vt[d * 64 + ((kg ^ (d & 7)) << 3) + k7b] = sv;
      }
    }
    __syncthreads();
    f32x4 sc[4];
#pragma unroll
    for (int nt = 0; nt < 4; ++nt) sc[nt] = (f32x4){0.f, 0.f, 0.f, 0.f};
#pragma unroll
    for (int s = 0; s < 2; ++s) {
#pragma unroll
      for (int nt = 0; nt < 4; ++nt) {
        int key = nt * 16 + l15;
        bf16x8 kf = *(bf16x8*)&sm.Kl[key * 64 + (((4 * s + quad) ^ (key & 7)) << 3)];
        sc[nt] = __builtin_amdgcn_mfma_f32_16x16x32_bf16(qf[s], kf, sc[nt], 0, 0, 0);
      }
    }
    bool diag = (kt == qb);
#pragma unroll
    for (int r = 0; r < 4; ++r) {
      float sv[4];
#pragma unroll
      for (int nt = 0; nt < 4; ++nt) {
        float v = sc[nt][r] * 0.125f;
        if (diag && (nt * 16 + l15 > wave * 16 + quad * 4 + r)) v = -1e30f;
        sv[nt] = v;
      }
      float mx = fmaxf(fmaxf(sv[0], sv[1]), fmaxf(sv[2], sv[3]));
      mx = fmaxf(mx, __shfl_xor(mx, 1));
      mx = fmaxf(mx, __shfl_xor(mx, 2));
      mx = fmaxf(mx, __shfl_xor(mx, 4));
      mx = fmaxf(mx, __shfl_xor(mx, 8));
      float mnew = fmaxf(mrow[r], mx);
      float al = __expf(mrow[r] - mnew);
      mrow[r] = mnew;
      alpha[r] = al;
      int prow = wave * 16 + quad * 4 + r;
      int r7 = prow & 7;
      float ps = 0.f;
#pragma unroll
      for (int nt = 0; nt < 4; ++nt) {
        float p = __expf(sv[nt] - mnew);
        ps += p;
        sm.Pl[prow * 64 + ((((nt << 1) + (l15 >> 3)) ^ r7) << 3) + (l15 & 7)] = f2b(p);
      }
      ps += __shfl_xor(ps, 1);
      ps += __shfl_xor(ps, 2);
      ps += __shfl_xor(ps, 4);
      ps += __shfl_xor(ps, 8);
      lrow[r] = lrow[r] * al + ps;
    }
#pragma unroll
    for (int dt = 0; dt < 4; ++dt)
#pragma unroll
      for (int r = 0; r < 4; ++r) Of[dt][r] *= alpha[r];
#pragma unroll
    for (int s = 0; s < 2; ++s) {
      bf16x8 pf = *(bf16x8*)&sm.Pl[(wave * 16 + l15) * 64 + (((4 * s + quad) ^ (l15 & 7)) << 3)];
#pragma unroll
      for (int dt = 0; dt < 4; ++dt) {
        int d = dt * 16 + l15;
        bf16x8 vf = *(bf16x8*)&sm.Vt[d * 64 + (((4 * s + quad) ^ (d & 7)) << 3)];
        Of[dt] = __builtin_amdgcn_mfma_f32_16x16x32_bf16(pf, vf, Of[dt], 0, 0, 0);
      }
    }
  }
#pragma unroll
  for (int r = 0; r < 4; ++r) alpha[r] = 1.f / lrow[r];
  int orow = qb * 64 + wave * 16 + quad * 4;
#pragma unroll
  for (int dt = 0; dt < 4; ++dt)
#pragma unroll
    for (int r = 0; r < 4; ++r)
      outp_h[(size_t)(b * L_ + orow + r) * 1024 + h * 64 + dt * 16 + l15] = f2b(Of[dt][r] * alpha[r]);
}

// blocks [0,512): delta scan. blocks [512,1536): attention. LDS overlaid.
__global__ __launch_bounds__(256) void attn_delta_fused(
    const short* __restrict__ qkv, short* __restrict__ attnO_h,
    const float* __restrict__ dq, const float* __restrict__ dk,
    const float* __restrict__ dv, const float* __restrict__ beta,
    const float* __restrict__ MK_g, const float* __restrict__ BqM_g,
    const float* __restrict__ denB_g, const float* __restrict__ zinc_g,
    short* __restrict__ ys_h, float* __restrict__ outS, float* __restrict__ outZ) {
  __shared__ __align__(16) char smem[SMEM_MAX];
  if (blockIdx.x < 512)
    delta_body(smem, blockIdx.x, dq, dk, dv, beta, MK_g, BqM_g, denB_g, zinc_g, ys_h, outS, outZ);
  else
    attn_body(smem, blockIdx.x - 512, qkv, attnO_h);
}

// ---------------- fused: LN(fo) + LN(LN(do1)) + gate mix ----------------
__global__ __launch_bounds__(256) void ln2mix_f(const float* __restrict__ X,
                                                const float* __restrict__ g1, const float* __restrict__ b1,
                                                const float* __restrict__ g2, const float* __restrict__ b2,
                                                const float* __restrict__ gpre, const float* __restrict__ bgate,
                                                const float* __restrict__ foraw,
                                                const float* __restrict__ fng, const float* __restrict__ fnb,
                                                float* __restrict__ outp) {
  int row = blockIdx.x, tid = threadIdx.x;
  const float* xr = X + (size_t)row * D_;
  const float* fr = foraw + (size_t)row * D_;
  __shared__ float rs[4], rss[4], frs[4], frss[4];
  float v[4], f[4];
  float s = 0.f, ss = 0.f, fs = 0.f, fss = 0.f;
#pragma unroll
  for (int i = 0; i < 4; ++i) {
    v[i] = xr[tid + i * 256]; s += v[i]; ss += v[i] * v[i];
    f[i] = fr[tid + i * 256]; fs += f[i]; fss += f[i] * f[i];
  }
#pragma unroll
  for (int off = 32; off; off >>= 1) {
    s += __shfl_xor(s, off); ss += __shfl_xor(ss, off);
    fs += __shfl_xor(fs, off); fss += __shfl_xor(fss, off);
  }
  if ((tid & 63) == 0) { rs[tid >> 6] = s; rss[tid >> 6] = ss; frs[tid >> 6] = fs; frss[tid >> 6] = fss; }
  __syncthreads();
  float S = rs[0] + rs[1] + rs[2] + rs[3];
  float SS = rss[0] + rss[1] + rss[2] + rss[3];
  float FS = frs[0] + frs[1] + frs[2] + frs[3];
  float FSS = frss[0] + frss[1] + frss[2] + frss[3];
  float mean = S * (1.f / 1024.f);
  float var = SS * (1.f / 1024.f) - mean * mean;
  float inv = rsqrtf(var + 1e-5f);
  float fmean = FS * (1.f / 1024.f);
  float fvar = FSS * (1.f / 1024.f) - fmean * fmean;
  float finv = rsqrtf(fvar + 1e-5f);
  s = 0.f; ss = 0.f;
#pragma unroll
  for (int i = 0; i < 4; ++i) {
    int c = tid + i * 256;
    v[i] = (v[i] - mean) * inv * g1[c] + b1[c];
    s += v[i]; ss += v[i] * v[i];
  }
#pragma unroll
  for (int off = 32; off; off >>= 1) { s += __shfl_xor(s, off); ss += __shfl_xor(ss, off); }
  __syncthreads();
  if ((tid & 63) == 0) { rs[tid >> 6] = s; rss[tid >> 6] = ss; }
  __syncthreads();
  S = rs[0] + rs[1] + rs[2] + rs[3];
  SS = rss[0] + rss[1] + rss[2] + rss[3];
  mean = S * (1.f / 1024.f);
  var = SS * (1.f / 1024.f) - mean * mean;
  inv = rsqrtf(var + 1e-5f);
#pragma unroll
  for (int i = 0; i < 4; ++i) {
    int c = tid + i * 256;
    size_t idx = (size_t)row * D_ + c;
    float w = (v[i] - mean) * inv * g2[c] + b2[c];
    float fl = (f[i] - fmean) * finv * fng[c] + fnb[c];
    float gg = 1.f / (1.f + __expf(-(gpre[idx] + bgate[c])));
    outp[idx] = gg * fl + (1.f - gg) * w;
  }
}

// ---------------- fused conv (q) / conv+L2norm (k) ----------------
__global__ __launch_bounds__(256) void convnorm_kernel(const float* __restrict__ qin, const float* __restrict__ kin,
                                                       const float* __restrict__ qw, const float* __restrict__ qb,
                                                       const float* __restrict__ kw, const float* __restrict__ kb,
                                                       float* __restrict__ qout, float* __restrict__ kout) {
  int path = blockIdx.y;
  int row = blockIdx.x * 4 + (threadIdx.x >> 6);
  int lane = threadIdx.x & 63;
  int bl = row >> 4, h = row & 15;
  int t = bl & (L_ - 1);
  int d = h * 64 + lane;
  size_t idx = (size_t)bl * D_ + d;
  const float* xin = path ? kin : qin;
  const float* w = path ? kw : qw;
  const float* bias = path ? kb : qb;
  float acc = bias[d];
#pragma unroll
  for (int j = 0; j < 4; ++j) {
    int tt = t - 3 + j;
    if (tt >= 0) acc += w[d * 4 + j] * xin[idx + (size_t)(j - 3) * D_];
  }
  if (path) {
    float n2 = acc * acc;
#pragma unroll
    for (int off = 32; off; off >>= 1) n2 += __shfl_xor(n2, off);
    acc = acc / fmaxf(sqrtf(n2), 1e-12f);
    kout[idx] = acc;
  } else {
    qout[idx] = acc;
  }
}

// ================= chunked delta scan prep =================
__global__ __launch_bounds__(256) void prep_kernel(const float* __restrict__ dq, const float* __restrict__ dk,
                                                   const float* __restrict__ beta,
                                                   float* __restrict__ MK_g, float* __restrict__ BqM_g,
                                                   float* __restrict__ denB_g, float* __restrict__ zinc_g) {
  __shared__ __align__(16) float Kl[32 * 68];
  __shared__ __align__(16) float Ql[32 * 68];
  __shared__ __align__(16) float Ml[32 * 36];
  __shared__ __align__(16) float Xl[32 * 36];
  __shared__ __align__(16) float Bql[32 * 36];
  __shared__ __align__(16) float bl[32];
  int c = blockIdx.x, bh = blockIdx.y;
  int b = bh >> 4, h = bh & 15;
  int t0 = c * 32;
  int tid = threadIdx.x;
#pragma unroll
  for (int rep = 0; rep < 2; ++rep) {
    int id = tid * 2 + rep;
    int r = id >> 4, j4 = id & 15;
    size_t gi = (size_t)(b * L_ + t0 + r) * 1024 + h * 64 + j4 * 4;
    *(float4*)&Kl[r * 68 + j4 * 4] = *(const float4*)&dk[gi];
    *(float4*)&Ql[r * 68 + j4 * 4] = *(const float4*)&dq[gi];
  }
  if (tid < 32) bl[tid] = beta[(size_t)(b * L_ + t0 + tid) * 16 + h];
  __syncthreads();
  int t = tid >> 3, s0 = (tid & 7) * 4;
  float accA[4] = {0.f, 0.f, 0.f, 0.f}, accB[4] = {0.f, 0.f, 0.f, 0.f};
#pragma unroll
  for (int k4 = 0; k4 < 16; ++k4) {
    float4 kt = *(float4*)&Kl[t * 68 + k4 * 4];
    float4 qt = *(float4*)&Ql[t * 68 + k4 * 4];
#pragma unroll
    for (int j = 0; j < 4; ++j) {
      float4 ks = *(float4*)&Kl[(s0 + j) * 68 + k4 * 4];
      accA[j] += dot4(kt, ks);
      accB[j] += dot4(qt, ks);
    }
  }
#pragma unroll
  for (int j = 0; j < 4; ++j) {
    int s = s0 + j;
    Ml[t * 36 + s] = (s < t) ? bl[t] * accA[j] : ((s == t) ? 1.f : 0.f);
    Bql[t * 36 + s] = (s < t) ? accB[j] : 0.f;
  }
  __syncthreads();
  if (tid < 32) {
    int col = tid;
    float xr[32];
#pragma unroll
    for (int tt = 0; tt < 32; ++tt) {
      float xv = (tt == col) ? 1.f : 0.f;
#pragma unroll
      for (int s = 0; s < tt; ++s) xv -= Ml[tt * 36 + s] * xr[s];
      xr[tt] = xv;
      Xl[tt * 36 + col] = xv;
    }
  }
  __syncthreads();
  size_t cb = (size_t)(bh * 64 + c);
  {
    int s = tid >> 3, j8 = (tid & 7) * 8;
    float4 m0 = make_float4(0.f, 0.f, 0.f, 0.f);
    float4 m1 = make_float4(0.f, 0.f, 0.f, 0.f);
#pragma unroll
    for (int t2 = 0; t2 < 32; ++t2) {
      float xv = Xl[t2 * 36 + s];
      float4 k0 = *(float4*)&Kl[t2 * 68 + j8];
      float4 k1 = *(float4*)&Kl[t2 * 68 + j8 + 4];
      m0.x += xv * k0.x; m0.y += xv * k0.y; m0.z += xv * k0.z; m0.w += xv * k0.w;
      m1.x += xv * k1.x; m1.y += xv * k1.y; m1.z += xv * k1.z; m1.w += xv * k1.w;
    }
    float* mkp = MK_g + (cb * 32 + s) * 64 + j8;
    *(float4*)mkp = m0;
    *(float4*)(mkp + 4) = m1;
  }
  {
    int tt = tid >> 3, s4 = (tid & 7) * 4;
    float4 acc = make_float4(0.f, 0.f, 0.f, 0.f);
#pragma unroll
    for (int u4 = 0; u4 < 8; ++u4) {
      float4 bq = *(float4*)&Bql[tt * 36 + u4 * 4];
      float4 x0 = *(float4*)&Xl[(u4 * 4 + 0) * 36 + s4];
      float4 x1 = *(float4*)&Xl[(u4 * 4 + 1) * 36 + s4];
      float4 x2 = *(float4*)&Xl[(u4 * 4 + 2) * 36 + s4];
      float4 x3 = *(float4*)&Xl[(u4 * 4 + 3) * 36 + s4];
      acc.x += bq.x * x0.x + bq.y * x1.x + bq.z * x2.x + bq.w * x3.x;
      acc.y += bq.x * x0.y + bq.y * x1.y + bq.z * x2.y + bq.w * x3.y;
      acc.z += bq.x * x0.z + bq.y * x1.z + bq.z * x2.z + bq.w * x3.z;
      acc.w += bq.x * x0.w + bq.y * x1.w + bq.z * x2.w + bq.w * x3.w;
    }
    *(float4*)&BqM_g[cb * 1024 + tt * 32 + s4] = acc;
  }
  if (tid < 32) {
    float a = 0.f;
#pragma unroll
    for (int s4i = 0; s4i < 8; ++s4i)
      a += dot4(*(float4*)&Bql[tid * 36 + s4i * 4], *(float4*)&bl[s4i * 4]);
    denB_g[cb * 32 + tid] = a;
  }
  if (tid >= 64 && tid < 128) {
    int j = tid - 64;
    float a = 0.f;
#pragma unroll
    for (int s = 0; s < 32; ++s) a += bl[s] * Kl[s * 68 + j];
    zinc_g[cb * 64 + j] = a;
  }
}

extern "C" void kernel_launch(void* const* d_in, const int* in_sizes, int n_in,
                              void* d_out, int out_size, void* d_ws, size_t ws_size,
                              hipStream_t stream) {
  const float* x     = (const float*)d_in[0];
  const float* Wqkv  = (const float*)d_in[1];
  const float* Wout  = (const float*)d_in[2];
  const float* Wgate = (const float*)d_in[3];
  const float* bgate = (const float*)d_in[4];
  const float* fn_g  = (const float*)d_in[5];
  const float* fn_b  = (const float*)d_in[6];
  const float* dn_g  = (const float*)d_in[7];
  const float* dn_b  = (const float*)d_in[8];
  const float* dWq   = (const float*)d_in[9];
  const float* dWk   = (const float*)d_in[10];
  const float* dWv   = (const float*)d_in[11];
  const float* dWo   = (const float*)d_in[12];
  const float* Wbeta = (const float*)d_in[13];
  const float* bbeta = (const float*)d_in[14];
  const float* cq_w  = (const float*)d_in[15];
  const float* cq_b  = (const float*)d_in[16];
  const float* ck_w  = (const float*)d_in[17];
  const float* ck_b  = (const float*)d_in[18];
  const float* ln_g  = (const float*)d_in[19];
  const float* ln_b  = (const float*)d_in[20];

  float* ws = (float*)d_ws;
  // ---- EXACT round-8 layout (passed); lifetimes s1..s9 ----
  float* dqc    = ws;                      // [0, 4194304)       s3->s6
  float* dkc    = ws + 4194304;            // [4194304, 8388608) s3->s6
  float* dv     = ws + 8388608;            // s4->s6
  float* gpre   = ws + 12582912;           // s4->s9
  float* betab  = ws + 16777216;           // 64K floats, s4->s6 (Wqh region, dead after s2)
  float* denB_g = ws + 16842752;           // 64K, s5->s6
  float* zinc_g = ws + 16908288;           // 128K, s5->s6
  float* MK_g   = ws + 17039360;           // 4M, s5->s6 (Wql..Wqkvt region, dead after s2/s4)
  short* Wqh    = (short*)(ws + 16777216); // 0.5M floats, s1->s2
  short* Wql    = (short*)(ws + 17301504); // s1->s2
  short* Wkh    = (short*)(ws + 17825792); // s1->s2
  short* Wkl    = (short*)(ws + 18350080); // s1->s2
  short* Wvt    = (short*)(ws + 18874368); // s1->s4
  short* wtg    = (short*)(ws + 19398656); // s1->s4
  short* Wqkvt  = (short*)(ws + 19922944); // 1.5M floats, s1->s4
  float* dqp    = ws + 21495808;           // 4M, s2->s3
  float* dkp    = ws + 25690112;           // 4M, s2->s3  (peak 29884416 floats)
  short* qkvh   = (short*)(ws + 21495808); // 6.29M floats, s4->s6 (dqp/dkp dead)
  float* BqM_g  = ws + 27787264;           // 2M, s5->s6 (dkp tail dead, past qkvh end)
  short* Woutt  = (short*)ws;              // [0, 0.52M floats) s7->s8 (dqc dead)
  short* Wot    = (short*)(ws + 524288);   // s7->s8
  float* do1    = ws + 4194304;            // s8->s9 (dkc dead)
  float* fo     = ws + 8388608;            // s8->s9 (dv dead)

  float* out  = (float*)d_out;
  float* outS = out + 4194304;
  float* outZ = out + 4325376;
  // d_out scratch (verified sizes): xh 2,097,152 floats @0 (s1->s4, dead before s6 writes ysb_h);
  // xl 2,097,152 floats @2097152 (s1->s2, dead before s6 writes attnO_h).
  short* xh      = (short*)out;             // 4,194,304 shorts = [0, 2097152) floats
  short* xl      = (short*)(out + 2097152); // [2097152, 4194304) floats
  short* ysb_h   = (short*)out;             // s6->s8, overwrites dead xh
  short* attnO_h = (short*)(out + 2097152); // s6->s8, overwrites dead xl

  // s1: all weight preprocessing + x hi/lo bf16 split (to d_out scratch)
  tcast_all<<<2816, 256, 0, stream>>>(Wqkv, dWq, dWk, dWv, Wgate, x,
                                      Wqkvt, Wqh, Wql, Wkh, Wkl, Wvt, wtg, xh, xl);
  // s2: split-precision dq/dk GEMM (pre-split bf16 A)
  gemm_bt3_hA<<<dim3(16, 32, 2), 256, 0, stream>>>(xh, xl, Wqh, Wql, Wkh, Wkl, dqp, dkp);
  // s3: causal conv + L2norm
  convnorm_kernel<<<dim3(16384, 2), 256, 0, stream>>>(dqp, dkp, cq_w, cq_b, ck_w, ck_b, dqc, dkc);
  // s4: qkv GEMM + dv/gate GEMM (bf16 A) + beta (fp32 x), one dispatch
  gemm3_beta<<<5888, 256, 0, stream>>>(xh, x, Wqkvt, qkvh, Wvt, wtg, dv, gpre, Wbeta, bbeta, betab);
  // s5: per-chunk prep (Minv hoisted products)
  prep_kernel<<<dim3(64, 32), 256, 0, stream>>>(dqc, dkc, betab, MK_g, BqM_g, denB_g, zinc_g);
  // s6: fused delta scan (blocks 0-511) || attention (blocks 512-1535)
  attn_delta_fused<<<1536, 256, 0, stream>>>(qkvh, attnO_h, dqc, dkc, dv, betab,
                                             MK_g, BqM_g, denB_g, zinc_g, ysb_h, outS, outZ);
  // s7: backend weight tcast
  tcast2<<<dim3(16, 16, 2), 256, 0, stream>>>(Wout, dWo, Woutt, Wot);
  // s8: dual output GEMM (bf16 A)
  gemm_bt2_hA<<<dim3(16, 32, 2), 256, 0, stream>>>(attnO_h, Woutt, ysb_h, Wot, fo, do1);
  // s9: final LN/LN/gate mix
  ln2mix_f<<<4096, 256, 0, stream>>>(do1, ln_g, ln_b, dn_g, dn_b, gpre, bgate, fo, fn_g, fn_b, out);
}